// Round 1
// baseline (849.682 us; speedup 1.0000x reference)
//
#include <hip/hip_runtime.h>
#include <hip/hip_bf16.h>

#define NN 8192
#define EE 262144
#define HID 64

// ---------------------------------------------------------------- GEMM (f32)
// C[M,Nc] = A[M,K] @ B(+bias)(+relu).  TRANS_B: B stored [Nc,K].
template<bool TRANS_B, int ACT>
__global__ void gemm_f32(const float* __restrict__ A, const float* __restrict__ B,
                         const float* __restrict__ bias, float* __restrict__ C,
                         int M, int Nc, int K) {
    __shared__ float As[16][65];
    __shared__ float Bs[16][65];
    int tid = threadIdx.x;
    int brow = blockIdx.y * 64, bcol = blockIdx.x * 64;
    int tr = (tid / 16) * 4;
    int tc = (tid % 16) * 4;
    float acc[4][4] = {};
    for (int k0 = 0; k0 < K; k0 += 16) {
        {   // A tile 64x16
            int r  = tid / 4;
            int kk = (tid % 4) * 4;
            const float* a = A + (size_t)(brow + r) * K + k0 + kk;
            #pragma unroll
            for (int j = 0; j < 4; ++j) As[kk + j][r] = a[j];
        }
        if (!TRANS_B) {   // B[K][Nc]
            int kk = tid / 16;
            int n4 = (tid % 16) * 4;
            #pragma unroll
            for (int j = 0; j < 4; ++j) {
                int n = bcol + n4 + j;
                Bs[kk][n4 + j] = (n < Nc) ? B[(size_t)(k0 + kk) * Nc + n] : 0.f;
            }
        } else {          // B[Nc][K]
            int n  = tid / 4;
            int kk = (tid % 4) * 4;
            #pragma unroll
            for (int j = 0; j < 4; ++j)
                Bs[kk + j][n] = (bcol + n < Nc) ? B[(size_t)(bcol + n) * K + k0 + kk + j] : 0.f;
        }
        __syncthreads();
        #pragma unroll
        for (int kk = 0; kk < 16; ++kk) {
            float av[4], bv[4];
            #pragma unroll
            for (int i = 0; i < 4; ++i) av[i] = As[kk][tr + i];
            #pragma unroll
            for (int j = 0; j < 4; ++j) bv[j] = Bs[kk][tc + j];
            #pragma unroll
            for (int i = 0; i < 4; ++i)
                #pragma unroll
                for (int j = 0; j < 4; ++j)
                    acc[i][j] += av[i] * bv[j];
        }
        __syncthreads();
    }
    #pragma unroll
    for (int i = 0; i < 4; ++i) {
        int r = brow + tr + i;
        #pragma unroll
        for (int j = 0; j < 4; ++j) {
            int c = bcol + tc + j;
            if (c < Nc) {
                float v = acc[i][j];
                if (bias) v += bias[c];
                if (ACT == 1) v = fmaxf(v, 0.f);
                C[(size_t)r * Nc + c] = v;
            }
        }
    }
}

// ------------------------------------------------------------------ GAT prep
__global__ void k_fill_i32(int* p, int v, int n) {
    int i = blockIdx.x * 256 + threadIdx.x;
    if (i < n) p[i] = v;
}

__global__ void count_deg(const int* __restrict__ ei, int* __restrict__ deg, int E) {
    int e = blockIdx.x * 256 + threadIdx.x;
    if (e < E) atomicAdd(&deg[ei[E + e]], 1);   // ei[1] row = dst
}

// single block, 1024 threads, N=8192 (8 per thread)
__global__ void scan_deg(const int* __restrict__ deg, int* __restrict__ row_ptr,
                         int* __restrict__ cursor, int N) {
    __shared__ int tmp[1024];
    int tid = threadIdx.x;
    int base = tid * 8;
    int local[8];
    int s = 0;
    #pragma unroll
    for (int j = 0; j < 8; ++j) { local[j] = deg[base + j]; s += local[j]; }
    tmp[tid] = s;
    __syncthreads();
    for (int off = 1; off < 1024; off <<= 1) {
        int add = (tid >= off) ? tmp[tid - off] : 0;
        __syncthreads();
        tmp[tid] += add;
        __syncthreads();
    }
    int run = tmp[tid] - s;   // exclusive prefix of this chunk
    #pragma unroll
    for (int j = 0; j < 8; ++j) {
        row_ptr[base + j] = run;
        cursor[base + j]  = run;
        run += local[j];
    }
    if (tid == 1023) row_ptr[N] = run;
}

__global__ void fill_csr(const int* __restrict__ ei, int* __restrict__ cursor,
                         int* __restrict__ col, int E, int N) {
    int e = blockIdx.x * 256 + threadIdx.x;
    if (e < E) {
        int dst = ei[E + e];
        int pos = atomicAdd(&cursor[dst], 1);
        col[pos] = ei[e];
    } else if (e < E + N) {
        int n = e - E;
        int pos = atomicAdd(&cursor[n], 1);
        col[pos] = n;
    }
}

// ---------------------------------------------------------------- GAT kernels
// a_s[n,h] = sum_c h[n,h,c]*att_s[h,c]  (wave per (n,h), lane per channel)
__global__ void gat_coef(const float* __restrict__ h, const float* __restrict__ att_s,
                         const float* __restrict__ att_d, float* __restrict__ a_s,
                         float* __restrict__ a_d, int N, int H) {
    int wid  = (blockIdx.x * 256 + threadIdx.x) >> 6;
    int lane = threadIdx.x & 63;
    if (wid >= N * H) return;
    int hh = wid % H;
    float v = h[(size_t)wid * 64 + lane];
    float s = v * att_s[hh * 64 + lane];
    float d = v * att_d[hh * 64 + lane];
    #pragma unroll
    for (int off = 32; off; off >>= 1) {
        s += __shfl_down(s, off);
        d += __shfl_down(d, off);
    }
    if (lane == 0) { a_s[wid] = s; a_d[wid] = d; }
}

// wave per (dst n, head h): segment softmax + weighted gather; atomicAdd head mean
__global__ void gat_gather(const float* __restrict__ h, const float* __restrict__ a_s,
                           const float* __restrict__ a_d, const int* __restrict__ row_ptr,
                           const int* __restrict__ col, float* __restrict__ out,
                           int N, int H) {
    int wid  = (blockIdx.x * 256 + threadIdx.x) >> 6;
    int lane = threadIdx.x & 63;
    if (wid >= N * H) return;
    int n = wid / H, hh = wid % H;
    int beg = row_ptr[n], end = row_ptr[n + 1];
    float adn = a_d[n * H + hh];
    // pass 1: max score
    float m = -1e30f;
    for (int j = beg + lane; j < end; j += 64) {
        float sc = a_s[col[j] * H + hh] + adn;
        sc = sc > 0.f ? sc : 0.2f * sc;
        m = fmaxf(m, sc);
    }
    #pragma unroll
    for (int off = 32; off; off >>= 1) m = fmaxf(m, __shfl_xor(m, off));
    // pass 2: exp weights + gather (lane = channel)
    float acc = 0.f, denom = 0.f;
    for (int base = beg; base < end; base += 64) {
        int j = base + lane;
        float w = 0.f; int s = 0;
        if (j < end) {
            s = col[j];
            float sc = a_s[s * H + hh] + adn;
            sc = sc > 0.f ? sc : 0.2f * sc;
            w = __expf(sc - m);
        }
        denom += w;
        int cnt = min(64, end - base);
        for (int k = 0; k < cnt; ++k) {
            float wk = __shfl(w, k);
            int   sk = __shfl(s, k);
            acc += wk * h[(size_t)sk * (H * 64) + hh * 64 + lane];
        }
    }
    #pragma unroll
    for (int off = 32; off; off >>= 1) denom += __shfl_xor(denom, off);
    atomicAdd(&out[n * 64 + lane], acc / ((denom + 1e-16f) * H));
}

// ------------------------------------------------------------------ BatchNorm
__global__ void bn_stats(const float* __restrict__ x, const float* __restrict__ gamma,
                         const float* __restrict__ beta, float* __restrict__ scale,
                         float* __restrict__ shift, int N) {
    int c = blockIdx.x;
    float s = 0.f, ss = 0.f;
    for (int r = threadIdx.x; r < N; r += 256) {
        float v = x[(size_t)r * 64 + c];
        s += v; ss += v * v;
    }
    #pragma unroll
    for (int off = 32; off; off >>= 1) {
        s  += __shfl_xor(s, off);
        ss += __shfl_xor(ss, off);
    }
    __shared__ float red[8];
    int wv = threadIdx.x >> 6, ln = threadIdx.x & 63;
    if (ln == 0) { red[wv] = s; red[4 + wv] = ss; }
    __syncthreads();
    if (threadIdx.x == 0) {
        float S  = red[0] + red[1] + red[2] + red[3];
        float SS = red[4] + red[5] + red[6] + red[7];
        float mu  = S / N;
        float var = SS / N - mu * mu;
        float istd = rsqrtf(var + 1e-5f);
        scale[c] = gamma[c] * istd;
        shift[c] = beta[c] - mu * gamma[c] * istd;
    }
}

__global__ void bn_apply(const float* __restrict__ x, const float* __restrict__ scale,
                         const float* __restrict__ shift, float* __restrict__ y, int total) {
    int i = blockIdx.x * 256 + threadIdx.x;
    if (i < total) {
        int c = i & 63;
        y[i] = fmaxf(x[i] * scale[c] + shift[c], 0.f);
    }
}

// ------------------------------------------------------------------ MHA (flash)
// thread = one query, head = blockIdx.z, key-split = blockIdx.y
__global__ void mha_attn(const float* __restrict__ q, const float* __restrict__ kg,
                         const float* __restrict__ vg, float* __restrict__ part,
                         int N, int nsplit) {
    const int H = 4;
    __shared__ float Ks[128][16];
    __shared__ float Vs[128][16];
    int h = blockIdx.z;
    int sp = blockIdx.y;
    int qi = blockIdx.x * 256 + threadIdx.x;
    int chunk = (N + nsplit - 1) / nsplit;
    int beg = sp * chunk, end = min(N, beg + chunk);
    float qr[16];
    #pragma unroll
    for (int d = 0; d < 16; ++d) qr[d] = q[(size_t)qi * 64 + h * 16 + d] * 0.25f;
    float m = -1e30f, denom = 0.f, acc[16];
    #pragma unroll
    for (int d = 0; d < 16; ++d) acc[d] = 0.f;
    for (int kb = beg; kb < end; kb += 128) {
        int cnt = min(128, end - kb);
        __syncthreads();
        {
            int r  = threadIdx.x >> 1;
            int d8 = (threadIdx.x & 1) * 8;
            if (r < cnt) {
                const float* kp = kg + (size_t)(kb + r) * 64 + h * 16 + d8;
                const float* vp = vg + (size_t)(kb + r) * 64 + h * 16 + d8;
                #pragma unroll
                for (int j = 0; j < 8; ++j) { Ks[r][d8 + j] = kp[j]; Vs[r][d8 + j] = vp[j]; }
            }
        }
        __syncthreads();
        for (int kk = 0; kk < cnt; ++kk) {
            float dot = 0.f;
            #pragma unroll
            for (int d = 0; d < 16; ++d) dot += qr[d] * Ks[kk][d];
            if (dot > m) {
                float corr = __expf(m - dot);
                denom *= corr;
                #pragma unroll
                for (int d = 0; d < 16; ++d) acc[d] *= corr;
                m = dot;
            }
            float w = __expf(dot - m);
            denom += w;
            #pragma unroll
            for (int d = 0; d < 16; ++d) acc[d] += w * Vs[kk][d];
        }
    }
    float* p = part + ((size_t)(sp * N + qi) * H + h) * 18;
    p[0] = m; p[1] = denom;
    #pragma unroll
    for (int d = 0; d < 16; ++d) p[2 + d] = acc[d];
}

__global__ void mha_merge(const float* __restrict__ part, float* __restrict__ out,
                          int N, int nsplit) {
    const int H = 4;
    int idx = blockIdx.x * 256 + threadIdx.x;
    if (idx >= N * H) return;
    int qi = idx / H, h = idx % H;
    float M = -1e30f;
    for (int s = 0; s < nsplit; ++s)
        M = fmaxf(M, part[((size_t)(s * N + qi) * H + h) * 18]);
    float den = 0.f, num[16];
    #pragma unroll
    for (int d = 0; d < 16; ++d) num[d] = 0.f;
    for (int s = 0; s < nsplit; ++s) {
        const float* p = part + ((size_t)(s * N + qi) * H + h) * 18;
        float sc = __expf(p[0] - M);
        den += p[1] * sc;
        #pragma unroll
        for (int d = 0; d < 16; ++d) num[d] += p[2 + d] * sc;
    }
    float inv = 1.f / den;
    #pragma unroll
    for (int d = 0; d < 16; ++d) out[(size_t)qi * 64 + h * 16 + d] = num[d] * inv;
}

// ------------------------------------------------------------------- host side
static inline void launch_gemm(const float* A, const float* B, const float* bias, float* C,
                               int M, int Nc, int K, bool transB, int act, hipStream_t st) {
    dim3 grid((Nc + 63) / 64, M / 64), blk(256);
    if (!transB)       gemm_f32<false, 0><<<grid, blk, 0, st>>>(A, B, bias, C, M, Nc, K);
    else if (act == 0) gemm_f32<true, 0><<<grid, blk, 0, st>>>(A, B, bias, C, M, Nc, K);
    else               gemm_f32<true, 1><<<grid, blk, 0, st>>>(A, B, bias, C, M, Nc, K);
}

extern "C" void kernel_launch(void* const* d_in, const int* in_sizes, int n_in,
                              void* d_out, int out_size, void* d_ws, size_t ws_size,
                              hipStream_t stream) {
    const int N = NN, E = EE;
    const float* x    = (const float*)d_in[0];
    const int*   ei   = (const int*)d_in[1];
    const float* W[3]   = {(const float*)d_in[2], (const float*)d_in[6], (const float*)d_in[10]};
    const float* as_[3] = {(const float*)d_in[3], (const float*)d_in[7], (const float*)d_in[11]};
    const float* ad_[3] = {(const float*)d_in[4], (const float*)d_in[8], (const float*)d_in[12]};
    const float* bn_g = (const float*)d_in[14];
    const float* bn_b = (const float*)d_in[15];
    const float* Wq = (const float*)d_in[16];
    const float* Wk = (const float*)d_in[17];
    const float* Wv = (const float*)d_in[18];
    const float* Wo = (const float*)d_in[19];
    const float* bq = (const float*)d_in[20];
    const float* bk = (const float*)d_in[21];
    const float* bv = (const float*)d_in[22];
    const float* bo = (const float*)d_in[23];
    const float* Wc1 = (const float*)d_in[24];
    const float* bc1 = (const float*)d_in[25];
    const float* Wc2 = (const float*)d_in[26];
    const float* bc2 = (const float*)d_in[27];

    char* ws = (char*)d_ws;
    float* h    = (float*)(ws + 0);            // 8192*512*4 = 16,777,216
    float* part = h;                           // reused during MHA (6*8192*4*18*4 = 14.2 MB)
    float* a_s  = (float*)(ws + 16777216);     // 262,144
    float* a_d  = (float*)(ws + 17039360);     // 262,144
    int* row_ptr = (int*)(ws + 17301504);      // 33,024 (8193 ints, padded)
    int* cursor  = (int*)(ws + 17334528);      // 32,768
    int* deg     = (int*)(ws + 17367296);      // 32,768
    int* col     = (int*)(ws + 17400064);      // 1,081,344
    float* xg   = (float*)(ws + 18481408);     // 2,097,152
    float* xb   = (float*)(ws + 20578560);     // 2,097,152
    float* qb   = (float*)(ws + 22675712);     // 2,097,152
    float* kbuf = (float*)(ws + 24772864);     // 2,097,152
    float* vbuf = (float*)(ws + 26870016);     // 2,097,152
    float* ao   = (float*)(ws + 28967168);     // 2,097,152
    float* c1   = (float*)(ws + 31064320);     // 1,048,576
    float* bnscale = (float*)(ws + 32112896);  // 64
    float* bnshift = bnscale + 64;             // 64

    // ---- CSR build (same graph all layers); self-loops via deg init = 1
    k_fill_i32<<<(N + 255) / 256, 256, 0, stream>>>(deg, 1, N);
    count_deg<<<(E + 255) / 256, 256, 0, stream>>>(ei, deg, E);
    scan_deg<<<1, 1024, 0, stream>>>(deg, row_ptr, cursor, N);
    fill_csr<<<(E + N + 255) / 256, 256, 0, stream>>>(ei, cursor, col, E, N);

    // ---- 3 GAT layers (+BN+ReLU).  GAT bias cancels through BN -> skipped.
    const int heads[3] = {8, 8, 1};
    const int fins[3]  = {128, 64, 64};
    const float* xin = x;
    for (int i = 0; i < 3; ++i) {
        int H = heads[i], K = fins[i];
        launch_gemm(xin, W[i], nullptr, h, N, H * 64, K, false, 0, stream);
        gat_coef<<<(N * H) / 4, 256, 0, stream>>>(h, as_[i], ad_[i], a_s, a_d, N, H);
        hipMemsetAsync(xg, 0, (size_t)N * 64 * 4, stream);
        gat_gather<<<(N * H) / 4, 256, 0, stream>>>(h, a_s, a_d, row_ptr, col, xg, N, H);
        bn_stats<<<64, 256, 0, stream>>>(xg, bn_g + i * 64, bn_b + i * 64, bnscale, bnshift, N);
        bn_apply<<<(N * 64) / 256, 256, 0, stream>>>(xg, bnscale, bnshift, xb, N * 64);
        xin = xb;
    }

    // ---- MHA (4 heads, hd=16), flash-style with 6 key splits
    launch_gemm(xb, Wq, bq, qb,   N, 64, 64, true, 0, stream);
    launch_gemm(xb, Wk, bk, kbuf, N, 64, 64, true, 0, stream);
    launch_gemm(xb, Wv, bv, vbuf, N, 64, 64, true, 0, stream);
    const int NSPLIT = 6;
    mha_attn<<<dim3(N / 256, NSPLIT, 4), 256, 0, stream>>>(qb, kbuf, vbuf, part, N, NSPLIT);
    mha_merge<<<(N * 4 + 255) / 256, 256, 0, stream>>>(part, ao, N, NSPLIT);
    launch_gemm(ao, Wo, bo, xg, N, 64, 64, true, 0, stream);   // xg = attn output

    // ---- classifier
    launch_gemm(xg, Wc1, bc1, c1, N, 32, 64, true, 1, stream);
    launch_gemm(c1, Wc2, bc2, (float*)d_out, N, 10, 32, true, 0, stream);
}

// Round 3
// 771.448 us; speedup vs baseline: 1.1014x; 1.1014x over previous
//
#include <hip/hip_runtime.h>
#include <hip/hip_bf16.h>

#define NN 8192
#define EE 262144
#define HID 64

typedef _Float16 half4_t __attribute__((ext_vector_type(4)));
typedef float f32x4 __attribute__((ext_vector_type(4)));

// ---------------------------------------------------------------- GEMM (f32)
// C[M,Nc] = A[M,K] @ B(+bias)(+relu).  TRANS_B: B stored [Nc,K].
template<bool TRANS_B, int ACT>
__global__ void gemm_f32(const float* __restrict__ A, const float* __restrict__ B,
                         const float* __restrict__ bias, float* __restrict__ C,
                         int M, int Nc, int K) {
    __shared__ float As[16][65];
    __shared__ float Bs[16][65];
    int tid = threadIdx.x;
    int brow = blockIdx.y * 64, bcol = blockIdx.x * 64;
    int tr = (tid / 16) * 4;
    int tc = (tid % 16) * 4;
    float acc[4][4] = {};
    for (int k0 = 0; k0 < K; k0 += 16) {
        {   // A tile 64x16
            int r  = tid / 4;
            int kk = (tid % 4) * 4;
            const float* a = A + (size_t)(brow + r) * K + k0 + kk;
            #pragma unroll
            for (int j = 0; j < 4; ++j) As[kk + j][r] = a[j];
        }
        if (!TRANS_B) {   // B[K][Nc]
            int kk = tid / 16;
            int n4 = (tid % 16) * 4;
            #pragma unroll
            for (int j = 0; j < 4; ++j) {
                int n = bcol + n4 + j;
                Bs[kk][n4 + j] = (n < Nc) ? B[(size_t)(k0 + kk) * Nc + n] : 0.f;
            }
        } else {          // B[Nc][K]
            int n  = tid / 4;
            int kk = (tid % 4) * 4;
            #pragma unroll
            for (int j = 0; j < 4; ++j)
                Bs[kk + j][n] = (bcol + n < Nc) ? B[(size_t)(bcol + n) * K + k0 + kk + j] : 0.f;
        }
        __syncthreads();
        #pragma unroll
        for (int kk = 0; kk < 16; ++kk) {
            float av[4], bv[4];
            #pragma unroll
            for (int i = 0; i < 4; ++i) av[i] = As[kk][tr + i];
            #pragma unroll
            for (int j = 0; j < 4; ++j) bv[j] = Bs[kk][tc + j];
            #pragma unroll
            for (int i = 0; i < 4; ++i)
                #pragma unroll
                for (int j = 0; j < 4; ++j)
                    acc[i][j] += av[i] * bv[j];
        }
        __syncthreads();
    }
    #pragma unroll
    for (int i = 0; i < 4; ++i) {
        int r = brow + tr + i;
        #pragma unroll
        for (int j = 0; j < 4; ++j) {
            int c = bcol + tc + j;
            if (c < Nc) {
                float v = acc[i][j];
                if (bias) v += bias[c];
                if (ACT == 1) v = fmaxf(v, 0.f);
                C[(size_t)r * Nc + c] = v;
            }
        }
    }
}

// ------------------------------------------------------------------ GAT prep
__global__ void k_fill_i32(int* p, int v, int n) {
    int i = blockIdx.x * 256 + threadIdx.x;
    if (i < n) p[i] = v;
}

__global__ void count_deg(const int* __restrict__ ei, int* __restrict__ deg, int E) {
    int e = blockIdx.x * 256 + threadIdx.x;
    if (e < E) atomicAdd(&deg[ei[E + e]], 1);   // ei[1] row = dst
}

// single block, 1024 threads, N=8192 (8 per thread)
__global__ void scan_deg(const int* __restrict__ deg, int* __restrict__ row_ptr,
                         int* __restrict__ cursor, int N) {
    __shared__ int tmp[1024];
    int tid = threadIdx.x;
    int base = tid * 8;
    int local[8];
    int s = 0;
    #pragma unroll
    for (int j = 0; j < 8; ++j) { local[j] = deg[base + j]; s += local[j]; }
    tmp[tid] = s;
    __syncthreads();
    for (int off = 1; off < 1024; off <<= 1) {
        int add = (tid >= off) ? tmp[tid - off] : 0;
        __syncthreads();
        tmp[tid] += add;
        __syncthreads();
    }
    int run = tmp[tid] - s;   // exclusive prefix of this chunk
    #pragma unroll
    for (int j = 0; j < 8; ++j) {
        row_ptr[base + j] = run;
        cursor[base + j]  = run;
        run += local[j];
    }
    if (tid == 1023) row_ptr[N] = run;
}

__global__ void fill_csr(const int* __restrict__ ei, int* __restrict__ cursor,
                         int* __restrict__ col, int E, int N) {
    int e = blockIdx.x * 256 + threadIdx.x;
    if (e < E) {
        int dst = ei[E + e];
        int pos = atomicAdd(&cursor[dst], 1);
        col[pos] = ei[e];
    } else if (e < E + N) {
        int n = e - E;
        int pos = atomicAdd(&cursor[n], 1);
        col[pos] = n;
    }
}

// ---------------------------------------------------------------- GAT kernels
// a_s[n,h] = sum_c h[n,h,c]*att_s[h,c]  (wave per (n,h), lane per channel)
__global__ void gat_coef(const float* __restrict__ h, const float* __restrict__ att_s,
                         const float* __restrict__ att_d, float* __restrict__ a_s,
                         float* __restrict__ a_d, int N, int H) {
    int wid  = (blockIdx.x * 256 + threadIdx.x) >> 6;
    int lane = threadIdx.x & 63;
    if (wid >= N * H) return;
    int hh = wid % H;
    float v = h[(size_t)wid * 64 + lane];
    float s = v * att_s[hh * 64 + lane];
    float d = v * att_d[hh * 64 + lane];
    #pragma unroll
    for (int off = 32; off; off >>= 1) {
        s += __shfl_down(s, off);
        d += __shfl_down(d, off);
    }
    if (lane == 0) { a_s[wid] = s; a_d[wid] = d; }
}

// wave per destination node n; loops over heads; NO atomics, f64 accumulation
// (fmax is order-independent; double add makes edge-order noise ~1e-16).
__global__ void gat_gather2(const float* __restrict__ h, const float* __restrict__ a_s,
                            const float* __restrict__ a_d, const int* __restrict__ row_ptr,
                            const int* __restrict__ col, float* __restrict__ out,
                            int N, int H) {
    int n    = (blockIdx.x * 256 + threadIdx.x) >> 6;
    int lane = threadIdx.x & 63;
    if (n >= N) return;
    int beg = row_ptr[n], end = row_ptr[n + 1];
    float res = 0.f;
    for (int hh = 0; hh < H; ++hh) {
        float adn = a_d[n * H + hh];
        // pass 1: max score (exactly order-independent)
        float m = -1e30f;
        for (int j = beg + lane; j < end; j += 64) {
            float sc = a_s[col[j] * H + hh] + adn;
            sc = sc > 0.f ? sc : 0.2f * sc;
            m = fmaxf(m, sc);
        }
        #pragma unroll
        for (int off = 32; off; off >>= 1) m = fmaxf(m, __shfl_xor(m, off));
        // pass 2: exp weights + gather (lane = channel), double accumulation
        double acc = 0.0, denom = 0.0;
        for (int base = beg; base < end; base += 64) {
            int j = base + lane;
            float w = 0.f; int s = 0;
            if (j < end) {
                s = col[j];
                float sc = a_s[s * H + hh] + adn;
                sc = sc > 0.f ? sc : 0.2f * sc;
                w = __expf(sc - m);
            }
            denom += (double)w;
            int cnt = min(64, end - base);
            for (int k = 0; k < cnt; ++k) {
                float wk = __shfl(w, k);
                int   sk = __shfl(s, k);
                acc += (double)(wk * h[(size_t)sk * (H * 64) + hh * 64 + lane]);
            }
        }
        #pragma unroll
        for (int off = 32; off; off >>= 1) denom += __shfl_xor(denom, off);
        res += (float)(acc / ((denom + 1e-16) * H));
    }
    out[(size_t)n * 64 + lane] = res;
}

// ------------------------------------------------------------------ BatchNorm
__global__ void bn_stats(const float* __restrict__ x, const float* __restrict__ gamma,
                         const float* __restrict__ beta, float* __restrict__ scale,
                         float* __restrict__ shift, int N) {
    int c = blockIdx.x;
    float s = 0.f, ss = 0.f;
    for (int r = threadIdx.x; r < N; r += 256) {
        float v = x[(size_t)r * 64 + c];
        s += v; ss += v * v;
    }
    #pragma unroll
    for (int off = 32; off; off >>= 1) {
        s  += __shfl_xor(s, off);
        ss += __shfl_xor(ss, off);
    }
    __shared__ float red[8];
    int wv = threadIdx.x >> 6, ln = threadIdx.x & 63;
    if (ln == 0) { red[wv] = s; red[4 + wv] = ss; }
    __syncthreads();
    if (threadIdx.x == 0) {
        float S  = red[0] + red[1] + red[2] + red[3];
        float SS = red[4] + red[5] + red[6] + red[7];
        float mu  = S / N;
        float var = SS / N - mu * mu;
        float istd = rsqrtf(var + 1e-5f);
        scale[c] = gamma[c] * istd;
        shift[c] = beta[c] - mu * gamma[c] * istd;
    }
}

__global__ void bn_apply(const float* __restrict__ x, const float* __restrict__ scale,
                         const float* __restrict__ shift, float* __restrict__ y, int total) {
    int i = blockIdx.x * 256 + threadIdx.x;
    if (i < total) {
        int c = i & 63;
        y[i] = fmaxf(x[i] * scale[c] + shift[c], 0.f);
    }
}

// ------------------------------------------------------------------ MHA (MFMA fp16 flash)
__global__ void to_f16_qkv(const float* __restrict__ q, const float* __restrict__ k,
                           const float* __restrict__ v, _Float16* __restrict__ qh,
                           _Float16* __restrict__ kh, _Float16* __restrict__ vh, int total) {
    int i = blockIdx.x * 256 + threadIdx.x;
    if (i < total) {
        qh[i] = (_Float16)(q[i] * 0.25f);   // fold 1/sqrt(hd) into Q
        kh[i] = (_Float16)k[i];
        vh[i] = (_Float16)v[i];
    }
}

// wave = 16 queries of one head, ALL keys (no split, no partials):
//   S^T[key x q] = mfma(K_frag, Q_frag)   (D: col=q=lane&15, row=key=4*(lane>>4)+reg)
//   O^T[d x q]  += mfma(V^T_frag, P^T_frag)  -- P^T feeds B directly from S^T's D layout
// Writes normalized output straight to ao. Fully deterministic.
__global__ void mha_fa1(const _Float16* __restrict__ qh, const _Float16* __restrict__ kh,
                        const _Float16* __restrict__ vh, float* __restrict__ ao, int N) {
    int h    = blockIdx.y;
    int wave = threadIdx.x >> 6;
    int lane = threadIdx.x & 63;
    int lo16 = lane & 15;
    int g    = lane >> 4;
    int q    = (blockIdx.x * 4 + wave) * 16 + lo16;

    // Q fragment (B operand of QK^T): lane holds Q[q][4g..4g+3]
    half4_t qf = *(const half4_t*)(qh + (size_t)q * 64 + h * 16 + g * 4);

    float m = -1e30f, l = 0.f;
    f32x4 o = {0.f, 0.f, 0.f, 0.f};
    const f32x4 zero = {0.f, 0.f, 0.f, 0.f};

    for (int k0 = 0; k0 < N; k0 += 16) {
        // K fragment (A operand): lane holds K[k0+lo16][4g..4g+3] -- one 8B load
        half4_t kf = *(const half4_t*)(kh + (size_t)(k0 + lo16) * 64 + h * 16 + g * 4);
        // V^T fragment (A operand of PV): lane holds V[k0+4g+i][d=lo16]
        half4_t vf;
        #pragma unroll
        for (int i = 0; i < 4; ++i)
            vf[i] = vh[(size_t)(k0 + g * 4 + i) * 64 + h * 16 + lo16];

        f32x4 s = __builtin_amdgcn_mfma_f32_16x16x16f16(kf, qf, zero, 0, 0, 0);
        // lane: scores of query lo16 for keys k0+4g+{0..3}
        float tm = fmaxf(fmaxf(s[0], s[1]), fmaxf(s[2], s[3]));
        tm = fmaxf(tm, __shfl_xor(tm, 16));
        tm = fmaxf(tm, __shfl_xor(tm, 32));
        float mnew = fmaxf(m, tm);
        float r = __expf(m - mnew);
        float p0 = __expf(s[0] - mnew);
        float p1 = __expf(s[1] - mnew);
        float p2 = __expf(s[2] - mnew);
        float p3 = __expf(s[3] - mnew);
        l = l * r + ((p0 + p1) + (p2 + p3));
        m = mnew;
        half4_t pf;
        pf[0] = (_Float16)p0; pf[1] = (_Float16)p1;
        pf[2] = (_Float16)p2; pf[3] = (_Float16)p3;
        #pragma unroll
        for (int i = 0; i < 4; ++i) o[i] *= r;   // O^T col = q = lo16 -> lane-local rescale
        o = __builtin_amdgcn_mfma_f32_16x16x16f16(vf, pf, o, 0, 0, 0);
    }
    // l partials are per lane-group (disjoint key subsets); sum the 4 groups
    l += __shfl_xor(l, 16);
    l += __shfl_xor(l, 32);
    float inv = 1.f / l;
    f32x4 res;
    #pragma unroll
    for (int i = 0; i < 4; ++i) res[i] = o[i] * inv;   // res[i] = O[q][4g+i]
    *(f32x4*)(ao + (size_t)q * 64 + h * 16 + g * 4) = res;
}

// ------------------------------------------------------------------- host side
static inline void launch_gemm(const float* A, const float* B, const float* bias, float* C,
                               int M, int Nc, int K, bool transB, int act, hipStream_t st) {
    dim3 grid((Nc + 63) / 64, M / 64), blk(256);
    if (!transB)       gemm_f32<false, 0><<<grid, blk, 0, st>>>(A, B, bias, C, M, Nc, K);
    else if (act == 0) gemm_f32<true, 0><<<grid, blk, 0, st>>>(A, B, bias, C, M, Nc, K);
    else               gemm_f32<true, 1><<<grid, blk, 0, st>>>(A, B, bias, C, M, Nc, K);
}

extern "C" void kernel_launch(void* const* d_in, const int* in_sizes, int n_in,
                              void* d_out, int out_size, void* d_ws, size_t ws_size,
                              hipStream_t stream) {
    const int N = NN, E = EE;
    const float* x    = (const float*)d_in[0];
    const int*   ei   = (const int*)d_in[1];
    const float* W[3]   = {(const float*)d_in[2], (const float*)d_in[6], (const float*)d_in[10]};
    const float* as_[3] = {(const float*)d_in[3], (const float*)d_in[7], (const float*)d_in[11]};
    const float* ad_[3] = {(const float*)d_in[4], (const float*)d_in[8], (const float*)d_in[12]};
    const float* bn_g = (const float*)d_in[14];
    const float* bn_b = (const float*)d_in[15];
    const float* Wq = (const float*)d_in[16];
    const float* Wk = (const float*)d_in[17];
    const float* Wv = (const float*)d_in[18];
    const float* Wo = (const float*)d_in[19];
    const float* bq = (const float*)d_in[20];
    const float* bk = (const float*)d_in[21];
    const float* bv = (const float*)d_in[22];
    const float* bo = (const float*)d_in[23];
    const float* Wc1 = (const float*)d_in[24];
    const float* bc1 = (const float*)d_in[25];
    const float* Wc2 = (const float*)d_in[26];
    const float* bc2 = (const float*)d_in[27];

    char* ws = (char*)d_ws;
    float* h    = (float*)(ws + 0);            // 8192*512*4 = 16,777,216 (GAT phase)
    _Float16* qh = (_Float16*)(ws + 6291456);  // 1,048,576 (MHA phase, reuses h region tail)
    _Float16* kh = (_Float16*)(ws + 7340032);  // 1,048,576
    _Float16* vh = (_Float16*)(ws + 8388608);  // 1,048,576
    float* a_s  = (float*)(ws + 16777216);     // 262,144
    float* a_d  = (float*)(ws + 17039360);     // 262,144
    int* row_ptr = (int*)(ws + 17301504);      // 33,024 (8193 ints, padded)
    int* cursor  = (int*)(ws + 17334528);      // 32,768
    int* deg     = (int*)(ws + 17367296);      // 32,768
    int* col     = (int*)(ws + 17400064);      // 1,081,344
    float* xg   = (float*)(ws + 18481408);     // 2,097,152
    float* xb   = (float*)(ws + 20578560);     // 2,097,152
    float* qb   = (float*)(ws + 22675712);     // 2,097,152
    float* kbuf = (float*)(ws + 24772864);     // 2,097,152
    float* vbuf = (float*)(ws + 26870016);     // 2,097,152
    float* ao   = (float*)(ws + 28967168);     // 2,097,152
    float* c1   = (float*)(ws + 31064320);     // 1,048,576
    float* bnscale = (float*)(ws + 32112896);  // 64
    float* bnshift = bnscale + 64;             // 64

    // ---- CSR build (same graph all layers); self-loops via deg init = 1
    k_fill_i32<<<(N + 255) / 256, 256, 0, stream>>>(deg, 1, N);
    count_deg<<<(E + 255) / 256, 256, 0, stream>>>(ei, deg, E);
    scan_deg<<<1, 1024, 0, stream>>>(deg, row_ptr, cursor, N);
    fill_csr<<<(E + N + 255) / 256, 256, 0, stream>>>(ei, cursor, col, E, N);

    // ---- 3 GAT layers (+BN+ReLU).  GAT bias cancels through BN -> skipped.
    const int heads[3] = {8, 8, 1};
    const int fins[3]  = {128, 64, 64};
    const float* xin = x;
    for (int i = 0; i < 3; ++i) {
        int H = heads[i], K = fins[i];
        launch_gemm(xin, W[i], nullptr, h, N, H * 64, K, false, 0, stream);
        gat_coef<<<(N * H) / 4, 256, 0, stream>>>(h, as_[i], ad_[i], a_s, a_d, N, H);
        gat_gather2<<<N / 4, 256, 0, stream>>>(h, a_s, a_d, row_ptr, col, xg, N, H);
        bn_stats<<<64, 256, 0, stream>>>(xg, bn_g + i * 64, bn_b + i * 64, bnscale, bnshift, N);
        bn_apply<<<(N * 64) / 256, 256, 0, stream>>>(xg, bnscale, bnshift, xb, N * 64);
        xin = xb;
    }

    // ---- MHA (4 heads, hd=16), MFMA fp16 flash, single pass (no partials)
    launch_gemm(xb, Wq, bq, qb,   N, 64, 64, true, 0, stream);
    launch_gemm(xb, Wk, bk, kbuf, N, 64, 64, true, 0, stream);
    launch_gemm(xb, Wv, bv, vbuf, N, 64, 64, true, 0, stream);
    to_f16_qkv<<<(N * 64) / 256, 256, 0, stream>>>(qb, kbuf, vbuf, qh, kh, vh, N * 64);
    mha_fa1<<<dim3(N / 64, 4), 256, 0, stream>>>(qh, kh, vh, ao, N);
    launch_gemm(ao, Wo, bo, xg, N, 64, 64, true, 0, stream);   // xg = attn output

    // ---- classifier
    launch_gemm(xg, Wc1, bc1, c1, N, 32, 64, true, 1, stream);
    launch_gemm(c1, Wc2, bc2, (float*)d_out, N, 10, 32, true, 0, stream);
}

// Round 4
// 665.919 us; speedup vs baseline: 1.2760x; 1.1585x over previous
//
#include <hip/hip_runtime.h>
#include <hip/hip_bf16.h>

#define NN 8192
#define EE 262144
#define HID 64

typedef _Float16 half4_t __attribute__((ext_vector_type(4)));
typedef _Float16 half8_t __attribute__((ext_vector_type(8)));
typedef float f32x4 __attribute__((ext_vector_type(4)));

// ---------------------------------------------------------------- GEMM (f32, small Nc)
template<bool TRANS_B, int ACT>
__global__ void gemm_f32(const float* __restrict__ A, const float* __restrict__ B,
                         const float* __restrict__ bias, float* __restrict__ C,
                         int M, int Nc, int K) {
    __shared__ float As[16][65];
    __shared__ float Bs[16][65];
    int tid = threadIdx.x;
    int brow = blockIdx.y * 64, bcol = blockIdx.x * 64;
    int tr = (tid / 16) * 4;
    int tc = (tid % 16) * 4;
    float acc[4][4] = {};
    for (int k0 = 0; k0 < K; k0 += 16) {
        {   // A tile 64x16
            int r  = tid / 4;
            int kk = (tid % 4) * 4;
            const float* a = A + (size_t)(brow + r) * K + k0 + kk;
            #pragma unroll
            for (int j = 0; j < 4; ++j) As[kk + j][r] = a[j];
        }
        if (!TRANS_B) {   // B[K][Nc]
            int kk = tid / 16;
            int n4 = (tid % 16) * 4;
            #pragma unroll
            for (int j = 0; j < 4; ++j) {
                int n = bcol + n4 + j;
                Bs[kk][n4 + j] = (n < Nc) ? B[(size_t)(k0 + kk) * Nc + n] : 0.f;
            }
        } else {          // B[Nc][K]
            int n  = tid / 4;
            int kk = (tid % 4) * 4;
            #pragma unroll
            for (int j = 0; j < 4; ++j)
                Bs[kk + j][n] = (bcol + n < Nc) ? B[(size_t)(bcol + n) * K + k0 + kk + j] : 0.f;
        }
        __syncthreads();
        #pragma unroll
        for (int kk = 0; kk < 16; ++kk) {
            float av[4], bv[4];
            #pragma unroll
            for (int i = 0; i < 4; ++i) av[i] = As[kk][tr + i];
            #pragma unroll
            for (int j = 0; j < 4; ++j) bv[j] = Bs[kk][tc + j];
            #pragma unroll
            for (int i = 0; i < 4; ++i)
                #pragma unroll
                for (int j = 0; j < 4; ++j)
                    acc[i][j] += av[i] * bv[j];
        }
        __syncthreads();
    }
    #pragma unroll
    for (int i = 0; i < 4; ++i) {
        int r = brow + tr + i;
        #pragma unroll
        for (int j = 0; j < 4; ++j) {
            int c = bcol + tc + j;
            if (c < Nc) {
                float v = acc[i][j];
                if (bias) v += bias[c];
                if (ACT == 1) v = fmaxf(v, 0.f);
                C[(size_t)r * Nc + c] = v;
            }
        }
    }
}

// ---------------------------------------------------------------- GEMM (MFMA f16 in, f32 acc)
// C[M,Nc] = (A[M,K] @ B)*scale (+bias applied before scale). Nc, M multiples of 64; K of 32.
// Fragment conventions identical to the (verified) attention kernel:
//   mfma(X,Y,C): D[r][c] = sum_k X[r][k]*Y[c][k];  X/Y frag: lane holds [lane&15][4*(lane>>4)+i]
//   D frag: lane holds D[4*(lane>>4)+reg][lane&15]
template<bool TRANS_B, bool OUT_F16, int ACT>
__global__ void mfma_gemm(const float* __restrict__ A, const float* __restrict__ B,
                          const float* __restrict__ bias, void* __restrict__ Cout,
                          int M, int Nc, int K, float scale) {
    __shared__ _Float16 Ah[64][36];
    __shared__ _Float16 Bt[64][36];
    int tid  = threadIdx.x;
    int wave = tid >> 6, lane = tid & 63, lo16 = lane & 15, g = lane >> 4;
    int brow = blockIdx.y * 64, bcol = blockIdx.x * 64;
    f32x4 acc[4];
    #pragma unroll
    for (int i = 0; i < 4; ++i) acc[i] = (f32x4){0.f, 0.f, 0.f, 0.f};

    for (int k0 = 0; k0 < K; k0 += 32) {
        {   // stage A 64x32 -> f16
            int r  = tid >> 2;
            int ks = (tid & 3) * 8;
            const float* ap = A + (size_t)(brow + r) * K + k0 + ks;
            f32x4 a0 = *(const f32x4*)ap;
            f32x4 a1 = *(const f32x4*)(ap + 4);
            half4_t h0, h1;
            #pragma unroll
            for (int i = 0; i < 4; ++i) { h0[i] = (_Float16)a0[i]; h1[i] = (_Float16)a1[i]; }
            *(half4_t*)&Ah[r][ks]     = h0;
            *(half4_t*)&Ah[r][ks + 4] = h1;
        }
        if (TRANS_B) {   // B[Nc][K] -> Bt[n][k]
            int n  = tid >> 2;
            int ks = (tid & 3) * 8;
            const float* bp = B + (size_t)(bcol + n) * K + k0 + ks;
            f32x4 b0 = *(const f32x4*)bp;
            f32x4 b1 = *(const f32x4*)(bp + 4);
            half4_t h0, h1;
            #pragma unroll
            for (int i = 0; i < 4; ++i) { h0[i] = (_Float16)b0[i]; h1[i] = (_Float16)b1[i]; }
            *(half4_t*)&Bt[n][ks]     = h0;
            *(half4_t*)&Bt[n][ks + 4] = h1;
        } else {         // B[K][Nc] -> Bt[n][k] (transpose during staging, coalesced reads)
            int n  = tid & 63;
            int kb = (tid >> 6) * 8;
            half4_t h0, h1;
            #pragma unroll
            for (int i = 0; i < 4; ++i)
                h0[i] = (_Float16)B[(size_t)(k0 + kb + i) * Nc + bcol + n];
            #pragma unroll
            for (int i = 0; i < 4; ++i)
                h1[i] = (_Float16)B[(size_t)(k0 + kb + 4 + i) * Nc + bcol + n];
            *(half4_t*)&Bt[n][kb]     = h0;
            *(half4_t*)&Bt[n][kb + 4] = h1;
        }
        __syncthreads();
        #pragma unroll
        for (int kh = 0; kh < 2; ++kh) {
            half4_t af = *(const half4_t*)&Ah[wave * 16 + lo16][kh * 16 + g * 4];
            #pragma unroll
            for (int cf = 0; cf < 4; ++cf) {
                half4_t bf = *(const half4_t*)&Bt[cf * 16 + lo16][kh * 16 + g * 4];
                acc[cf] = __builtin_amdgcn_mfma_f32_16x16x16f16(af, bf, acc[cf], 0, 0, 0);
            }
        }
        __syncthreads();
    }
    int rbase = brow + wave * 16 + g * 4;
    #pragma unroll
    for (int cf = 0; cf < 4; ++cf) {
        int c = bcol + cf * 16 + lo16;
        float bv = bias ? bias[c] : 0.f;
        #pragma unroll
        for (int reg = 0; reg < 4; ++reg) {
            float v = (acc[cf][reg] + bv) * scale;
            if (ACT == 1) v = fmaxf(v, 0.f);
            if (OUT_F16) ((_Float16*)Cout)[(size_t)(rbase + reg) * Nc + c] = (_Float16)v;
            else         ((float*)Cout)[(size_t)(rbase + reg) * Nc + c] = v;
        }
    }
}

// ------------------------------------------------------------------ GAT prep
__global__ void k_fill_i32(int* p, int v, int n) {
    int i = blockIdx.x * 256 + threadIdx.x;
    if (i < n) p[i] = v;
}

__global__ void count_deg(const int* __restrict__ ei, int* __restrict__ deg, int E) {
    int e = blockIdx.x * 256 + threadIdx.x;
    if (e < E) atomicAdd(&deg[ei[E + e]], 1);   // ei[1] row = dst
}

// single block, 1024 threads, N=8192 (8 per thread)
__global__ void scan_deg(const int* __restrict__ deg, int* __restrict__ row_ptr,
                         int* __restrict__ cursor, int N) {
    __shared__ int tmp[1024];
    int tid = threadIdx.x;
    int base = tid * 8;
    int local[8];
    int s = 0;
    #pragma unroll
    for (int j = 0; j < 8; ++j) { local[j] = deg[base + j]; s += local[j]; }
    tmp[tid] = s;
    __syncthreads();
    for (int off = 1; off < 1024; off <<= 1) {
        int add = (tid >= off) ? tmp[tid - off] : 0;
        __syncthreads();
        tmp[tid] += add;
        __syncthreads();
    }
    int run = tmp[tid] - s;   // exclusive prefix of this chunk
    #pragma unroll
    for (int j = 0; j < 8; ++j) {
        row_ptr[base + j] = run;
        cursor[base + j]  = run;
        run += local[j];
    }
    if (tid == 1023) row_ptr[N] = run;
}

__global__ void fill_csr(const int* __restrict__ ei, int* __restrict__ cursor,
                         int* __restrict__ col, int E, int N) {
    int e = blockIdx.x * 256 + threadIdx.x;
    if (e < E) {
        int dst = ei[E + e];
        int pos = atomicAdd(&cursor[dst], 1);
        col[pos] = ei[e];
    } else if (e < E + N) {
        int n = e - E;
        int pos = atomicAdd(&cursor[n], 1);
        col[pos] = n;
    }
}

// ---------------------------------------------------------------- GAT kernels
__global__ void gat_coef(const float* __restrict__ h, const float* __restrict__ att_s,
                         const float* __restrict__ att_d, float* __restrict__ a_s,
                         float* __restrict__ a_d, int N, int H) {
    int wid  = (blockIdx.x * 256 + threadIdx.x) >> 6;
    int lane = threadIdx.x & 63;
    if (wid >= N * H) return;
    int hh = wid % H;
    float v = h[(size_t)wid * 64 + lane];
    float s = v * att_s[hh * 64 + lane];
    float d = v * att_d[hh * 64 + lane];
    #pragma unroll
    for (int off = 32; off; off >>= 1) {
        s += __shfl_down(s, off);
        d += __shfl_down(d, off);
    }
    if (lane == 0) { a_s[wid] = s; a_d[wid] = d; }
}

// wave per (dst n, head h): segment softmax + weighted gather; atomicAdd head mean
// (round-1 proven version: atomic order noise ~1e-6, post-timing-safe)
__global__ void gat_gather(const float* __restrict__ h, const float* __restrict__ a_s,
                           const float* __restrict__ a_d, const int* __restrict__ row_ptr,
                           const int* __restrict__ col, float* __restrict__ out,
                           int N, int H) {
    int wid  = (blockIdx.x * 256 + threadIdx.x) >> 6;
    int lane = threadIdx.x & 63;
    if (wid >= N * H) return;
    int n = wid / H, hh = wid % H;
    int beg = row_ptr[n], end = row_ptr[n + 1];
    float adn = a_d[n * H + hh];
    // pass 1: max score
    float m = -1e30f;
    for (int j = beg + lane; j < end; j += 64) {
        float sc = a_s[col[j] * H + hh] + adn;
        sc = sc > 0.f ? sc : 0.2f * sc;
        m = fmaxf(m, sc);
    }
    #pragma unroll
    for (int off = 32; off; off >>= 1) m = fmaxf(m, __shfl_xor(m, off));
    // pass 2: exp weights + gather (lane = channel)
    float acc = 0.f, denom = 0.f;
    for (int base = beg; base < end; base += 64) {
        int j = base + lane;
        float w = 0.f; int s = 0;
        if (j < end) {
            s = col[j];
            float sc = a_s[s * H + hh] + adn;
            sc = sc > 0.f ? sc : 0.2f * sc;
            w = __expf(sc - m);
        }
        denom += w;
        int cnt = min(64, end - base);
        for (int k = 0; k < cnt; ++k) {
            float wk = __shfl(w, k);
            int   sk = __shfl(s, k);
            acc += wk * h[(size_t)sk * (H * 64) + hh * 64 + lane];
        }
    }
    #pragma unroll
    for (int off = 32; off; off >>= 1) denom += __shfl_xor(denom, off);
    atomicAdd(&out[n * 64 + lane], acc / ((denom + 1e-16f) * H));
}

// ------------------------------------------------------------------ BatchNorm
__global__ void bn_stats(const float* __restrict__ x, const float* __restrict__ gamma,
                         const float* __restrict__ beta, float* __restrict__ scale,
                         float* __restrict__ shift, int N) {
    int c = blockIdx.x;
    float s = 0.f, ss = 0.f;
    for (int r = threadIdx.x; r < N; r += 256) {
        float v = x[(size_t)r * 64 + c];
        s += v; ss += v * v;
    }
    #pragma unroll
    for (int off = 32; off; off >>= 1) {
        s  += __shfl_xor(s, off);
        ss += __shfl_xor(ss, off);
    }
    __shared__ float red[8];
    int wv = threadIdx.x >> 6, ln = threadIdx.x & 63;
    if (ln == 0) { red[wv] = s; red[4 + wv] = ss; }
    __syncthreads();
    if (threadIdx.x == 0) {
        float S  = red[0] + red[1] + red[2] + red[3];
        float SS = red[4] + red[5] + red[6] + red[7];
        float mu  = S / N;
        float var = SS / N - mu * mu;
        float istd = rsqrtf(var + 1e-5f);
        scale[c] = gamma[c] * istd;
        shift[c] = beta[c] - mu * gamma[c] * istd;
    }
}

__global__ void bn_apply(const float* __restrict__ x, const float* __restrict__ scale,
                         const float* __restrict__ shift, float* __restrict__ y, int total) {
    int i = blockIdx.x * 256 + threadIdx.x;
    if (i < total) {
        int c = i & 63;
        y[i] = fmaxf(x[i] * scale[c] + shift[c], 0.f);
    }
}

// ------------------------------------------------------------------ MHA
// vh [N][64] f16 -> vt [64][N] f16 (row c = h*16+d), LDS-tiled transpose
__global__ void vtrans(const _Float16* __restrict__ vh, _Float16* __restrict__ vt, int N) {
    __shared__ _Float16 tile[64][68];
    int kb = blockIdx.x * 64;
    int t  = threadIdx.x;
    {
        int r = t >> 2, c0 = (t & 3) * 16;
        half8_t x0 = *(const half8_t*)(vh + (size_t)(kb + r) * 64 + c0);
        half8_t x1 = *(const half8_t*)(vh + (size_t)(kb + r) * 64 + c0 + 8);
        #pragma unroll
        for (int i = 0; i < 8; ++i) { tile[r][c0 + i] = x0[i]; tile[r][c0 + 8 + i] = x1[i]; }
    }
    __syncthreads();
    {
        int c = t >> 2, ks = (t & 3) * 16;
        half8_t y0, y1;
        #pragma unroll
        for (int i = 0; i < 8; ++i) { y0[i] = tile[ks + i][c]; y1[i] = tile[ks + 8 + i][c]; }
        *(half8_t*)(vt + (size_t)c * N + kb + ks)     = y0;
        *(half8_t*)(vt + (size_t)c * N + kb + ks + 8) = y1;
    }
}

// wave = 16 queries of one head, all keys, 32 keys/iter with depth-1 register prefetch.
__global__ void mha_fa2(const _Float16* __restrict__ qh, const _Float16* __restrict__ kh,
                        const _Float16* __restrict__ vt, float* __restrict__ ao, int N) {
    int h    = blockIdx.y;
    int wave = threadIdx.x >> 6;
    int lane = threadIdx.x & 63;
    int lo16 = lane & 15;
    int g    = lane >> 4;
    int q    = (blockIdx.x * 4 + wave) * 16 + lo16;

    half4_t qf = *(const half4_t*)(qh + (size_t)q * 64 + h * 16 + g * 4);
    const _Float16* kp = kh + h * 16 + g * 4;                 // + key*64
    const _Float16* vp = vt + ((size_t)(h * 16 + lo16)) * N;  // + key

    float m = -1e30f, l = 0.f;
    f32x4 o = {0.f, 0.f, 0.f, 0.f};
    const f32x4 zero = {0.f, 0.f, 0.f, 0.f};

    half4_t kA = *(const half4_t*)(kp + (size_t)lo16 * 64);
    half4_t kB = *(const half4_t*)(kp + (size_t)(16 + lo16) * 64);
    half4_t vA = *(const half4_t*)(vp + g * 4);
    half4_t vB = *(const half4_t*)(vp + 16 + g * 4);

    for (int k0 = 0; k0 < N; k0 += 32) {
        int kn = (k0 + 32 < N) ? k0 + 32 : 0;   // wrap on last iter (values unused)
        half4_t kA2 = *(const half4_t*)(kp + (size_t)(kn + lo16) * 64);
        half4_t kB2 = *(const half4_t*)(kp + (size_t)(kn + 16 + lo16) * 64);
        half4_t vA2 = *(const half4_t*)(vp + kn + g * 4);
        half4_t vB2 = *(const half4_t*)(vp + kn + 16 + g * 4);

        f32x4 s0 = __builtin_amdgcn_mfma_f32_16x16x16f16(kA, qf, zero, 0, 0, 0);
        f32x4 s1 = __builtin_amdgcn_mfma_f32_16x16x16f16(kB, qf, zero, 0, 0, 0);
        // lane holds scores of query lo16 for keys k0+4g+{0..3} (s0) and k0+16+4g+{0..3} (s1)
        float tm = fmaxf(fmaxf(fmaxf(s0[0], s0[1]), fmaxf(s0[2], s0[3])),
                         fmaxf(fmaxf(s1[0], s1[1]), fmaxf(s1[2], s1[3])));
        tm = fmaxf(tm, __shfl_xor(tm, 16));
        tm = fmaxf(tm, __shfl_xor(tm, 32));
        float mnew = fmaxf(m, tm);
        float r = __expf(m - mnew);
        float p0 = __expf(s0[0] - mnew), p1 = __expf(s0[1] - mnew);
        float p2 = __expf(s0[2] - mnew), p3 = __expf(s0[3] - mnew);
        float p4 = __expf(s1[0] - mnew), p5 = __expf(s1[1] - mnew);
        float p6 = __expf(s1[2] - mnew), p7 = __expf(s1[3] - mnew);
        l = l * r + (((p0 + p1) + (p2 + p3)) + ((p4 + p5) + (p6 + p7)));
        m = mnew;
        half4_t pf0, pf1;
        pf0[0] = (_Float16)p0; pf0[1] = (_Float16)p1; pf0[2] = (_Float16)p2; pf0[3] = (_Float16)p3;
        pf1[0] = (_Float16)p4; pf1[1] = (_Float16)p5; pf1[2] = (_Float16)p6; pf1[3] = (_Float16)p7;
        #pragma unroll
        for (int i = 0; i < 4; ++i) o[i] *= r;
        o = __builtin_amdgcn_mfma_f32_16x16x16f16(vA, pf0, o, 0, 0, 0);
        o = __builtin_amdgcn_mfma_f32_16x16x16f16(vB, pf1, o, 0, 0, 0);
        kA = kA2; kB = kB2; vA = vA2; vB = vB2;
    }
    // sum l across the 4 lane-groups (disjoint key subsets)
    l += __shfl_xor(l, 16);
    l += __shfl_xor(l, 32);
    float inv = 1.f / l;
    f32x4 res;
    #pragma unroll
    for (int i = 0; i < 4; ++i) res[i] = o[i] * inv;   // res[i] = O[q][h*16+4g+i]
    *(f32x4*)(ao + (size_t)q * 64 + h * 16 + g * 4) = res;
}

// ------------------------------------------------------------------- host side
static inline void launch_gemm(const float* A, const float* B, const float* bias, float* C,
                               int M, int Nc, int K, bool transB, int act, hipStream_t st) {
    dim3 grid((Nc + 63) / 64, M / 64), blk(256);
    if (!transB)       gemm_f32<false, 0><<<grid, blk, 0, st>>>(A, B, bias, C, M, Nc, K);
    else if (act == 0) gemm_f32<true, 0><<<grid, blk, 0, st>>>(A, B, bias, C, M, Nc, K);
    else               gemm_f32<true, 1><<<grid, blk, 0, st>>>(A, B, bias, C, M, Nc, K);
}

extern "C" void kernel_launch(void* const* d_in, const int* in_sizes, int n_in,
                              void* d_out, int out_size, void* d_ws, size_t ws_size,
                              hipStream_t stream) {
    const int N = NN, E = EE;
    const float* x    = (const float*)d_in[0];
    const int*   ei   = (const int*)d_in[1];
    const float* W[3]   = {(const float*)d_in[2], (const float*)d_in[6], (const float*)d_in[10]};
    const float* as_[3] = {(const float*)d_in[3], (const float*)d_in[7], (const float*)d_in[11]};
    const float* ad_[3] = {(const float*)d_in[4], (const float*)d_in[8], (const float*)d_in[12]};
    const float* bn_g = (const float*)d_in[14];
    const float* bn_b = (const float*)d_in[15];
    const float* Wq = (const float*)d_in[16];
    const float* Wk = (const float*)d_in[17];
    const float* Wv = (const float*)d_in[18];
    const float* Wo = (const float*)d_in[19];
    const float* bq = (const float*)d_in[20];
    const float* bk = (const float*)d_in[21];
    const float* bv = (const float*)d_in[22];
    const float* bo = (const float*)d_in[23];
    const float* Wc1 = (const float*)d_in[24];
    const float* bc1 = (const float*)d_in[25];
    const float* Wc2 = (const float*)d_in[26];
    const float* bc2 = (const float*)d_in[27];

    char* ws = (char*)d_ws;
    float* h    = (float*)(ws + 0);            // 8192*512*4 = 16,777,216 (GAT phase)
    _Float16* qh = (_Float16*)(ws + 6291456);  // 1,048,576 (MHA phase, inside dead-h region)
    _Float16* kh = (_Float16*)(ws + 7340032);  // 1,048,576
    _Float16* vh = (_Float16*)(ws + 8388608);  // 1,048,576
    _Float16* vt = (_Float16*)(ws + 9437184);  // 1,048,576
    float* a_s  = (float*)(ws + 16777216);     // 262,144
    float* a_d  = (float*)(ws + 17039360);     // 262,144
    int* row_ptr = (int*)(ws + 17301504);      // 33,024 (8193 ints, padded)
    int* cursor  = (int*)(ws + 17334528);      // 32,768
    int* deg     = (int*)(ws + 17367296);      // 32,768
    int* col     = (int*)(ws + 17400064);      // 1,081,344
    float* xg   = (float*)(ws + 18481408);     // 2,097,152
    float* xb   = (float*)(ws + 20578560);     // 2,097,152
    float* ao   = (float*)(ws + 28967168);     // 2,097,152
    float* c1   = (float*)(ws + 31064320);     // 1,048,576
    float* bnscale = (float*)(ws + 32112896);  // 64
    float* bnshift = bnscale + 64;             // 64

    // ---- CSR build (same graph all layers); self-loops via deg init = 1
    k_fill_i32<<<(N + 255) / 256, 256, 0, stream>>>(deg, 1, N);
    count_deg<<<(E + 255) / 256, 256, 0, stream>>>(ei, deg, E);
    scan_deg<<<1, 1024, 0, stream>>>(deg, row_ptr, cursor, N);
    fill_csr<<<(E + N + 255) / 256, 256, 0, stream>>>(ei, cursor, col, E, N);

    // ---- 3 GAT layers (+BN+ReLU).  GAT bias cancels through BN -> skipped.
    const int heads[3] = {8, 8, 1};
    const int fins[3]  = {128, 64, 64};
    const float* xin = x;
    for (int i = 0; i < 3; ++i) {
        int H = heads[i], K = fins[i];
        mfma_gemm<false, false, 0><<<dim3(H, N / 64), 256, 0, stream>>>(
            xin, W[i], nullptr, h, N, H * 64, K, 1.f);
        gat_coef<<<(N * H) / 4, 256, 0, stream>>>(h, as_[i], ad_[i], a_s, a_d, N, H);
        hipMemsetAsync(xg, 0, (size_t)N * 64 * 4, stream);
        gat_gather<<<(N * H) / 4, 256, 0, stream>>>(h, a_s, a_d, row_ptr, col, xg, N, H);
        bn_stats<<<64, 256, 0, stream>>>(xg, bn_g + i * 64, bn_b + i * 64, bnscale, bnshift, N);
        bn_apply<<<(N * 64) / 256, 256, 0, stream>>>(xg, bnscale, bnshift, xb, N * 64);
        xin = xb;
    }

    // ---- MHA (4 heads, hd=16): f16 Q/K/V straight from MFMA GEMM, flash single-pass
    mfma_gemm<true, true, 0><<<dim3(1, N / 64), 256, 0, stream>>>(xb, Wq, bq, qh, N, 64, 64, 0.25f);
    mfma_gemm<true, true, 0><<<dim3(1, N / 64), 256, 0, stream>>>(xb, Wk, bk, kh, N, 64, 64, 1.f);
    mfma_gemm<true, true, 0><<<dim3(1, N / 64), 256, 0, stream>>>(xb, Wv, bv, vh, N, 64, 64, 1.f);
    vtrans<<<N / 64, 256, 0, stream>>>(vh, vt, N);
    mha_fa2<<<dim3(N / 64, 4), 256, 0, stream>>>(qh, kh, vt, ao, N);
    mfma_gemm<true, false, 0><<<dim3(1, N / 64), 256, 0, stream>>>(ao, Wo, bo, xg, N, 64, 64, 1.f);

    // ---- classifier (small Nc: f32 path)
    launch_gemm(xg, Wc1, bc1, c1, N, 32, 64, true, 1, stream);
    launch_gemm(c1, Wc2, bc2, (float*)d_out, N, 10, 32, true, 0, stream);
}

// Round 5
// 545.756 us; speedup vs baseline: 1.5569x; 1.2202x over previous
//
#include <hip/hip_runtime.h>
#include <hip/hip_bf16.h>

#define NN 8192
#define EE 262144
#define HID 64

typedef _Float16 half4_t __attribute__((ext_vector_type(4)));
typedef _Float16 half8_t __attribute__((ext_vector_type(8)));
typedef float f32x4 __attribute__((ext_vector_type(4)));

// ---------------------------------------------------------------- GEMM (f32, small Nc)
template<bool TRANS_B, int ACT>
__global__ void gemm_f32(const float* __restrict__ A, const float* __restrict__ B,
                         const float* __restrict__ bias, float* __restrict__ C,
                         int M, int Nc, int K) {
    __shared__ float As[16][65];
    __shared__ float Bs[16][65];
    int tid = threadIdx.x;
    int brow = blockIdx.y * 64, bcol = blockIdx.x * 64;
    int tr = (tid / 16) * 4;
    int tc = (tid % 16) * 4;
    float acc[4][4] = {};
    for (int k0 = 0; k0 < K; k0 += 16) {
        {   // A tile 64x16
            int r  = tid / 4;
            int kk = (tid % 4) * 4;
            const float* a = A + (size_t)(brow + r) * K + k0 + kk;
            #pragma unroll
            for (int j = 0; j < 4; ++j) As[kk + j][r] = a[j];
        }
        if (!TRANS_B) {   // B[K][Nc]
            int kk = tid / 16;
            int n4 = (tid % 16) * 4;
            #pragma unroll
            for (int j = 0; j < 4; ++j) {
                int n = bcol + n4 + j;
                Bs[kk][n4 + j] = (n < Nc) ? B[(size_t)(k0 + kk) * Nc + n] : 0.f;
            }
        } else {          // B[Nc][K]
            int n  = tid / 4;
            int kk = (tid % 4) * 4;
            #pragma unroll
            for (int j = 0; j < 4; ++j)
                Bs[kk + j][n] = (bcol + n < Nc) ? B[(size_t)(bcol + n) * K + k0 + kk + j] : 0.f;
        }
        __syncthreads();
        #pragma unroll
        for (int kk = 0; kk < 16; ++kk) {
            float av[4], bv[4];
            #pragma unroll
            for (int i = 0; i < 4; ++i) av[i] = As[kk][tr + i];
            #pragma unroll
            for (int j = 0; j < 4; ++j) bv[j] = Bs[kk][tc + j];
            #pragma unroll
            for (int i = 0; i < 4; ++i)
                #pragma unroll
                for (int j = 0; j < 4; ++j)
                    acc[i][j] += av[i] * bv[j];
        }
        __syncthreads();
    }
    #pragma unroll
    for (int i = 0; i < 4; ++i) {
        int r = brow + tr + i;
        #pragma unroll
        for (int j = 0; j < 4; ++j) {
            int c = bcol + tc + j;
            if (c < Nc) {
                float v = acc[i][j];
                if (bias) v += bias[c];
                if (ACT == 1) v = fmaxf(v, 0.f);
                C[(size_t)r * Nc + c] = v;
            }
        }
    }
}

// ---------------------------------------------------------------- GEMM (MFMA f16 in, f32 acc)
template<bool TRANS_B, bool OUT_F16, int ACT>
__global__ void mfma_gemm(const float* __restrict__ A, const float* __restrict__ B,
                          const float* __restrict__ bias, void* __restrict__ Cout,
                          int M, int Nc, int K, float scale) {
    __shared__ _Float16 Ah[64][36];
    __shared__ _Float16 Bt[64][36];
    int tid  = threadIdx.x;
    int wave = tid >> 6, lane = tid & 63, lo16 = lane & 15, g = lane >> 4;
    int brow = blockIdx.y * 64, bcol = blockIdx.x * 64;
    f32x4 acc[4];
    #pragma unroll
    for (int i = 0; i < 4; ++i) acc[i] = (f32x4){0.f, 0.f, 0.f, 0.f};

    for (int k0 = 0; k0 < K; k0 += 32) {
        {   // stage A 64x32 -> f16
            int r  = tid >> 2;
            int ks = (tid & 3) * 8;
            const float* ap = A + (size_t)(brow + r) * K + k0 + ks;
            f32x4 a0 = *(const f32x4*)ap;
            f32x4 a1 = *(const f32x4*)(ap + 4);
            half4_t h0, h1;
            #pragma unroll
            for (int i = 0; i < 4; ++i) { h0[i] = (_Float16)a0[i]; h1[i] = (_Float16)a1[i]; }
            *(half4_t*)&Ah[r][ks]     = h0;
            *(half4_t*)&Ah[r][ks + 4] = h1;
        }
        if (TRANS_B) {   // B[Nc][K] -> Bt[n][k]
            int n  = tid >> 2;
            int ks = (tid & 3) * 8;
            const float* bp = B + (size_t)(bcol + n) * K + k0 + ks;
            f32x4 b0 = *(const f32x4*)bp;
            f32x4 b1 = *(const f32x4*)(bp + 4);
            half4_t h0, h1;
            #pragma unroll
            for (int i = 0; i < 4; ++i) { h0[i] = (_Float16)b0[i]; h1[i] = (_Float16)b1[i]; }
            *(half4_t*)&Bt[n][ks]     = h0;
            *(half4_t*)&Bt[n][ks + 4] = h1;
        } else {         // B[K][Nc] -> Bt[n][k] (transpose during staging)
            int n  = tid & 63;
            int kb = (tid >> 6) * 8;
            half4_t h0, h1;
            #pragma unroll
            for (int i = 0; i < 4; ++i)
                h0[i] = (_Float16)B[(size_t)(k0 + kb + i) * Nc + bcol + n];
            #pragma unroll
            for (int i = 0; i < 4; ++i)
                h1[i] = (_Float16)B[(size_t)(k0 + kb + 4 + i) * Nc + bcol + n];
            *(half4_t*)&Bt[n][kb]     = h0;
            *(half4_t*)&Bt[n][kb + 4] = h1;
        }
        __syncthreads();
        #pragma unroll
        for (int kh = 0; kh < 2; ++kh) {
            half4_t af = *(const half4_t*)&Ah[wave * 16 + lo16][kh * 16 + g * 4];
            #pragma unroll
            for (int cf = 0; cf < 4; ++cf) {
                half4_t bf = *(const half4_t*)&Bt[cf * 16 + lo16][kh * 16 + g * 4];
                acc[cf] = __builtin_amdgcn_mfma_f32_16x16x16f16(af, bf, acc[cf], 0, 0, 0);
            }
        }
        __syncthreads();
    }
    int rbase = brow + wave * 16 + g * 4;
    #pragma unroll
    for (int cf = 0; cf < 4; ++cf) {
        int c = bcol + cf * 16 + lo16;
        float bv = bias ? bias[c] : 0.f;
        #pragma unroll
        for (int reg = 0; reg < 4; ++reg) {
            float v = (acc[cf][reg] + bv) * scale;
            if (ACT == 1) v = fmaxf(v, 0.f);
            if (OUT_F16) ((_Float16*)Cout)[(size_t)(rbase + reg) * Nc + c] = (_Float16)v;
            else         ((float*)Cout)[(size_t)(rbase + reg) * Nc + c] = v;
        }
    }
}

// ------------------------------------------------------------------ GAT prep
__global__ void k_fill_i32(int* p, int v, int n) {
    int i = blockIdx.x * 256 + threadIdx.x;
    if (i < n) p[i] = v;
}

__global__ void count_deg(const int* __restrict__ ei, int* __restrict__ deg, int E) {
    int e = blockIdx.x * 256 + threadIdx.x;
    if (e < E) atomicAdd(&deg[ei[E + e]], 1);   // ei[1] row = dst
}

__global__ void scan_deg(const int* __restrict__ deg, int* __restrict__ row_ptr,
                         int* __restrict__ cursor, int N) {
    __shared__ int tmp[1024];
    int tid = threadIdx.x;
    int base = tid * 8;
    int local[8];
    int s = 0;
    #pragma unroll
    for (int j = 0; j < 8; ++j) { local[j] = deg[base + j]; s += local[j]; }
    tmp[tid] = s;
    __syncthreads();
    for (int off = 1; off < 1024; off <<= 1) {
        int add = (tid >= off) ? tmp[tid - off] : 0;
        __syncthreads();
        tmp[tid] += add;
        __syncthreads();
    }
    int run = tmp[tid] - s;   // exclusive prefix of this chunk
    #pragma unroll
    for (int j = 0; j < 8; ++j) {
        row_ptr[base + j] = run;
        cursor[base + j]  = run;
        run += local[j];
    }
    if (tid == 1023) row_ptr[N] = run;
}

__global__ void fill_csr(const int* __restrict__ ei, int* __restrict__ cursor,
                         int* __restrict__ col, int E, int N) {
    int e = blockIdx.x * 256 + threadIdx.x;
    if (e < E) {
        int dst = ei[E + e];
        int pos = atomicAdd(&cursor[dst], 1);
        col[pos] = ei[e];
    } else if (e < E + N) {
        int n = e - E;
        int pos = atomicAdd(&cursor[n], 1);
        col[pos] = n;
    }
}

// ---------------------------------------------------------------- GAT kernels
__global__ void gat_coef(const float* __restrict__ h, const float* __restrict__ att_s,
                         const float* __restrict__ att_d, float* __restrict__ a_s,
                         float* __restrict__ a_d, int N, int H) {
    int wid  = (blockIdx.x * 256 + threadIdx.x) >> 6;
    int lane = threadIdx.x & 63;
    if (wid >= N * H) return;
    int hh = wid % H;
    float v = h[(size_t)wid * 64 + lane];
    float s = v * att_s[hh * 64 + lane];
    float d = v * att_d[hh * 64 + lane];
    #pragma unroll
    for (int off = 32; off; off >>= 1) {
        s += __shfl_down(s, off);
        d += __shfl_down(d, off);
    }
    if (lane == 0) { a_s[wid] = s; a_d[wid] = d; }
}

// wave per (dst n, head h): segment softmax + weighted gather; atomicAdd head mean
__global__ void gat_gather(const float* __restrict__ h, const float* __restrict__ a_s,
                           const float* __restrict__ a_d, const int* __restrict__ row_ptr,
                           const int* __restrict__ col, float* __restrict__ out,
                           int N, int H) {
    int wid  = (blockIdx.x * 256 + threadIdx.x) >> 6;
    int lane = threadIdx.x & 63;
    if (wid >= N * H) return;
    int n = wid / H, hh = wid % H;
    int beg = row_ptr[n], end = row_ptr[n + 1];
    float adn = a_d[n * H + hh];
    float m = -1e30f;
    for (int j = beg + lane; j < end; j += 64) {
        float sc = a_s[col[j] * H + hh] + adn;
        sc = sc > 0.f ? sc : 0.2f * sc;
        m = fmaxf(m, sc);
    }
    #pragma unroll
    for (int off = 32; off; off >>= 1) m = fmaxf(m, __shfl_xor(m, off));
    float acc = 0.f, denom = 0.f;
    for (int base = beg; base < end; base += 64) {
        int j = base + lane;
        float w = 0.f; int s = 0;
        if (j < end) {
            s = col[j];
            float sc = a_s[s * H + hh] + adn;
            sc = sc > 0.f ? sc : 0.2f * sc;
            w = __expf(sc - m);
        }
        denom += w;
        int cnt = min(64, end - base);
        for (int k = 0; k < cnt; ++k) {
            float wk = __shfl(w, k);
            int   sk = __shfl(s, k);
            acc += wk * h[(size_t)sk * (H * 64) + hh * 64 + lane];
        }
    }
    #pragma unroll
    for (int off = 32; off; off >>= 1) denom += __shfl_xor(denom, off);
    atomicAdd(&out[n * 64 + lane], acc / ((denom + 1e-16f) * H));
}

// ------------------------------------------------------------------ BatchNorm
__global__ void bn_stats(const float* __restrict__ x, const float* __restrict__ gamma,
                         const float* __restrict__ beta, float* __restrict__ scale,
                         float* __restrict__ shift, int N) {
    int c = blockIdx.x;
    float s = 0.f, ss = 0.f;
    for (int r = threadIdx.x; r < N; r += 256) {
        float v = x[(size_t)r * 64 + c];
        s += v; ss += v * v;
    }
    #pragma unroll
    for (int off = 32; off; off >>= 1) {
        s  += __shfl_xor(s, off);
        ss += __shfl_xor(ss, off);
    }
    __shared__ float red[8];
    int wv = threadIdx.x >> 6, ln = threadIdx.x & 63;
    if (ln == 0) { red[wv] = s; red[4 + wv] = ss; }
    __syncthreads();
    if (threadIdx.x == 0) {
        float S  = red[0] + red[1] + red[2] + red[3];
        float SS = red[4] + red[5] + red[6] + red[7];
        float mu  = S / N;
        float var = SS / N - mu * mu;
        float istd = rsqrtf(var + 1e-5f);
        scale[c] = gamma[c] * istd;
        shift[c] = beta[c] - mu * gamma[c] * istd;
    }
}

__global__ void bn_apply(const float* __restrict__ x, const float* __restrict__ scale,
                         const float* __restrict__ shift, float* __restrict__ y, int total) {
    int i = blockIdx.x * 256 + threadIdx.x;
    if (i < total) {
        int c = i & 63;
        y[i] = fmaxf(x[i] * scale[c] + shift[c], 0.f);
    }
}

// ------------------------------------------------------------------ MHA
// vh [N][64] f16 -> vt [64][N] f16 (row = h*16+d), LDS-tiled transpose
__global__ void vtrans(const _Float16* __restrict__ vh, _Float16* __restrict__ vt, int N) {
    __shared__ _Float16 tile[64][68];
    int kb = blockIdx.x * 64;
    int t  = threadIdx.x;
    {
        int r = t >> 2, c0 = (t & 3) * 16;
        half8_t x0 = *(const half8_t*)(vh + (size_t)(kb + r) * 64 + c0);
        half8_t x1 = *(const half8_t*)(vh + (size_t)(kb + r) * 64 + c0 + 8);
        #pragma unroll
        for (int i = 0; i < 8; ++i) { tile[r][c0 + i] = x0[i]; tile[r][c0 + 8 + i] = x1[i]; }
    }
    __syncthreads();
    {
        int c = t >> 2, ks = (t & 3) * 16;
        half8_t y0, y1;
        #pragma unroll
        for (int i = 0; i < 8; ++i) { y0[i] = tile[ks + i][c]; y1[i] = tile[ks + 8 + i][c]; }
        *(half8_t*)(vt + (size_t)c * N + kb + ks)     = y0;
        *(half8_t*)(vt + (size_t)c * N + kb + ks + 8) = y1;
    }
}

// kh [N][64] f16 -> khp [4][N][16] f16 (head-major rows, 32B per key)
__global__ void kpack(const _Float16* __restrict__ kh, _Float16* __restrict__ khp, int N) {
    int id = blockIdx.x * 256 + threadIdx.x;   // N*8 threads
    int n = id >> 3, c8 = (id & 7) * 8;
    half8_t v = *(const half8_t*)(kh + (size_t)n * 64 + c8);
    int h = c8 >> 4, d0 = c8 & 15;
    *(half8_t*)(khp + ((size_t)h * N + n) * 16 + d0) = v;
}

// Block = 4 waves, one head, 64 queries. K/V tiles (64 keys) cooperatively staged
// in LDS, double-buffered; coalesced global loads from head-major khp / vt.
__global__ void mha_fa3(const _Float16* __restrict__ qh, const _Float16* __restrict__ khp,
                        const _Float16* __restrict__ vt, float* __restrict__ ao, int N) {
    __shared__ _Float16 Kt[2][64][20];   // [key][ch], pad 16->20
    __shared__ _Float16 Vt[2][16][68];   // [ch][key], pad 64->68
    int h    = blockIdx.y;
    int t    = threadIdx.x;
    int lane = t & 63;
    int wave = t >> 6;
    int lo16 = lane & 15;
    int g    = lane >> 4;
    int q    = blockIdx.x * 64 + wave * 16 + lo16;

    half4_t qf = *(const half4_t*)(qh + (size_t)q * 64 + h * 16 + g * 4);
    const _Float16* kp = khp + (size_t)h * N * 16;
    const _Float16* vp = vt + (size_t)h * 16 * N;

    int skey = t >> 2, sch = (t & 3) * 4;       // K staging coords (2KB contiguous)
    int sd = t >> 4, skv = (t & 15) * 4;        // V staging coords (16 x 128B rows)

    // stage tile 0
    *(half4_t*)&Kt[0][skey][sch] = *(const half4_t*)(kp + (size_t)skey * 16 + sch);
    *(half4_t*)&Vt[0][sd][skv]   = *(const half4_t*)(vp + (size_t)sd * N + skv);

    float m = -1e30f, l = 0.f;
    f32x4 o = {0.f, 0.f, 0.f, 0.f};
    const f32x4 zero = {0.f, 0.f, 0.f, 0.f};
    int nt = N / 64;

    for (int it = 0; it < nt; ++it) {
        int cur = it & 1;
        __syncthreads();   // staged data for tile `it` visible; prev reads done
        if (it + 1 < nt) {
            int kt = (it + 1) * 64;
            *(half4_t*)&Kt[cur ^ 1][skey][sch] = *(const half4_t*)(kp + (size_t)(kt + skey) * 16 + sch);
            *(half4_t*)&Vt[cur ^ 1][sd][skv]   = *(const half4_t*)(vp + (size_t)sd * N + kt + skv);
        }
        // ---- QK^T: 4 sub-tiles of 16 keys
        f32x4 s[4];
        #pragma unroll
        for (int st = 0; st < 4; ++st) {
            half4_t kf = *(const half4_t*)&Kt[cur][st * 16 + lo16][g * 4];
            s[st] = __builtin_amdgcn_mfma_f32_16x16x16f16(kf, qf, zero, 0, 0, 0);
        }
        // ---- online softmax over 64 keys
        float tm = -1e30f;
        #pragma unroll
        for (int st = 0; st < 4; ++st)
            tm = fmaxf(tm, fmaxf(fmaxf(s[st][0], s[st][1]), fmaxf(s[st][2], s[st][3])));
        tm = fmaxf(tm, __shfl_xor(tm, 16));
        tm = fmaxf(tm, __shfl_xor(tm, 32));
        float mnew = fmaxf(m, tm);
        float r = __expf(m - mnew);
        m = mnew;
        float lsum = 0.f;
        half4_t pf[4];
        #pragma unroll
        for (int st = 0; st < 4; ++st) {
            #pragma unroll
            for (int i = 0; i < 4; ++i) {
                float p = __expf(s[st][i] - mnew);
                lsum += p;
                pf[st][i] = (_Float16)p;
            }
        }
        l = l * r + lsum;
        #pragma unroll
        for (int i = 0; i < 4; ++i) o[i] *= r;   // O^T col = q -> lane-local rescale
        // ---- PV
        #pragma unroll
        for (int st = 0; st < 4; ++st) {
            half4_t vf = *(const half4_t*)&Vt[cur][lo16][st * 16 + g * 4];
            o = __builtin_amdgcn_mfma_f32_16x16x16f16(vf, pf[st], o, 0, 0, 0);
        }
    }
    // l partials: lane-group g covered keys {16st+4g+i} -- disjoint across g
    l += __shfl_xor(l, 16);
    l += __shfl_xor(l, 32);
    float inv = 1.f / l;
    f32x4 res;
    #pragma unroll
    for (int i = 0; i < 4; ++i) res[i] = o[i] * inv;   // res[i] = O[q][h*16+4g+i]
    *(f32x4*)(ao + (size_t)q * 64 + h * 16 + g * 4) = res;
}

// ------------------------------------------------------------------- host side
static inline void launch_gemm(const float* A, const float* B, const float* bias, float* C,
                               int M, int Nc, int K, bool transB, int act, hipStream_t st) {
    dim3 grid((Nc + 63) / 64, M / 64), blk(256);
    if (!transB)       gemm_f32<false, 0><<<grid, blk, 0, st>>>(A, B, bias, C, M, Nc, K);
    else if (act == 0) gemm_f32<true, 0><<<grid, blk, 0, st>>>(A, B, bias, C, M, Nc, K);
    else               gemm_f32<true, 1><<<grid, blk, 0, st>>>(A, B, bias, C, M, Nc, K);
}

extern "C" void kernel_launch(void* const* d_in, const int* in_sizes, int n_in,
                              void* d_out, int out_size, void* d_ws, size_t ws_size,
                              hipStream_t stream) {
    const int N = NN, E = EE;
    const float* x    = (const float*)d_in[0];
    const int*   ei   = (const int*)d_in[1];
    const float* W[3]   = {(const float*)d_in[2], (const float*)d_in[6], (const float*)d_in[10]};
    const float* as_[3] = {(const float*)d_in[3], (const float*)d_in[7], (const float*)d_in[11]};
    const float* ad_[3] = {(const float*)d_in[4], (const float*)d_in[8], (const float*)d_in[12]};
    const float* bn_g = (const float*)d_in[14];
    const float* bn_b = (const float*)d_in[15];
    const float* Wq = (const float*)d_in[16];
    const float* Wk = (const float*)d_in[17];
    const float* Wv = (const float*)d_in[18];
    const float* Wo = (const float*)d_in[19];
    const float* bq = (const float*)d_in[20];
    const float* bk = (const float*)d_in[21];
    const float* bv = (const float*)d_in[22];
    const float* bo = (const float*)d_in[23];
    const float* Wc1 = (const float*)d_in[24];
    const float* bc1 = (const float*)d_in[25];
    const float* Wc2 = (const float*)d_in[26];
    const float* bc2 = (const float*)d_in[27];

    char* ws = (char*)d_ws;
    float* h    = (float*)(ws + 0);            // 8192*512*4 = 16,777,216 (GAT phase)
    _Float16* qh = (_Float16*)(ws + 6291456);  // 1,048,576 (MHA phase, inside dead-h region)
    _Float16* kh = (_Float16*)(ws + 7340032);  // 1,048,576
    _Float16* vh = (_Float16*)(ws + 8388608);  // 1,048,576
    _Float16* vt = (_Float16*)(ws + 9437184);  // 1,048,576
    _Float16* khp = (_Float16*)(ws + 10485760); // 1,048,576
    float* a_s  = (float*)(ws + 16777216);     // 262,144
    float* a_d  = (float*)(ws + 17039360);     // 262,144
    int* row_ptr = (int*)(ws + 17301504);      // 33,024
    int* cursor  = (int*)(ws + 17334528);      // 32,768
    int* deg     = (int*)(ws + 17367296);      // 32,768
    int* col     = (int*)(ws + 17400064);      // 1,081,344
    float* xg   = (float*)(ws + 18481408);     // 2,097,152
    float* xb   = (float*)(ws + 20578560);     // 2,097,152
    float* ao   = (float*)(ws + 28967168);     // 2,097,152
    float* c1   = (float*)(ws + 31064320);     // 1,048,576
    float* bnscale = (float*)(ws + 32112896);  // 64
    float* bnshift = bnscale + 64;             // 64

    // ---- CSR build (same graph all layers); self-loops via deg init = 1
    k_fill_i32<<<(N + 255) / 256, 256, 0, stream>>>(deg, 1, N);
    count_deg<<<(E + 255) / 256, 256, 0, stream>>>(ei, deg, E);
    scan_deg<<<1, 1024, 0, stream>>>(deg, row_ptr, cursor, N);
    fill_csr<<<(E + N + 255) / 256, 256, 0, stream>>>(ei, cursor, col, E, N);

    // ---- 3 GAT layers (+BN+ReLU).  GAT bias cancels through BN -> skipped.
    const int heads[3] = {8, 8, 1};
    const int fins[3]  = {128, 64, 64};
    const float* xin = x;
    for (int i = 0; i < 3; ++i) {
        int H = heads[i], K = fins[i];
        mfma_gemm<false, false, 0><<<dim3(H, N / 64), 256, 0, stream>>>(
            xin, W[i], nullptr, h, N, H * 64, K, 1.f);
        gat_coef<<<(N * H) / 4, 256, 0, stream>>>(h, as_[i], ad_[i], a_s, a_d, N, H);
        hipMemsetAsync(xg, 0, (size_t)N * 64 * 4, stream);
        gat_gather<<<(N * H) / 4, 256, 0, stream>>>(h, a_s, a_d, row_ptr, col, xg, N, H);
        bn_stats<<<64, 256, 0, stream>>>(xg, bn_g + i * 64, bn_b + i * 64, bnscale, bnshift, N);
        bn_apply<<<(N * 64) / 256, 256, 0, stream>>>(xg, bnscale, bnshift, xb, N * 64);
        xin = xb;
    }

    // ---- MHA (4 heads, hd=16): f16 Q/K/V from MFMA GEMM; LDS-staged flash
    mfma_gemm<true, true, 0><<<dim3(1, N / 64), 256, 0, stream>>>(xb, Wq, bq, qh, N, 64, 64, 0.25f);
    mfma_gemm<true, true, 0><<<dim3(1, N / 64), 256, 0, stream>>>(xb, Wk, bk, kh, N, 64, 64, 1.f);
    mfma_gemm<true, true, 0><<<dim3(1, N / 64), 256, 0, stream>>>(xb, Wv, bv, vh, N, 64, 64, 1.f);
    vtrans<<<N / 64, 256, 0, stream>>>(vh, vt, N);
    kpack<<<N * 8 / 256, 256, 0, stream>>>(kh, khp, N);
    mha_fa3<<<dim3(N / 64, 4), 256, 0, stream>>>(qh, khp, vt, ao, N);
    mfma_gemm<true, false, 0><<<dim3(1, N / 64), 256, 0, stream>>>(ao, Wo, bo, xg, N, 64, 64, 1.f);

    // ---- classifier (small Nc: f32 path)
    launch_gemm(xg, Wc1, bc1, c1, N, 32, 64, true, 1, stream);
    launch_gemm(c1, Wc2, bc2, (float*)d_out, N, 10, 32, true, 0, stream);
}

// Round 6
// 412.435 us; speedup vs baseline: 2.0602x; 1.3233x over previous
//
#include <hip/hip_runtime.h>
#include <hip/hip_bf16.h>

#define NN 8192
#define EE 262144
#define HID 64

typedef _Float16 half4_t __attribute__((ext_vector_type(4)));
typedef _Float16 half8_t __attribute__((ext_vector_type(8)));
typedef float f32x4 __attribute__((ext_vector_type(4)));

// ---------------------------------------------------------------- GEMM (f32, small Nc)
template<bool TRANS_B, int ACT>
__global__ void gemm_f32(const float* __restrict__ A, const float* __restrict__ B,
                         const float* __restrict__ bias, float* __restrict__ C,
                         int M, int Nc, int K) {
    __shared__ float As[16][65];
    __shared__ float Bs[16][65];
    int tid = threadIdx.x;
    int brow = blockIdx.y * 64, bcol = blockIdx.x * 64;
    int tr = (tid / 16) * 4;
    int tc = (tid % 16) * 4;
    float acc[4][4] = {};
    for (int k0 = 0; k0 < K; k0 += 16) {
        {   // A tile 64x16
            int r  = tid / 4;
            int kk = (tid % 4) * 4;
            const float* a = A + (size_t)(brow + r) * K + k0 + kk;
            #pragma unroll
            for (int j = 0; j < 4; ++j) As[kk + j][r] = a[j];
        }
        if (!TRANS_B) {   // B[K][Nc]
            int kk = tid / 16;
            int n4 = (tid % 16) * 4;
            #pragma unroll
            for (int j = 0; j < 4; ++j) {
                int n = bcol + n4 + j;
                Bs[kk][n4 + j] = (n < Nc) ? B[(size_t)(k0 + kk) * Nc + n] : 0.f;
            }
        } else {          // B[Nc][K]
            int n  = tid / 4;
            int kk = (tid % 4) * 4;
            #pragma unroll
            for (int j = 0; j < 4; ++j)
                Bs[kk + j][n] = (bcol + n < Nc) ? B[(size_t)(bcol + n) * K + k0 + kk + j] : 0.f;
        }
        __syncthreads();
        #pragma unroll
        for (int kk = 0; kk < 16; ++kk) {
            float av[4], bv[4];
            #pragma unroll
            for (int i = 0; i < 4; ++i) av[i] = As[kk][tr + i];
            #pragma unroll
            for (int j = 0; j < 4; ++j) bv[j] = Bs[kk][tc + j];
            #pragma unroll
            for (int i = 0; i < 4; ++i)
                #pragma unroll
                for (int j = 0; j < 4; ++j)
                    acc[i][j] += av[i] * bv[j];
        }
        __syncthreads();
    }
    #pragma unroll
    for (int i = 0; i < 4; ++i) {
        int r = brow + tr + i;
        #pragma unroll
        for (int j = 0; j < 4; ++j) {
            int c = bcol + tc + j;
            if (c < Nc) {
                float v = acc[i][j];
                if (bias) v += bias[c];
                if (ACT == 1) v = fmaxf(v, 0.f);
                C[(size_t)r * Nc + c] = v;
            }
        }
    }
}

// ---------------------------------------------------------------- GEMM (MFMA f16 in, f32 acc)
template<bool TRANS_B, bool OUT_F16, int ACT>
__global__ void mfma_gemm(const float* __restrict__ A, const float* __restrict__ B,
                          const float* __restrict__ bias, void* __restrict__ Cout,
                          int M, int Nc, int K, float scale) {
    __shared__ _Float16 Ah[64][36];
    __shared__ _Float16 Bt[64][36];
    int tid  = threadIdx.x;
    int wave = tid >> 6, lane = tid & 63, lo16 = lane & 15, g = lane >> 4;
    int brow = blockIdx.y * 64, bcol = blockIdx.x * 64;
    f32x4 acc[4];
    #pragma unroll
    for (int i = 0; i < 4; ++i) acc[i] = (f32x4){0.f, 0.f, 0.f, 0.f};

    for (int k0 = 0; k0 < K; k0 += 32) {
        {   // stage A 64x32 -> f16
            int r  = tid >> 2;
            int ks = (tid & 3) * 8;
            const float* ap = A + (size_t)(brow + r) * K + k0 + ks;
            f32x4 a0 = *(const f32x4*)ap;
            f32x4 a1 = *(const f32x4*)(ap + 4);
            half4_t h0, h1;
            #pragma unroll
            for (int i = 0; i < 4; ++i) { h0[i] = (_Float16)a0[i]; h1[i] = (_Float16)a1[i]; }
            *(half4_t*)&Ah[r][ks]     = h0;
            *(half4_t*)&Ah[r][ks + 4] = h1;
        }
        if (TRANS_B) {   // B[Nc][K] -> Bt[n][k]
            int n  = tid >> 2;
            int ks = (tid & 3) * 8;
            const float* bp = B + (size_t)(bcol + n) * K + k0 + ks;
            f32x4 b0 = *(const f32x4*)bp;
            f32x4 b1 = *(const f32x4*)(bp + 4);
            half4_t h0, h1;
            #pragma unroll
            for (int i = 0; i < 4; ++i) { h0[i] = (_Float16)b0[i]; h1[i] = (_Float16)b1[i]; }
            *(half4_t*)&Bt[n][ks]     = h0;
            *(half4_t*)&Bt[n][ks + 4] = h1;
        } else {         // B[K][Nc] -> Bt[n][k] (transpose during staging)
            int n  = tid & 63;
            int kb = (tid >> 6) * 8;
            half4_t h0, h1;
            #pragma unroll
            for (int i = 0; i < 4; ++i)
                h0[i] = (_Float16)B[(size_t)(k0 + kb + i) * Nc + bcol + n];
            #pragma unroll
            for (int i = 0; i < 4; ++i)
                h1[i] = (_Float16)B[(size_t)(k0 + kb + 4 + i) * Nc + bcol + n];
            *(half4_t*)&Bt[n][kb]     = h0;
            *(half4_t*)&Bt[n][kb + 4] = h1;
        }
        __syncthreads();
        #pragma unroll
        for (int kh = 0; kh < 2; ++kh) {
            half4_t af = *(const half4_t*)&Ah[wave * 16 + lo16][kh * 16 + g * 4];
            #pragma unroll
            for (int cf = 0; cf < 4; ++cf) {
                half4_t bf = *(const half4_t*)&Bt[cf * 16 + lo16][kh * 16 + g * 4];
                acc[cf] = __builtin_amdgcn_mfma_f32_16x16x16f16(af, bf, acc[cf], 0, 0, 0);
            }
        }
        __syncthreads();
    }
    int rbase = brow + wave * 16 + g * 4;
    #pragma unroll
    for (int cf = 0; cf < 4; ++cf) {
        int c = bcol + cf * 16 + lo16;
        float bv = bias ? bias[c] : 0.f;
        #pragma unroll
        for (int reg = 0; reg < 4; ++reg) {
            float v = (acc[cf][reg] + bv) * scale;
            if (ACT == 1) v = fmaxf(v, 0.f);
            if (OUT_F16) ((_Float16*)Cout)[(size_t)(rbase + reg) * Nc + c] = (_Float16)v;
            else         ((float*)Cout)[(size_t)(rbase + reg) * Nc + c] = v;
        }
    }
}

// ------------------------------------------------------------------ GAT prep
__global__ void k_fill_i32(int* p, int v, int n) {
    int i = blockIdx.x * 256 + threadIdx.x;
    if (i < n) p[i] = v;
}

__global__ void count_deg(const int* __restrict__ ei, int* __restrict__ deg, int E) {
    int e = blockIdx.x * 256 + threadIdx.x;
    if (e < E) atomicAdd(&deg[ei[E + e]], 1);   // ei[1] row = dst
}

__global__ void scan_deg(const int* __restrict__ deg, int* __restrict__ row_ptr,
                         int* __restrict__ cursor, int N) {
    __shared__ int tmp[1024];
    int tid = threadIdx.x;
    int base = tid * 8;
    int local[8];
    int s = 0;
    #pragma unroll
    for (int j = 0; j < 8; ++j) { local[j] = deg[base + j]; s += local[j]; }
    tmp[tid] = s;
    __syncthreads();
    for (int off = 1; off < 1024; off <<= 1) {
        int add = (tid >= off) ? tmp[tid - off] : 0;
        __syncthreads();
        tmp[tid] += add;
        __syncthreads();
    }
    int run = tmp[tid] - s;   // exclusive prefix of this chunk
    #pragma unroll
    for (int j = 0; j < 8; ++j) {
        row_ptr[base + j] = run;
        cursor[base + j]  = run;
        run += local[j];
    }
    if (tid == 1023) row_ptr[N] = run;
}

__global__ void fill_csr(const int* __restrict__ ei, int* __restrict__ cursor,
                         int* __restrict__ col, int E, int N) {
    int e = blockIdx.x * 256 + threadIdx.x;
    if (e < E) {
        int dst = ei[E + e];
        int pos = atomicAdd(&cursor[dst], 1);
        col[pos] = ei[e];
    } else if (e < E + N) {
        int n = e - E;
        int pos = atomicAdd(&cursor[n], 1);
        col[pos] = n;
    }
}

// ---------------------------------------------------------------- GAT kernels
// h is f16 now: a_s[n,h] = sum_c h[n,h,c]*att_s[h,c]
__global__ void gat_coef(const _Float16* __restrict__ h, const float* __restrict__ att_s,
                         const float* __restrict__ att_d, float* __restrict__ a_s,
                         float* __restrict__ a_d, int N, int H) {
    int wid  = (blockIdx.x * 256 + threadIdx.x) >> 6;
    int lane = threadIdx.x & 63;
    if (wid >= N * H) return;
    int hh = wid % H;
    float v = (float)h[(size_t)wid * 64 + lane];
    float s = v * att_s[hh * 64 + lane];
    float d = v * att_d[hh * 64 + lane];
    #pragma unroll
    for (int off = 32; off; off >>= 1) {
        s += __shfl_down(s, off);
        d += __shfl_down(d, off);
    }
    if (lane == 0) { a_s[wid] = s; a_d[wid] = d; }
}

// wave per (dst n, head h). Per 64-edge chunk: each lane stashes its (w,col) pair
// in per-wave LDS; inner loop does uniform-address ds_read_b64 broadcasts (no
// shuffles), unrolled x4 with 4 independent FMA chains -> 4 gathers in flight.
// f16 h halves gather bytes. atomicAdd head-mean into out (order noise ~1e-6).
__global__ void gat_gather3(const _Float16* __restrict__ h, const float* __restrict__ a_s,
                            const float* __restrict__ a_d, const int* __restrict__ row_ptr,
                            const int* __restrict__ col, float* __restrict__ out,
                            int N, int H) {
    __shared__ uint2 wc[4][64];
    int t    = threadIdx.x;
    int wave = t >> 6;
    int lane = t & 63;
    int wid  = (blockIdx.x * 256 + t) >> 6;
    if (wid >= N * H) return;
    int n = wid / H, hh = wid % H;
    int beg = row_ptr[n], end = row_ptr[n + 1];
    float adn = a_d[n * H + hh];
    // pass 1: max score
    float m = -1e30f;
    for (int j = beg + lane; j < end; j += 64) {
        float sc = a_s[col[j] * H + hh] + adn;
        sc = sc > 0.f ? sc : 0.2f * sc;
        m = fmaxf(m, sc);
    }
    #pragma unroll
    for (int off = 32; off; off >>= 1) m = fmaxf(m, __shfl_xor(m, off));
    // pass 2: exp weights + broadcast gather
    const _Float16* hb = h + (size_t)hh * 64 + lane;
    const size_t rs = (size_t)H * 64;
    float denom = 0.f;
    float acc0 = 0.f, acc1 = 0.f, acc2 = 0.f, acc3 = 0.f;
    for (int base = beg; base < end; base += 64) {
        int j = base + lane;
        float w = 0.f; int s = 0;
        if (j < end) {
            s = col[j];
            float sc = a_s[s * H + hh] + adn;
            sc = sc > 0.f ? sc : 0.2f * sc;
            w = __expf(sc - m);
        }
        denom += w;
        uint2 p; p.x = __float_as_uint(w); p.y = (unsigned)s;
        wc[wave][lane] = p;   // same-wave DS ops are in-order; no barrier needed
        int cnt = min(64, end - base);
        int k = 0;
        for (; k + 4 <= cnt; k += 4) {
            uint2 p0 = wc[wave][k];
            uint2 p1 = wc[wave][k + 1];
            uint2 p2 = wc[wave][k + 2];
            uint2 p3 = wc[wave][k + 3];
            acc0 += __uint_as_float(p0.x) * (float)hb[(size_t)p0.y * rs];
            acc1 += __uint_as_float(p1.x) * (float)hb[(size_t)p1.y * rs];
            acc2 += __uint_as_float(p2.x) * (float)hb[(size_t)p2.y * rs];
            acc3 += __uint_as_float(p3.x) * (float)hb[(size_t)p3.y * rs];
        }
        for (; k < cnt; ++k) {
            uint2 p0 = wc[wave][k];
            acc0 += __uint_as_float(p0.x) * (float)hb[(size_t)p0.y * rs];
        }
    }
    float acc = (acc0 + acc1) + (acc2 + acc3);
    #pragma unroll
    for (int off = 32; off; off >>= 1) denom += __shfl_xor(denom, off);
    atomicAdd(&out[n * 64 + lane], acc / ((denom + 1e-16f) * H));
}

// ------------------------------------------------------------------ BatchNorm
__global__ void bn_stats(const float* __restrict__ x, const float* __restrict__ gamma,
                         const float* __restrict__ beta, float* __restrict__ scale,
                         float* __restrict__ shift, int N) {
    int c = blockIdx.x;
    float s = 0.f, ss = 0.f;
    for (int r = threadIdx.x; r < N; r += 256) {
        float v = x[(size_t)r * 64 + c];
        s += v; ss += v * v;
    }
    #pragma unroll
    for (int off = 32; off; off >>= 1) {
        s  += __shfl_xor(s, off);
        ss += __shfl_xor(ss, off);
    }
    __shared__ float red[8];
    int wv = threadIdx.x >> 6, ln = threadIdx.x & 63;
    if (ln == 0) { red[wv] = s; red[4 + wv] = ss; }
    __syncthreads();
    if (threadIdx.x == 0) {
        float S  = red[0] + red[1] + red[2] + red[3];
        float SS = red[4] + red[5] + red[6] + red[7];
        float mu  = S / N;
        float var = SS / N - mu * mu;
        float istd = rsqrtf(var + 1e-5f);
        scale[c] = gamma[c] * istd;
        shift[c] = beta[c] - mu * gamma[c] * istd;
    }
}

__global__ void bn_apply(const float* __restrict__ x, const float* __restrict__ scale,
                         const float* __restrict__ shift, float* __restrict__ y, int total) {
    int i = blockIdx.x * 256 + threadIdx.x;
    if (i < total) {
        int c = i & 63;
        y[i] = fmaxf(x[i] * scale[c] + shift[c], 0.f);
    }
}

// ------------------------------------------------------------------ MHA
// vh [N][64] f16 -> vt [64][N] f16 (row = h*16+d), LDS-tiled transpose
__global__ void vtrans(const _Float16* __restrict__ vh, _Float16* __restrict__ vt, int N) {
    __shared__ _Float16 tile[64][68];
    int kb = blockIdx.x * 64;
    int t  = threadIdx.x;
    {
        int r = t >> 2, c0 = (t & 3) * 16;
        half8_t x0 = *(const half8_t*)(vh + (size_t)(kb + r) * 64 + c0);
        half8_t x1 = *(const half8_t*)(vh + (size_t)(kb + r) * 64 + c0 + 8);
        #pragma unroll
        for (int i = 0; i < 8; ++i) { tile[r][c0 + i] = x0[i]; tile[r][c0 + 8 + i] = x1[i]; }
    }
    __syncthreads();
    {
        int c = t >> 2, ks = (t & 3) * 16;
        half8_t y0, y1;
        #pragma unroll
        for (int i = 0; i < 8; ++i) { y0[i] = tile[ks + i][c]; y1[i] = tile[ks + 8 + i][c]; }
        *(half8_t*)(vt + (size_t)c * N + kb + ks)     = y0;
        *(half8_t*)(vt + (size_t)c * N + kb + ks + 8) = y1;
    }
}

// kh [N][64] f16 -> khp [4][N][16] f16 (head-major rows, 32B per key)
__global__ void kpack(const _Float16* __restrict__ kh, _Float16* __restrict__ khp, int N) {
    int id = blockIdx.x * 256 + threadIdx.x;   // N*8 threads
    int n = id >> 3, c8 = (id & 7) * 8;
    half8_t v = *(const half8_t*)(kh + (size_t)n * 64 + c8);
    int h = c8 >> 4, d0 = c8 & 15;
    *(half8_t*)(khp + ((size_t)h * N + n) * 16 + d0) = v;
}

// Block = 4 waves, one head, 64 queries. K/V tiles (64 keys) cooperatively staged
// in LDS, double-buffered; coalesced global loads from head-major khp / vt.
__global__ void mha_fa3(const _Float16* __restrict__ qh, const _Float16* __restrict__ khp,
                        const _Float16* __restrict__ vt, float* __restrict__ ao, int N) {
    __shared__ _Float16 Kt[2][64][20];   // [key][ch], pad 16->20
    __shared__ _Float16 Vt[2][16][68];   // [ch][key], pad 64->68
    int h    = blockIdx.y;
    int t    = threadIdx.x;
    int lane = t & 63;
    int wave = t >> 6;
    int lo16 = lane & 15;
    int g    = lane >> 4;
    int q    = blockIdx.x * 64 + wave * 16 + lo16;

    half4_t qf = *(const half4_t*)(qh + (size_t)q * 64 + h * 16 + g * 4);
    const _Float16* kp = khp + (size_t)h * N * 16;
    const _Float16* vp = vt + (size_t)h * 16 * N;

    int skey = t >> 2, sch = (t & 3) * 4;       // K staging coords (2KB contiguous)
    int sd = t >> 4, skv = (t & 15) * 4;        // V staging coords (16 x 128B rows)

    // stage tile 0
    *(half4_t*)&Kt[0][skey][sch] = *(const half4_t*)(kp + (size_t)skey * 16 + sch);
    *(half4_t*)&Vt[0][sd][skv]   = *(const half4_t*)(vp + (size_t)sd * N + skv);

    float m = -1e30f, l = 0.f;
    f32x4 o = {0.f, 0.f, 0.f, 0.f};
    const f32x4 zero = {0.f, 0.f, 0.f, 0.f};
    int nt = N / 64;

    for (int it = 0; it < nt; ++it) {
        int cur = it & 1;
        __syncthreads();   // staged data for tile `it` visible; prev reads done
        if (it + 1 < nt) {
            int kt = (it + 1) * 64;
            *(half4_t*)&Kt[cur ^ 1][skey][sch] = *(const half4_t*)(kp + (size_t)(kt + skey) * 16 + sch);
            *(half4_t*)&Vt[cur ^ 1][sd][skv]   = *(const half4_t*)(vp + (size_t)sd * N + kt + skv);
        }
        // ---- QK^T: 4 sub-tiles of 16 keys
        f32x4 s[4];
        #pragma unroll
        for (int st = 0; st < 4; ++st) {
            half4_t kf = *(const half4_t*)&Kt[cur][st * 16 + lo16][g * 4];
            s[st] = __builtin_amdgcn_mfma_f32_16x16x16f16(kf, qf, zero, 0, 0, 0);
        }
        // ---- online softmax over 64 keys
        float tm = -1e30f;
        #pragma unroll
        for (int st = 0; st < 4; ++st)
            tm = fmaxf(tm, fmaxf(fmaxf(s[st][0], s[st][1]), fmaxf(s[st][2], s[st][3])));
        tm = fmaxf(tm, __shfl_xor(tm, 16));
        tm = fmaxf(tm, __shfl_xor(tm, 32));
        float mnew = fmaxf(m, tm);
        float r = __expf(m - mnew);
        m = mnew;
        float lsum = 0.f;
        half4_t pf[4];
        #pragma unroll
        for (int st = 0; st < 4; ++st) {
            #pragma unroll
            for (int i = 0; i < 4; ++i) {
                float p = __expf(s[st][i] - mnew);
                lsum += p;
                pf[st][i] = (_Float16)p;
            }
        }
        l = l * r + lsum;
        #pragma unroll
        for (int i = 0; i < 4; ++i) o[i] *= r;   // O^T col = q -> lane-local rescale
        // ---- PV
        #pragma unroll
        for (int st = 0; st < 4; ++st) {
            half4_t vf = *(const half4_t*)&Vt[cur][lo16][st * 16 + g * 4];
            o = __builtin_amdgcn_mfma_f32_16x16x16f16(vf, pf[st], o, 0, 0, 0);
        }
    }
    // l partials: lane-group g covered keys {16st+4g+i} -- disjoint across g
    l += __shfl_xor(l, 16);
    l += __shfl_xor(l, 32);
    float inv = 1.f / l;
    f32x4 res;
    #pragma unroll
    for (int i = 0; i < 4; ++i) res[i] = o[i] * inv;   // res[i] = O[q][h*16+4g+i]
    *(f32x4*)(ao + (size_t)q * 64 + h * 16 + g * 4) = res;
}

// ------------------------------------------------------------------- host side
static inline void launch_gemm(const float* A, const float* B, const float* bias, float* C,
                               int M, int Nc, int K, bool transB, int act, hipStream_t st) {
    dim3 grid((Nc + 63) / 64, M / 64), blk(256);
    if (!transB)       gemm_f32<false, 0><<<grid, blk, 0, st>>>(A, B, bias, C, M, Nc, K);
    else if (act == 0) gemm_f32<true, 0><<<grid, blk, 0, st>>>(A, B, bias, C, M, Nc, K);
    else               gemm_f32<true, 1><<<grid, blk, 0, st>>>(A, B, bias, C, M, Nc, K);
}

extern "C" void kernel_launch(void* const* d_in, const int* in_sizes, int n_in,
                              void* d_out, int out_size, void* d_ws, size_t ws_size,
                              hipStream_t stream) {
    const int N = NN, E = EE;
    const float* x    = (const float*)d_in[0];
    const int*   ei   = (const int*)d_in[1];
    const float* W[3]   = {(const float*)d_in[2], (const float*)d_in[6], (const float*)d_in[10]};
    const float* as_[3] = {(const float*)d_in[3], (const float*)d_in[7], (const float*)d_in[11]};
    const float* ad_[3] = {(const float*)d_in[4], (const float*)d_in[8], (const float*)d_in[12]};
    const float* bn_g = (const float*)d_in[14];
    const float* bn_b = (const float*)d_in[15];
    const float* Wq = (const float*)d_in[16];
    const float* Wk = (const float*)d_in[17];
    const float* Wv = (const float*)d_in[18];
    const float* Wo = (const float*)d_in[19];
    const float* bq = (const float*)d_in[20];
    const float* bk = (const float*)d_in[21];
    const float* bv = (const float*)d_in[22];
    const float* bo = (const float*)d_in[23];
    const float* Wc1 = (const float*)d_in[24];
    const float* bc1 = (const float*)d_in[25];
    const float* Wc2 = (const float*)d_in[26];
    const float* bc2 = (const float*)d_in[27];

    char* ws = (char*)d_ws;
    _Float16* h16 = (_Float16*)(ws + 0);       // 8192*512*2 = 8,388,608 (GAT phase)
    _Float16* qh = (_Float16*)(ws + 9437184);  // 1,048,576 (MHA phase)
    _Float16* kh = (_Float16*)(ws + 10485760); // 1,048,576
    _Float16* vh = (_Float16*)(ws + 11534336); // 1,048,576
    _Float16* vt = (_Float16*)(ws + 12582912); // 1,048,576
    _Float16* khp = (_Float16*)(ws + 13631488);// 1,048,576
    float* a_s  = (float*)(ws + 16777216);     // 262,144
    float* a_d  = (float*)(ws + 17039360);     // 262,144
    int* row_ptr = (int*)(ws + 17301504);      // 33,024
    int* cursor  = (int*)(ws + 17334528);      // 32,768
    int* deg     = (int*)(ws + 17367296);      // 32,768
    int* col     = (int*)(ws + 17400064);      // 1,081,344
    float* xg   = (float*)(ws + 18481408);     // 2,097,152
    float* xb   = (float*)(ws + 20578560);     // 2,097,152
    float* ao   = (float*)(ws + 28967168);     // 2,097,152
    float* c1   = (float*)(ws + 31064320);     // 1,048,576
    float* bnscale = (float*)(ws + 32112896);  // 64
    float* bnshift = bnscale + 64;             // 64

    // ---- CSR build (same graph all layers); self-loops via deg init = 1
    k_fill_i32<<<(N + 255) / 256, 256, 0, stream>>>(deg, 1, N);
    count_deg<<<(E + 255) / 256, 256, 0, stream>>>(ei, deg, E);
    scan_deg<<<1, 1024, 0, stream>>>(deg, row_ptr, cursor, N);
    fill_csr<<<(E + N + 255) / 256, 256, 0, stream>>>(ei, cursor, col, E, N);

    // ---- 3 GAT layers (+BN+ReLU).  GAT bias cancels through BN -> skipped.
    const int heads[3] = {8, 8, 1};
    const int fins[3]  = {128, 64, 64};
    const float* xin = x;
    for (int i = 0; i < 3; ++i) {
        int H = heads[i], K = fins[i];
        mfma_gemm<false, true, 0><<<dim3(H, N / 64), 256, 0, stream>>>(
            xin, W[i], nullptr, h16, N, H * 64, K, 1.f);
        gat_coef<<<(N * H) / 4, 256, 0, stream>>>(h16, as_[i], ad_[i], a_s, a_d, N, H);
        hipMemsetAsync(xg, 0, (size_t)N * 64 * 4, stream);
        gat_gather3<<<(N * H) / 4, 256, 0, stream>>>(h16, a_s, a_d, row_ptr, col, xg, N, H);
        bn_stats<<<64, 256, 0, stream>>>(xg, bn_g + i * 64, bn_b + i * 64, bnscale, bnshift, N);
        bn_apply<<<(N * 64) / 256, 256, 0, stream>>>(xg, bnscale, bnshift, xb, N * 64);
        xin = xb;
    }

    // ---- MHA (4 heads, hd=16): f16 Q/K/V from MFMA GEMM; LDS-staged flash
    mfma_gemm<true, true, 0><<<dim3(1, N / 64), 256, 0, stream>>>(xb, Wq, bq, qh, N, 64, 64, 0.25f);
    mfma_gemm<true, true, 0><<<dim3(1, N / 64), 256, 0, stream>>>(xb, Wk, bk, kh, N, 64, 64, 1.f);
    mfma_gemm<true, true, 0><<<dim3(1, N / 64), 256, 0, stream>>>(xb, Wv, bv, vh, N, 64, 64, 1.f);
    vtrans<<<N / 64, 256, 0, stream>>>(vh, vt, N);
    kpack<<<N * 8 / 256, 256, 0, stream>>>(kh, khp, N);
    mha_fa3<<<dim3(N / 64, 4), 256, 0, stream>>>(qh, khp, vt, ao, N);
    mfma_gemm<true, false, 0><<<dim3(1, N / 64), 256, 0, stream>>>(ao, Wo, bo, xg, N, 64, 64, 1.f);

    // ---- classifier (small Nc: f32 path)
    launch_gemm(xg, Wc1, bc1, c1, N, 32, 64, true, 1, stream);
    launch_gemm(c1, Wc2, bc2, (float*)d_out, N, 10, 32, true, 0, stream);
}

// Round 8
// 379.412 us; speedup vs baseline: 2.2395x; 1.0870x over previous
//
#include <hip/hip_runtime.h>
#include <hip/hip_bf16.h>

#define NN 8192
#define EE 262144
#define HID 64

typedef _Float16 half4_t __attribute__((ext_vector_type(4)));
typedef _Float16 half8_t __attribute__((ext_vector_type(8)));
typedef float f32x4 __attribute__((ext_vector_type(4)));

extern "C" __device__ float __ocml_native_exp2_f32(float);
#define EXP2N(x) __ocml_native_exp2_f32(x)

// ---------------------------------------------------------------- GEMM (f32, small Nc)
template<bool TRANS_B, int ACT>
__global__ void gemm_f32(const float* __restrict__ A, const float* __restrict__ B,
                         const float* __restrict__ bias, float* __restrict__ C,
                         int M, int Nc, int K) {
    __shared__ float As[16][65];
    __shared__ float Bs[16][65];
    int tid = threadIdx.x;
    int brow = blockIdx.y * 64, bcol = blockIdx.x * 64;
    int tr = (tid / 16) * 4;
    int tc = (tid % 16) * 4;
    float acc[4][4] = {};
    for (int k0 = 0; k0 < K; k0 += 16) {
        {   // A tile 64x16
            int r  = tid / 4;
            int kk = (tid % 4) * 4;
            const float* a = A + (size_t)(brow + r) * K + k0 + kk;
            #pragma unroll
            for (int j = 0; j < 4; ++j) As[kk + j][r] = a[j];
        }
        if (!TRANS_B) {   // B[K][Nc]
            int kk = tid / 16;
            int n4 = (tid % 16) * 4;
            #pragma unroll
            for (int j = 0; j < 4; ++j) {
                int n = bcol + n4 + j;
                Bs[kk][n4 + j] = (n < Nc) ? B[(size_t)(k0 + kk) * Nc + n] : 0.f;
            }
        } else {          // B[Nc][K]
            int n  = tid / 4;
            int kk = (tid % 4) * 4;
            #pragma unroll
            for (int j = 0; j < 4; ++j)
                Bs[kk + j][n] = (bcol + n < Nc) ? B[(size_t)(bcol + n) * K + k0 + kk + j] : 0.f;
        }
        __syncthreads();
        #pragma unroll
        for (int kk = 0; kk < 16; ++kk) {
            float av[4], bv[4];
            #pragma unroll
            for (int i = 0; i < 4; ++i) av[i] = As[kk][tr + i];
            #pragma unroll
            for (int j = 0; j < 4; ++j) bv[j] = Bs[kk][tc + j];
            #pragma unroll
            for (int i = 0; i < 4; ++i)
                #pragma unroll
                for (int j = 0; j < 4; ++j)
                    acc[i][j] += av[i] * bv[j];
        }
        __syncthreads();
    }
    #pragma unroll
    for (int i = 0; i < 4; ++i) {
        int r = brow + tr + i;
        #pragma unroll
        for (int j = 0; j < 4; ++j) {
            int c = bcol + tc + j;
            if (c < Nc) {
                float v = acc[i][j];
                if (bias) v += bias[c];
                if (ACT == 1) v = fmaxf(v, 0.f);
                C[(size_t)r * Nc + c] = v;
            }
        }
    }
}

// ---------------------------------------------------------------- GEMM (MFMA f16 in, f32 acc)
template<bool TRANS_B, bool OUT_F16, int ACT>
__global__ void mfma_gemm(const float* __restrict__ A, const float* __restrict__ B,
                          const float* __restrict__ bias, void* __restrict__ Cout,
                          int M, int Nc, int K, float scale) {
    __shared__ _Float16 Ah[64][36];
    __shared__ _Float16 Bt[64][36];
    int tid  = threadIdx.x;
    int wave = tid >> 6, lane = tid & 63, lo16 = lane & 15, g = lane >> 4;
    int brow = blockIdx.y * 64, bcol = blockIdx.x * 64;
    f32x4 acc[4];
    #pragma unroll
    for (int i = 0; i < 4; ++i) acc[i] = (f32x4){0.f, 0.f, 0.f, 0.f};

    for (int k0 = 0; k0 < K; k0 += 32) {
        {   // stage A 64x32 -> f16
            int r  = tid >> 2;
            int ks = (tid & 3) * 8;
            const float* ap = A + (size_t)(brow + r) * K + k0 + ks;
            f32x4 a0 = *(const f32x4*)ap;
            f32x4 a1 = *(const f32x4*)(ap + 4);
            half4_t h0, h1;
            #pragma unroll
            for (int i = 0; i < 4; ++i) { h0[i] = (_Float16)a0[i]; h1[i] = (_Float16)a1[i]; }
            *(half4_t*)&Ah[r][ks]     = h0;
            *(half4_t*)&Ah[r][ks + 4] = h1;
        }
        if (TRANS_B) {   // B[Nc][K] -> Bt[n][k]
            int n  = tid >> 2;
            int ks = (tid & 3) * 8;
            const float* bp = B + (size_t)(bcol + n) * K + k0 + ks;
            f32x4 b0 = *(const f32x4*)bp;
            f32x4 b1 = *(const f32x4*)(bp + 4);
            half4_t h0, h1;
            #pragma unroll
            for (int i = 0; i < 4; ++i) { h0[i] = (_Float16)b0[i]; h1[i] = (_Float16)b1[i]; }
            *(half4_t*)&Bt[n][ks]     = h0;
            *(half4_t*)&Bt[n][ks + 4] = h1;
        } else {         // B[K][Nc] -> Bt[n][k] (transpose during staging)
            int n  = tid & 63;
            int kb = (tid >> 6) * 8;
            half4_t h0, h1;
            #pragma unroll
            for (int i = 0; i < 4; ++i)
                h0[i] = (_Float16)B[(size_t)(k0 + kb + i) * Nc + bcol + n];
            #pragma unroll
            for (int i = 0; i < 4; ++i)
                h1[i] = (_Float16)B[(size_t)(k0 + kb + 4 + i) * Nc + bcol + n];
            *(half4_t*)&Bt[n][kb]     = h0;
            *(half4_t*)&Bt[n][kb + 4] = h1;
        }
        __syncthreads();
        #pragma unroll
        for (int kh = 0; kh < 2; ++kh) {
            half4_t af = *(const half4_t*)&Ah[wave * 16 + lo16][kh * 16 + g * 4];
            #pragma unroll
            for (int cf = 0; cf < 4; ++cf) {
                half4_t bf = *(const half4_t*)&Bt[cf * 16 + lo16][kh * 16 + g * 4];
                acc[cf] = __builtin_amdgcn_mfma_f32_16x16x16f16(af, bf, acc[cf], 0, 0, 0);
            }
        }
        __syncthreads();
    }
    int rbase = brow + wave * 16 + g * 4;
    #pragma unroll
    for (int cf = 0; cf < 4; ++cf) {
        int c = bcol + cf * 16 + lo16;
        float bv = bias ? bias[c] : 0.f;
        #pragma unroll
        for (int reg = 0; reg < 4; ++reg) {
            float v = (acc[cf][reg] + bv) * scale;
            if (ACT == 1) v = fmaxf(v, 0.f);
            if (OUT_F16) ((_Float16*)Cout)[(size_t)(rbase + reg) * Nc + c] = (_Float16)v;
            else         ((float*)Cout)[(size_t)(rbase + reg) * Nc + c] = v;
        }
    }
}

// ------------------------------------------------------------------ GAT prep
__global__ void k_fill_i32(int* p, int v, int n) {
    int i = blockIdx.x * 256 + threadIdx.x;
    if (i < n) p[i] = v;
}

__global__ void count_deg(const int* __restrict__ ei, int* __restrict__ deg, int E) {
    int e = blockIdx.x * 256 + threadIdx.x;
    if (e < E) atomicAdd(&deg[ei[E + e]], 1);   // ei[1] row = dst
}

__global__ void scan_deg(const int* __restrict__ deg, int* __restrict__ row_ptr,
                         int* __restrict__ cursor, int N) {
    __shared__ int tmp[1024];
    int tid = threadIdx.x;
    int base = tid * 8;
    int local[8];
    int s = 0;
    #pragma unroll
    for (int j = 0; j < 8; ++j) { local[j] = deg[base + j]; s += local[j]; }
    tmp[tid] = s;
    __syncthreads();
    for (int off = 1; off < 1024; off <<= 1) {
        int add = (tid >= off) ? tmp[tid - off] : 0;
        __syncthreads();
        tmp[tid] += add;
        __syncthreads();
    }
    int run = tmp[tid] - s;   // exclusive prefix of this chunk
    #pragma unroll
    for (int j = 0; j < 8; ++j) {
        row_ptr[base + j] = run;
        cursor[base + j]  = run;
        run += local[j];
    }
    if (tid == 1023) row_ptr[N] = run;
}

__global__ void fill_csr(const int* __restrict__ ei, int* __restrict__ cursor,
                         int* __restrict__ col, int E, int N) {
    int e = blockIdx.x * 256 + threadIdx.x;
    if (e < E) {
        int dst = ei[E + e];
        int pos = atomicAdd(&cursor[dst], 1);
        col[pos] = ei[e];
    } else if (e < E + N) {
        int n = e - E;
        int pos = atomicAdd(&cursor[n], 1);
        col[pos] = n;
    }
}

// ---------------------------------------------------------------- GAT kernels
__global__ void gat_coef(const _Float16* __restrict__ h, const float* __restrict__ att_s,
                         const float* __restrict__ att_d, float* __restrict__ a_s,
                         float* __restrict__ a_d, int N, int H) {
    int wid  = (blockIdx.x * 256 + threadIdx.x) >> 6;
    int lane = threadIdx.x & 63;
    if (wid >= N * H) return;
    int hh = wid % H;
    float v = (float)h[(size_t)wid * 64 + lane];
    float s = v * att_s[hh * 64 + lane];
    float d = v * att_d[hh * 64 + lane];
    #pragma unroll
    for (int off = 32; off; off >>= 1) {
        s += __shfl_down(s, off);
        d += __shfl_down(d, off);
    }
    if (lane == 0) { a_s[wid] = s; a_d[wid] = d; }
}

// wave per (dst n, head h); per-wave LDS stash of (w,col); uniform ds broadcasts,
// 4 independent FMA chains. f16 h. atomicAdd head-mean (order noise ~1e-6).
__global__ void gat_gather3(const _Float16* __restrict__ h, const float* __restrict__ a_s,
                            const float* __restrict__ a_d, const int* __restrict__ row_ptr,
                            const int* __restrict__ col, float* __restrict__ out,
                            int N, int H) {
    __shared__ uint2 wc[4][64];
    int t    = threadIdx.x;
    int wave = t >> 6;
    int lane = t & 63;
    int wid  = (blockIdx.x * 256 + t) >> 6;
    if (wid >= N * H) return;
    int n = wid / H, hh = wid % H;
    int beg = row_ptr[n], end = row_ptr[n + 1];
    float adn = a_d[n * H + hh];
    float m = -1e30f;
    for (int j = beg + lane; j < end; j += 64) {
        float sc = a_s[col[j] * H + hh] + adn;
        sc = sc > 0.f ? sc : 0.2f * sc;
        m = fmaxf(m, sc);
    }
    #pragma unroll
    for (int off = 32; off; off >>= 1) m = fmaxf(m, __shfl_xor(m, off));
    const _Float16* hb = h + (size_t)hh * 64 + lane;
    const size_t rs = (size_t)H * 64;
    float denom = 0.f;
    float acc0 = 0.f, acc1 = 0.f, acc2 = 0.f, acc3 = 0.f;
    for (int base = beg; base < end; base += 64) {
        int j = base + lane;
        float w = 0.f; int s = 0;
        if (j < end) {
            s = col[j];
            float sc = a_s[s * H + hh] + adn;
            sc = sc > 0.f ? sc : 0.2f * sc;
            w = __expf(sc - m);
        }
        denom += w;
        uint2 p; p.x = __float_as_uint(w); p.y = (unsigned)s;
        wc[wave][lane] = p;   // same-wave DS ops are in-order; no barrier needed
        int cnt = min(64, end - base);
        int k = 0;
        for (; k + 4 <= cnt; k += 4) {
            uint2 p0 = wc[wave][k];
            uint2 p1 = wc[wave][k + 1];
            uint2 p2 = wc[wave][k + 2];
            uint2 p3 = wc[wave][k + 3];
            acc0 += __uint_as_float(p0.x) * (float)hb[(size_t)p0.y * rs];
            acc1 += __uint_as_float(p1.x) * (float)hb[(size_t)p1.y * rs];
            acc2 += __uint_as_float(p2.x) * (float)hb[(size_t)p2.y * rs];
            acc3 += __uint_as_float(p3.x) * (float)hb[(size_t)p3.y * rs];
        }
        for (; k < cnt; ++k) {
            uint2 p0 = wc[wave][k];
            acc0 += __uint_as_float(p0.x) * (float)hb[(size_t)p0.y * rs];
        }
    }
    float acc = (acc0 + acc1) + (acc2 + acc3);
    #pragma unroll
    for (int off = 32; off; off >>= 1) denom += __shfl_xor(denom, off);
    atomicAdd(&out[n * 64 + lane], acc / ((denom + 1e-16f) * H));
}

// ------------------------------------------------------------------ BatchNorm
__global__ void bn_stats(const float* __restrict__ x, const float* __restrict__ gamma,
                         const float* __restrict__ beta, float* __restrict__ scale,
                         float* __restrict__ shift, int N) {
    int c = blockIdx.x;
    float s = 0.f, ss = 0.f;
    for (int r = threadIdx.x; r < N; r += 256) {
        float v = x[(size_t)r * 64 + c];
        s += v; ss += v * v;
    }
    #pragma unroll
    for (int off = 32; off; off >>= 1) {
        s  += __shfl_xor(s, off);
        ss += __shfl_xor(ss, off);
    }
    __shared__ float red[8];
    int wv = threadIdx.x >> 6, ln = threadIdx.x & 63;
    if (ln == 0) { red[wv] = s; red[4 + wv] = ss; }
    __syncthreads();
    if (threadIdx.x == 0) {
        float S  = red[0] + red[1] + red[2] + red[3];
        float SS = red[4] + red[5] + red[6] + red[7];
        float mu  = S / N;
        float var = SS / N - mu * mu;
        float istd = rsqrtf(var + 1e-5f);
        scale[c] = gamma[c] * istd;
        shift[c] = beta[c] - mu * gamma[c] * istd;
    }
}

__global__ void bn_apply(const float* __restrict__ x, const float* __restrict__ scale,
                         const float* __restrict__ shift, float* __restrict__ y, int total) {
    int i = blockIdx.x * 256 + threadIdx.x;
    if (i < total) {
        int c = i & 63;
        y[i] = fmaxf(x[i] * scale[c] + shift[c], 0.f);
    }
}

// ------------------------------------------------------------------ MHA
// vh [N][64] f16 -> vt [64][N] f16 (row = h*16+d), LDS-tiled transpose
__global__ void vtrans(const _Float16* __restrict__ vh, _Float16* __restrict__ vt, int N) {
    __shared__ _Float16 tile[64][68];
    int kb = blockIdx.x * 64;
    int t  = threadIdx.x;
    {
        int r = t >> 2, c0 = (t & 3) * 16;
        half8_t x0 = *(const half8_t*)(vh + (size_t)(kb + r) * 64 + c0);
        half8_t x1 = *(const half8_t*)(vh + (size_t)(kb + r) * 64 + c0 + 8);
        #pragma unroll
        for (int i = 0; i < 8; ++i) { tile[r][c0 + i] = x0[i]; tile[r][c0 + 8 + i] = x1[i]; }
    }
    __syncthreads();
    {
        int c = t >> 2, ks = (t & 3) * 16;
        half8_t y0, y1;
        #pragma unroll
        for (int i = 0; i < 8; ++i) { y0[i] = tile[ks + i][c]; y1[i] = tile[ks + 8 + i][c]; }
        *(half8_t*)(vt + (size_t)c * N + kb + ks)     = y0;
        *(half8_t*)(vt + (size_t)c * N + kb + ks + 8) = y1;
    }
}

// kh [N][64] f16 -> khp [4][N][16] f16 (head-major rows, 32B per key)
__global__ void kpack(const _Float16* __restrict__ kh, _Float16* __restrict__ khp, int N) {
    int id = blockIdx.x * 256 + threadIdx.x;   // N*8 threads
    int n = id >> 3, c8 = (id & 7) * 8;
    half8_t v = *(const half8_t*)(kh + (size_t)n * 64 + c8);
    int h = c8 >> 4, d0 = c8 & 15;
    *(half8_t*)(khp + ((size_t)h * N + n) * 16 + d0) = v;
}

// Block = 8 waves / 512 thr, one head, 64 queries. Waves 0-3 (grp 0): even 64-key
// tiles; waves 4-7 (grp 1): odd tiles. Each group double-buffers its own K/V LDS
// tiles. Deterministic in-block merge (fixed order) via LDS. Softmax runs in the
// exp2 domain (log2e folded into Q scale): bare v_exp, no v_mul per score.
__global__ __launch_bounds__(512) void mha_fa4(const _Float16* __restrict__ qh,
                                               const _Float16* __restrict__ khp,
                                               const _Float16* __restrict__ vt,
                                               float* __restrict__ ao, int N) {
    __shared__ _Float16 Kt[2][2][64][20];   // [grp][buf][key][ch]
    __shared__ _Float16 Vt[2][2][16][70];   // [grp][buf][ch][key]
    __shared__ float MB[4][2][16];          // [wsub][{m,l}][q]
    __shared__ float OB[4][16][17];         // [wsub][d][q]
    int h    = blockIdx.y;
    int t    = threadIdx.x;
    int lane = t & 63;
    int wave = t >> 6;
    int grp  = wave >> 2;
    int wsub = wave & 3;
    int lo16 = lane & 15;
    int g    = lane >> 4;
    int q    = blockIdx.x * 64 + wsub * 16 + lo16;

    half4_t qf = *(const half4_t*)(qh + (size_t)q * 64 + h * 16 + g * 4);
    const _Float16* kp = khp + (size_t)h * N * 16;
    const _Float16* vp = vt + (size_t)h * 16 * N;

    int tg = t & 255;
    int skey = tg >> 2, sch = (tg & 3) * 4;   // K staging coords
    int sd = tg >> 4, skv = (tg & 15) * 4;    // V staging coords

    {   // prologue: stage this group's tile 0
        int kt = grp * 64;
        *(half4_t*)&Kt[grp][0][skey][sch] = *(const half4_t*)(kp + (size_t)(kt + skey) * 16 + sch);
        *(half4_t*)&Vt[grp][0][sd][skv]   = *(const half4_t*)(vp + (size_t)sd * N + kt + skv);
    }

    float m = -1e30f, l = 0.f;
    f32x4 o = {0.f, 0.f, 0.f, 0.f};
    const f32x4 zero = {0.f, 0.f, 0.f, 0.f};
    int nit = N / 128;

    for (int it = 0; it < nit; ++it) {
        int cur = it & 1;
        __syncthreads();
        if (it + 1 < nit) {
            int kt = ((it + 1) * 2 + grp) * 64;
            *(half4_t*)&Kt[grp][cur ^ 1][skey][sch] = *(const half4_t*)(kp + (size_t)(kt + skey) * 16 + sch);
            *(half4_t*)&Vt[grp][cur ^ 1][sd][skv]   = *(const half4_t*)(vp + (size_t)sd * N + kt + skv);
        }
        // ---- QK^T: 4 sub-tiles of 16 keys (scores already in log2 domain)
        f32x4 s[4];
        #pragma unroll
        for (int st = 0; st < 4; ++st) {
            half4_t kf = *(const half4_t*)&Kt[grp][cur][st * 16 + lo16][g * 4];
            s[st] = __builtin_amdgcn_mfma_f32_16x16x16f16(kf, qf, zero, 0, 0, 0);
        }
        // ---- online softmax (max tree in triples -> v_max3)
        float t0 = fmaxf(fmaxf(s[0][0], s[0][1]), s[0][2]);
        float t1 = fmaxf(fmaxf(s[0][3], s[1][0]), s[1][1]);
        float t2 = fmaxf(fmaxf(s[1][2], s[1][3]), s[2][0]);
        float t3 = fmaxf(fmaxf(s[2][1], s[2][2]), s[2][3]);
        float t4 = fmaxf(fmaxf(s[3][0], s[3][1]), fmaxf(s[3][2], s[3][3]));
        float tm = fmaxf(fmaxf(fmaxf(t0, t1), fmaxf(t2, t3)), t4);
        tm = fmaxf(tm, __shfl_xor(tm, 16));
        tm = fmaxf(tm, __shfl_xor(tm, 32));
        float mnew = fmaxf(m, tm);
        float r = EXP2N(m - mnew);
        m = mnew;
        float lsum = 0.f;
        half4_t pf[4];
        #pragma unroll
        for (int st = 0; st < 4; ++st) {
            float p0 = EXP2N(s[st][0] - mnew);
            float p1 = EXP2N(s[st][1] - mnew);
            float p2 = EXP2N(s[st][2] - mnew);
            float p3 = EXP2N(s[st][3] - mnew);
            lsum += (p0 + p1) + (p2 + p3);
            auto lo = __builtin_amdgcn_cvt_pkrtz(p0, p1);   // __fp16x2
            auto hi = __builtin_amdgcn_cvt_pkrtz(p2, p3);
            pf[st][0] = (_Float16)lo[0]; pf[st][1] = (_Float16)lo[1];
            pf[st][2] = (_Float16)hi[0]; pf[st][3] = (_Float16)hi[1];
        }
        l = l * r + lsum;
        #pragma unroll
        for (int i = 0; i < 4; ++i) o[i] *= r;   // O^T col = q -> lane-local rescale
        // ---- PV
        #pragma unroll
        for (int st = 0; st < 4; ++st) {
            half4_t vf = *(const half4_t*)&Vt[grp][cur][lo16][st * 16 + g * 4];
            o = __builtin_amdgcn_mfma_f32_16x16x16f16(vf, pf[st], o, 0, 0, 0);
        }
    }
    // per-wave l reduce across the 4 lane-groups (disjoint key subsets)
    l += __shfl_xor(l, 16);
    l += __shfl_xor(l, 32);

    if (grp == 1) {   // publish partial state
        if (lane < 16) { MB[wsub][0][lane] = m; MB[wsub][1][lane] = l; }
        #pragma unroll
        for (int i = 0; i < 4; ++i) OB[wsub][g * 4 + i][lo16] = o[i];
    }
    __syncthreads();
    if (grp == 0) {   // deterministic merge: grp0 then grp1
        float m1 = MB[wsub][0][lo16];
        float l1 = MB[wsub][1][lo16];
        float M  = fmaxf(m, m1);
        float e0 = EXP2N(m - M), e1 = EXP2N(m1 - M);
        float inv = 1.f / (l * e0 + l1 * e1);
        f32x4 res;
        #pragma unroll
        for (int i = 0; i < 4; ++i)
            res[i] = (o[i] * e0 + OB[wsub][g * 4 + i][lo16] * e1) * inv;
        *(f32x4*)(ao + (size_t)q * 64 + h * 16 + g * 4) = res;
    }
}

// ------------------------------------------------------------------- host side
static inline void launch_gemm(const float* A, const float* B, const float* bias, float* C,
                               int M, int Nc, int K, bool transB, int act, hipStream_t st) {
    dim3 grid((Nc + 63) / 64, M / 64), blk(256);
    if (!transB)       gemm_f32<false, 0><<<grid, blk, 0, st>>>(A, B, bias, C, M, Nc, K);
    else if (act == 0) gemm_f32<true, 0><<<grid, blk, 0, st>>>(A, B, bias, C, M, Nc, K);
    else               gemm_f32<true, 1><<<grid, blk, 0, st>>>(A, B, bias, C, M, Nc, K);
}

extern "C" void kernel_launch(void* const* d_in, const int* in_sizes, int n_in,
                              void* d_out, int out_size, void* d_ws, size_t ws_size,
                              hipStream_t stream) {
    const int N = NN, E = EE;
    const float* x    = (const float*)d_in[0];
    const int*   ei   = (const int*)d_in[1];
    const float* W[3]   = {(const float*)d_in[2], (const float*)d_in[6], (const float*)d_in[10]};
    const float* as_[3] = {(const float*)d_in[3], (const float*)d_in[7], (const float*)d_in[11]};
    const float* ad_[3] = {(const float*)d_in[4], (const float*)d_in[8], (const float*)d_in[12]};
    const float* bn_g = (const float*)d_in[14];
    const float* bn_b = (const float*)d_in[15];
    const float* Wq = (const float*)d_in[16];
    const float* Wk = (const float*)d_in[17];
    const float* Wv = (const float*)d_in[18];
    const float* Wo = (const float*)d_in[19];
    const float* bq = (const float*)d_in[20];
    const float* bk = (const float*)d_in[21];
    const float* bv = (const float*)d_in[22];
    const float* bo = (const float*)d_in[23];
    const float* Wc1 = (const float*)d_in[24];
    const float* bc1 = (const float*)d_in[25];
    const float* Wc2 = (const float*)d_in[26];
    const float* bc2 = (const float*)d_in[27];

    char* ws = (char*)d_ws;
    _Float16* h16 = (_Float16*)(ws + 0);       // 8192*512*2 = 8,388,608 (GAT phase)
    _Float16* qh = (_Float16*)(ws + 9437184);  // 1,048,576 (MHA phase)
    _Float16* kh = (_Float16*)(ws + 10485760); // 1,048,576
    _Float16* vh = (_Float16*)(ws + 11534336); // 1,048,576
    _Float16* vt = (_Float16*)(ws + 12582912); // 1,048,576
    _Float16* khp = (_Float16*)(ws + 13631488);// 1,048,576
    float* a_s  = (float*)(ws + 16777216);     // 262,144
    float* a_d  = (float*)(ws + 17039360);     // 262,144
    int* row_ptr = (int*)(ws + 17301504);      // 33,024
    int* cursor  = (int*)(ws + 17334528);      // 32,768
    int* deg     = (int*)(ws + 17367296);      // 32,768
    int* col     = (int*)(ws + 17400064);      // 1,081,344
    float* xg   = (float*)(ws + 18481408);     // 2,097,152
    float* xb   = (float*)(ws + 20578560);     // 2,097,152
    float* ao   = (float*)(ws + 28967168);     // 2,097,152
    float* c1   = (float*)(ws + 31064320);     // 1,048,576
    float* bnscale = (float*)(ws + 32112896);  // 64
    float* bnshift = bnscale + 64;             // 64

    // ---- CSR build (same graph all layers); self-loops via deg init = 1
    k_fill_i32<<<(N + 255) / 256, 256, 0, stream>>>(deg, 1, N);
    count_deg<<<(E + 255) / 256, 256, 0, stream>>>(ei, deg, E);
    scan_deg<<<1, 1024, 0, stream>>>(deg, row_ptr, cursor, N);
    fill_csr<<<(E + N + 255) / 256, 256, 0, stream>>>(ei, cursor, col, E, N);

    // ---- 3 GAT layers (+BN+ReLU).  GAT bias cancels through BN -> skipped.
    const int heads[3] = {8, 8, 1};
    const int fins[3]  = {128, 64, 64};
    const float* xin = x;
    for (int i = 0; i < 3; ++i) {
        int H = heads[i], K = fins[i];
        mfma_gemm<false, true, 0><<<dim3(H, N / 64), 256, 0, stream>>>(
            xin, W[i], nullptr, h16, N, H * 64, K, 1.f);
        gat_coef<<<(N * H) / 4, 256, 0, stream>>>(h16, as_[i], ad_[i], a_s, a_d, N, H);
        hipMemsetAsync(xg, 0, (size_t)N * 64 * 4, stream);
        gat_gather3<<<(N * H) / 4, 256, 0, stream>>>(h16, a_s, a_d, row_ptr, col, xg, N, H);
        bn_stats<<<64, 256, 0, stream>>>(xg, bn_g + i * 64, bn_b + i * 64, bnscale, bnshift, N);
        bn_apply<<<(N * 64) / 256, 256, 0, stream>>>(xg, bnscale, bnshift, xb, N * 64);
        xin = xb;
    }

    // ---- MHA (4 heads, hd=16): f16 Q/K/V from MFMA GEMM; exp2-domain flash
    // Q scale = 0.25 (1/sqrt(hd)) * log2(e) -> softmax in exp2 domain
    mfma_gemm<true, true, 0><<<dim3(1, N / 64), 256, 0, stream>>>(xb, Wq, bq, qh, N, 64, 64, 0.36067376f);
    mfma_gemm<true, true, 0><<<dim3(1, N / 64), 256, 0, stream>>>(xb, Wk, bk, kh, N, 64, 64, 1.f);
    mfma_gemm<true, true, 0><<<dim3(1, N / 64), 256, 0, stream>>>(xb, Wv, bv, vh, N, 64, 64, 1.f);
    vtrans<<<N / 64, 256, 0, stream>>>(vh, vt, N);
    kpack<<<N * 8 / 256, 256, 0, stream>>>(kh, khp, N);
    mha_fa4<<<dim3(N / 64, 4), 512, 0, stream>>>(qh, khp, vt, ao, N);
    mfma_gemm<true, false, 0><<<dim3(1, N / 64), 256, 0, stream>>>(ao, Wo, bo, xg, N, 64, 64, 1.f);

    // ---- classifier (small Nc: f32 path)
    launch_gemm(xg, Wc1, bc1, c1, N, 32, 64, true, 1, stream);
    launch_gemm(c1, Wc2, bc2, (float*)d_out, N, 10, 32, true, 0, stream);
}

// Round 9
// 376.788 us; speedup vs baseline: 2.2551x; 1.0070x over previous
//
#include <hip/hip_runtime.h>
#include <hip/hip_bf16.h>

#define NN 8192
#define EE 262144
#define HID 64

typedef _Float16 half4_t __attribute__((ext_vector_type(4)));
typedef _Float16 half8_t __attribute__((ext_vector_type(8)));
typedef float f32x4 __attribute__((ext_vector_type(4)));

extern "C" __device__ float __ocml_native_exp2_f32(float);
#define EXP2N(x) __ocml_native_exp2_f32(x)

// ---------------------------------------------------------------- GEMM (f32, small Nc)
template<bool TRANS_B, int ACT>
__global__ void gemm_f32(const float* __restrict__ A, const float* __restrict__ B,
                         const float* __restrict__ bias, float* __restrict__ C,
                         int M, int Nc, int K) {
    __shared__ float As[16][65];
    __shared__ float Bs[16][65];
    int tid = threadIdx.x;
    int brow = blockIdx.y * 64, bcol = blockIdx.x * 64;
    int tr = (tid / 16) * 4;
    int tc = (tid % 16) * 4;
    float acc[4][4] = {};
    for (int k0 = 0; k0 < K; k0 += 16) {
        {   // A tile 64x16
            int r  = tid / 4;
            int kk = (tid % 4) * 4;
            const float* a = A + (size_t)(brow + r) * K + k0 + kk;
            #pragma unroll
            for (int j = 0; j < 4; ++j) As[kk + j][r] = a[j];
        }
        if (!TRANS_B) {   // B[K][Nc]
            int kk = tid / 16;
            int n4 = (tid % 16) * 4;
            #pragma unroll
            for (int j = 0; j < 4; ++j) {
                int n = bcol + n4 + j;
                Bs[kk][n4 + j] = (n < Nc) ? B[(size_t)(k0 + kk) * Nc + n] : 0.f;
            }
        } else {          // B[Nc][K]
            int n  = tid / 4;
            int kk = (tid % 4) * 4;
            #pragma unroll
            for (int j = 0; j < 4; ++j)
                Bs[kk + j][n] = (bcol + n < Nc) ? B[(size_t)(bcol + n) * K + k0 + kk + j] : 0.f;
        }
        __syncthreads();
        #pragma unroll
        for (int kk = 0; kk < 16; ++kk) {
            float av[4], bv[4];
            #pragma unroll
            for (int i = 0; i < 4; ++i) av[i] = As[kk][tr + i];
            #pragma unroll
            for (int j = 0; j < 4; ++j) bv[j] = Bs[kk][tc + j];
            #pragma unroll
            for (int i = 0; i < 4; ++i)
                #pragma unroll
                for (int j = 0; j < 4; ++j)
                    acc[i][j] += av[i] * bv[j];
        }
        __syncthreads();
    }
    #pragma unroll
    for (int i = 0; i < 4; ++i) {
        int r = brow + tr + i;
        #pragma unroll
        for (int j = 0; j < 4; ++j) {
            int c = bcol + tc + j;
            if (c < Nc) {
                float v = acc[i][j];
                if (bias) v += bias[c];
                if (ACT == 1) v = fmaxf(v, 0.f);
                C[(size_t)r * Nc + c] = v;
            }
        }
    }
}

// ---------------------------------------------------------------- GEMM (MFMA f16 in, f32 acc)
// GAT=true additionally computes a_s[row,head]=sum_c C*att_s, a_d likewise, in the
// epilogue (16-lane shfl reduce; head = bcol/64 since the 64-col tile == one head).
template<bool TRANS_B, bool OUT_F16, int ACT, bool GAT>
__global__ void mfma_gemm(const float* __restrict__ A, const float* __restrict__ B,
                          const float* __restrict__ bias, void* __restrict__ Cout,
                          int M, int Nc, int K, float scale,
                          const float* __restrict__ att_s, const float* __restrict__ att_d,
                          float* __restrict__ a_s, float* __restrict__ a_d, int H) {
    __shared__ _Float16 Ah[64][36];
    __shared__ _Float16 Bt[64][36];
    int tid  = threadIdx.x;
    int wave = tid >> 6, lane = tid & 63, lo16 = lane & 15, g = lane >> 4;
    int brow = blockIdx.y * 64, bcol = blockIdx.x * 64;
    f32x4 acc[4];
    #pragma unroll
    for (int i = 0; i < 4; ++i) acc[i] = (f32x4){0.f, 0.f, 0.f, 0.f};

    for (int k0 = 0; k0 < K; k0 += 32) {
        {   // stage A 64x32 -> f16
            int r  = tid >> 2;
            int ks = (tid & 3) * 8;
            const float* ap = A + (size_t)(brow + r) * K + k0 + ks;
            f32x4 a0 = *(const f32x4*)ap;
            f32x4 a1 = *(const f32x4*)(ap + 4);
            half4_t h0, h1;
            #pragma unroll
            for (int i = 0; i < 4; ++i) { h0[i] = (_Float16)a0[i]; h1[i] = (_Float16)a1[i]; }
            *(half4_t*)&Ah[r][ks]     = h0;
            *(half4_t*)&Ah[r][ks + 4] = h1;
        }
        if (TRANS_B) {   // B[Nc][K] -> Bt[n][k]
            int n  = tid >> 2;
            int ks = (tid & 3) * 8;
            const float* bp = B + (size_t)(bcol + n) * K + k0 + ks;
            f32x4 b0 = *(const f32x4*)bp;
            f32x4 b1 = *(const f32x4*)(bp + 4);
            half4_t h0, h1;
            #pragma unroll
            for (int i = 0; i < 4; ++i) { h0[i] = (_Float16)b0[i]; h1[i] = (_Float16)b1[i]; }
            *(half4_t*)&Bt[n][ks]     = h0;
            *(half4_t*)&Bt[n][ks + 4] = h1;
        } else {         // B[K][Nc] -> Bt[n][k] (transpose during staging)
            int n  = tid & 63;
            int kb = (tid >> 6) * 8;
            half4_t h0, h1;
            #pragma unroll
            for (int i = 0; i < 4; ++i)
                h0[i] = (_Float16)B[(size_t)(k0 + kb + i) * Nc + bcol + n];
            #pragma unroll
            for (int i = 0; i < 4; ++i)
                h1[i] = (_Float16)B[(size_t)(k0 + kb + 4 + i) * Nc + bcol + n];
            *(half4_t*)&Bt[n][kb]     = h0;
            *(half4_t*)&Bt[n][kb + 4] = h1;
        }
        __syncthreads();
        #pragma unroll
        for (int kh = 0; kh < 2; ++kh) {
            half4_t af = *(const half4_t*)&Ah[wave * 16 + lo16][kh * 16 + g * 4];
            #pragma unroll
            for (int cf = 0; cf < 4; ++cf) {
                half4_t bf = *(const half4_t*)&Bt[cf * 16 + lo16][kh * 16 + g * 4];
                acc[cf] = __builtin_amdgcn_mfma_f32_16x16x16f16(af, bf, acc[cf], 0, 0, 0);
            }
        }
        __syncthreads();
    }
    int rbase = brow + wave * 16 + g * 4;
    #pragma unroll
    for (int cf = 0; cf < 4; ++cf) {
        int c = bcol + cf * 16 + lo16;
        float bv = bias ? bias[c] : 0.f;
        #pragma unroll
        for (int reg = 0; reg < 4; ++reg) {
            float v = (acc[cf][reg] + bv) * scale;
            if (ACT == 1) v = fmaxf(v, 0.f);
            if (OUT_F16) ((_Float16*)Cout)[(size_t)(rbase + reg) * Nc + c] = (_Float16)v;
            else         ((float*)Cout)[(size_t)(rbase + reg) * Nc + c] = v;
        }
    }
    if (GAT) {
        float as_c[4], ad_c[4];
        #pragma unroll
        for (int cf = 0; cf < 4; ++cf) {
            int c = bcol + cf * 16 + lo16;
            as_c[cf] = att_s[c];
            ad_c[cf] = att_d[c];
        }
        int head = bcol >> 6;
        #pragma unroll
        for (int reg = 0; reg < 4; ++reg) {
            float ps = 0.f, pd = 0.f;
            #pragma unroll
            for (int cf = 0; cf < 4; ++cf) {
                ps += acc[cf][reg] * as_c[cf];
                pd += acc[cf][reg] * ad_c[cf];
            }
            #pragma unroll
            for (int off = 8; off; off >>= 1) {
                ps += __shfl_xor(ps, off);
                pd += __shfl_xor(pd, off);
            }
            if (lo16 == 0) {
                int row = rbase + reg;
                a_s[row * H + head] = ps;
                a_d[row * H + head] = pd;
            }
        }
    }
}

// ------------------------------------------------------------------ GAT prep
__global__ void k_fill_i32(int* p, int v, int n) {
    int i = blockIdx.x * 256 + threadIdx.x;
    if (i < n) p[i] = v;
}

__global__ void count_deg(const int* __restrict__ ei, int* __restrict__ deg, int E) {
    int e = blockIdx.x * 256 + threadIdx.x;
    if (e < E) atomicAdd(&deg[ei[E + e]], 1);   // ei[1] row = dst
}

__global__ void scan_deg(const int* __restrict__ deg, int* __restrict__ row_ptr,
                         int* __restrict__ cursor, int N) {
    __shared__ int tmp[1024];
    int tid = threadIdx.x;
    int base = tid * 8;
    int local[8];
    int s = 0;
    #pragma unroll
    for (int j = 0; j < 8; ++j) { local[j] = deg[base + j]; s += local[j]; }
    tmp[tid] = s;
    __syncthreads();
    for (int off = 1; off < 1024; off <<= 1) {
        int add = (tid >= off) ? tmp[tid - off] : 0;
        __syncthreads();
        tmp[tid] += add;
        __syncthreads();
    }
    int run = tmp[tid] - s;   // exclusive prefix of this chunk
    #pragma unroll
    for (int j = 0; j < 8; ++j) {
        row_ptr[base + j] = run;
        cursor[base + j]  = run;
        run += local[j];
    }
    if (tid == 1023) row_ptr[N] = run;
}

__global__ void fill_csr(const int* __restrict__ ei, int* __restrict__ cursor,
                         int* __restrict__ col, int E, int N) {
    int e = blockIdx.x * 256 + threadIdx.x;
    if (e < E) {
        int dst = ei[E + e];
        int pos = atomicAdd(&cursor[dst], 1);
        col[pos] = ei[e];
    } else if (e < E + N) {
        int n = e - E;
        int pos = atomicAdd(&cursor[n], 1);
        col[pos] = n;
    }
}

// ---------------------------------------------------------------- GAT gather
// wave per (dst n, head h); per-wave LDS stash of (w,col); uniform ds broadcasts,
// 8 independent FMA chains. f16 h. atomicAdd head-mean (order noise ~1e-6).
__global__ void gat_gather3(const _Float16* __restrict__ h, const float* __restrict__ a_s,
                            const float* __restrict__ a_d, const int* __restrict__ row_ptr,
                            const int* __restrict__ col, float* __restrict__ out,
                            int N, int H) {
    __shared__ uint2 wc[4][64];
    int t    = threadIdx.x;
    int wave = t >> 6;
    int lane = t & 63;
    int wid  = (blockIdx.x * 256 + t) >> 6;
    if (wid >= N * H) return;
    int n = wid / H, hh = wid % H;
    int beg = row_ptr[n], end = row_ptr[n + 1];
    float adn = a_d[n * H + hh];
    float m = -1e30f;
    for (int j = beg + lane; j < end; j += 64) {
        float sc = a_s[col[j] * H + hh] + adn;
        sc = sc > 0.f ? sc : 0.2f * sc;
        m = fmaxf(m, sc);
    }
    #pragma unroll
    for (int off = 32; off; off >>= 1) m = fmaxf(m, __shfl_xor(m, off));
    const _Float16* hb = h + (size_t)hh * 64 + lane;
    const size_t rs = (size_t)H * 64;
    float denom = 0.f;
    float acc0 = 0.f, acc1 = 0.f, acc2 = 0.f, acc3 = 0.f;
    float acc4 = 0.f, acc5 = 0.f, acc6 = 0.f, acc7 = 0.f;
    for (int base = beg; base < end; base += 64) {
        int j = base + lane;
        float w = 0.f; int s = 0;
        if (j < end) {
            s = col[j];
            float sc = a_s[s * H + hh] + adn;
            sc = sc > 0.f ? sc : 0.2f * sc;
            w = __expf(sc - m);
        }
        denom += w;
        uint2 p; p.x = __float_as_uint(w); p.y = (unsigned)s;
        wc[wave][lane] = p;   // same-wave DS ops are in-order; no barrier needed
        int cnt = min(64, end - base);
        int k = 0;
        for (; k + 8 <= cnt; k += 8) {
            uint2 p0 = wc[wave][k];
            uint2 p1 = wc[wave][k + 1];
            uint2 p2 = wc[wave][k + 2];
            uint2 p3 = wc[wave][k + 3];
            uint2 p4 = wc[wave][k + 4];
            uint2 p5 = wc[wave][k + 5];
            uint2 p6 = wc[wave][k + 6];
            uint2 p7 = wc[wave][k + 7];
            acc0 += __uint_as_float(p0.x) * (float)hb[(size_t)p0.y * rs];
            acc1 += __uint_as_float(p1.x) * (float)hb[(size_t)p1.y * rs];
            acc2 += __uint_as_float(p2.x) * (float)hb[(size_t)p2.y * rs];
            acc3 += __uint_as_float(p3.x) * (float)hb[(size_t)p3.y * rs];
            acc4 += __uint_as_float(p4.x) * (float)hb[(size_t)p4.y * rs];
            acc5 += __uint_as_float(p5.x) * (float)hb[(size_t)p5.y * rs];
            acc6 += __uint_as_float(p6.x) * (float)hb[(size_t)p6.y * rs];
            acc7 += __uint_as_float(p7.x) * (float)hb[(size_t)p7.y * rs];
        }
        for (; k < cnt; ++k) {
            uint2 p0 = wc[wave][k];
            acc0 += __uint_as_float(p0.x) * (float)hb[(size_t)p0.y * rs];
        }
    }
    float acc = ((acc0 + acc1) + (acc2 + acc3)) + ((acc4 + acc5) + (acc6 + acc7));
    #pragma unroll
    for (int off = 32; off; off >>= 1) denom += __shfl_xor(denom, off);
    atomicAdd(&out[n * 64 + lane], acc / ((denom + 1e-16f) * H));
}

// ------------------------------------------------------------------ BatchNorm
__global__ void bn_stats(const float* __restrict__ x, const float* __restrict__ gamma,
                         const float* __restrict__ beta, float* __restrict__ scale,
                         float* __restrict__ shift, int N) {
    int c = blockIdx.x;
    float s = 0.f, ss = 0.f;
    for (int r = threadIdx.x; r < N; r += 256) {
        float v = x[(size_t)r * 64 + c];
        s += v; ss += v * v;
    }
    #pragma unroll
    for (int off = 32; off; off >>= 1) {
        s  += __shfl_xor(s, off);
        ss += __shfl_xor(ss, off);
    }
    __shared__ float red[8];
    int wv = threadIdx.x >> 6, ln = threadIdx.x & 63;
    if (ln == 0) { red[wv] = s; red[4 + wv] = ss; }
    __syncthreads();
    if (threadIdx.x == 0) {
        float S  = red[0] + red[1] + red[2] + red[3];
        float SS = red[4] + red[5] + red[6] + red[7];
        float mu  = S / N;
        float var = SS / N - mu * mu;
        float istd = rsqrtf(var + 1e-5f);
        scale[c] = gamma[c] * istd;
        shift[c] = beta[c] - mu * gamma[c] * istd;
    }
}

// applies BN+ReLU to y, then re-zeros x (the gather accumulator) for the next layer.
// x and xz alias -> no __restrict__ on them.
__global__ void bn_apply(const float* x, const float* __restrict__ scale,
                         const float* __restrict__ shift, float* __restrict__ y,
                         float* xz, int total) {
    int i = blockIdx.x * 256 + threadIdx.x;
    if (i < total) {
        int c = i & 63;
        float v = x[i];
        y[i] = fmaxf(v * scale[c] + shift[c], 0.f);
        xz[i] = 0.f;
    }
}

// ------------------------------------------------------------------ MHA
// vh [N][64] f16 -> vt [64][N] f16 (row = h*16+d), LDS-tiled transpose
__global__ void vtrans(const _Float16* __restrict__ vh, _Float16* __restrict__ vt, int N) {
    __shared__ _Float16 tile[64][68];
    int kb = blockIdx.x * 64;
    int t  = threadIdx.x;
    {
        int r = t >> 2, c0 = (t & 3) * 16;
        half8_t x0 = *(const half8_t*)(vh + (size_t)(kb + r) * 64 + c0);
        half8_t x1 = *(const half8_t*)(vh + (size_t)(kb + r) * 64 + c0 + 8);
        #pragma unroll
        for (int i = 0; i < 8; ++i) { tile[r][c0 + i] = x0[i]; tile[r][c0 + 8 + i] = x1[i]; }
    }
    __syncthreads();
    {
        int c = t >> 2, ks = (t & 3) * 16;
        half8_t y0, y1;
        #pragma unroll
        for (int i = 0; i < 8; ++i) { y0[i] = tile[ks + i][c]; y1[i] = tile[ks + 8 + i][c]; }
        *(half8_t*)(vt + (size_t)c * N + kb + ks)     = y0;
        *(half8_t*)(vt + (size_t)c * N + kb + ks + 8) = y1;
    }
}

// kh [N][64] f16 -> khp [4][N][16] f16 (head-major rows, 32B per key)
__global__ void kpack(const _Float16* __restrict__ kh, _Float16* __restrict__ khp, int N) {
    int id = blockIdx.x * 256 + threadIdx.x;   // N*8 threads
    int n = id >> 3, c8 = (id & 7) * 8;
    half8_t v = *(const half8_t*)(kh + (size_t)n * 64 + c8);
    int h = c8 >> 4, d0 = c8 & 15;
    *(half8_t*)(khp + ((size_t)h * N + n) * 16 + d0) = v;
}

// Block = 8 waves / 512 thr, one head, 64 queries; grp 0 = even 64-key tiles,
// grp 1 = odd. Double-buffered LDS; exp2-domain softmax with defer-max (THR=8);
// deterministic in-block merge. Kt pad 18 (36B stride, odd bank count -> <=2-way).
__global__ __launch_bounds__(512) void mha_fa4(const _Float16* __restrict__ qh,
                                               const _Float16* __restrict__ khp,
                                               const _Float16* __restrict__ vt,
                                               float* __restrict__ ao, int N) {
    __shared__ _Float16 Kt[2][2][64][18];   // [grp][buf][key][ch]
    __shared__ _Float16 Vt[2][2][16][70];   // [grp][buf][ch][key]
    __shared__ float MB[4][2][16];          // [wsub][{m,l}][q]
    __shared__ float OB[4][16][17];         // [wsub][d][q]
    int h    = blockIdx.y;
    int t    = threadIdx.x;
    int lane = t & 63;
    int wave = t >> 6;
    int grp  = wave >> 2;
    int wsub = wave & 3;
    int lo16 = lane & 15;
    int g    = lane >> 4;
    int q    = blockIdx.x * 64 + wsub * 16 + lo16;

    half4_t qf = *(const half4_t*)(qh + (size_t)q * 64 + h * 16 + g * 4);
    const _Float16* kp = khp + (size_t)h * N * 16;
    const _Float16* vp = vt + (size_t)h * 16 * N;

    int tg = t & 255;
    int skey = tg >> 2, sch = (tg & 3) * 4;   // K staging coords
    int sd = tg >> 4, skv = (tg & 15) * 4;    // V staging coords

    {   // prologue: stage this group's tile 0
        int kt = grp * 64;
        *(half4_t*)&Kt[grp][0][skey][sch] = *(const half4_t*)(kp + (size_t)(kt + skey) * 16 + sch);
        *(half4_t*)&Vt[grp][0][sd][skv]   = *(const half4_t*)(vp + (size_t)sd * N + kt + skv);
    }

    float m = -1e30f, l = 0.f;
    f32x4 o = {0.f, 0.f, 0.f, 0.f};
    const f32x4 zero = {0.f, 0.f, 0.f, 0.f};
    int nit = N / 128;

    for (int it = 0; it < nit; ++it) {
        int cur = it & 1;
        __syncthreads();
        if (it + 1 < nit) {
            int kt = ((it + 1) * 2 + grp) * 64;
            *(half4_t*)&Kt[grp][cur ^ 1][skey][sch] = *(const half4_t*)(kp + (size_t)(kt + skey) * 16 + sch);
            *(half4_t*)&Vt[grp][cur ^ 1][sd][skv]   = *(const half4_t*)(vp + (size_t)sd * N + kt + skv);
        }
        // ---- QK^T: 4 sub-tiles of 16 keys (scores already in log2 domain)
        f32x4 s[4];
        __builtin_amdgcn_s_setprio(1);
        #pragma unroll
        for (int st = 0; st < 4; ++st) {
            half4_t kf = *(const half4_t*)&Kt[grp][cur][st * 16 + lo16][g * 4];
            s[st] = __builtin_amdgcn_mfma_f32_16x16x16f16(kf, qf, zero, 0, 0, 0);
        }
        __builtin_amdgcn_s_setprio(0);
        // ---- online softmax, defer-max (THR=8 in log2 domain)
        float t0 = fmaxf(fmaxf(s[0][0], s[0][1]), s[0][2]);
        float t1 = fmaxf(fmaxf(s[0][3], s[1][0]), s[1][1]);
        float t2 = fmaxf(fmaxf(s[1][2], s[1][3]), s[2][0]);
        float t3 = fmaxf(fmaxf(s[2][1], s[2][2]), s[2][3]);
        float t4 = fmaxf(fmaxf(s[3][0], s[3][1]), fmaxf(s[3][2], s[3][3]));
        float tm = fmaxf(fmaxf(fmaxf(t0, t1), fmaxf(t2, t3)), t4);
        tm = fmaxf(tm, __shfl_xor(tm, 16));
        tm = fmaxf(tm, __shfl_xor(tm, 32));
        if (!__all(tm <= m + 8.f)) {
            float mnew = fmaxf(m, tm);
            float r = EXP2N(m - mnew);
            l *= r;
            #pragma unroll
            for (int i = 0; i < 4; ++i) o[i] *= r;
            m = mnew;
        }
        float lsum = 0.f;
        half4_t pf[4];
        #pragma unroll
        for (int st = 0; st < 4; ++st) {
            float p0 = EXP2N(s[st][0] - m);
            float p1 = EXP2N(s[st][1] - m);
            float p2 = EXP2N(s[st][2] - m);
            float p3 = EXP2N(s[st][3] - m);
            lsum += (p0 + p1) + (p2 + p3);
            auto lo = __builtin_amdgcn_cvt_pkrtz(p0, p1);   // __fp16x2
            auto hi = __builtin_amdgcn_cvt_pkrtz(p2, p3);
            pf[st][0] = (_Float16)lo[0]; pf[st][1] = (_Float16)lo[1];
            pf[st][2] = (_Float16)hi[0]; pf[st][3] = (_Float16)hi[1];
        }
        l += lsum;
        // ---- PV
        __builtin_amdgcn_s_setprio(1);
        #pragma unroll
        for (int st = 0; st < 4; ++st) {
            half4_t vf = *(const half4_t*)&Vt[grp][cur][lo16][st * 16 + g * 4];
            o = __builtin_amdgcn_mfma_f32_16x16x16f16(vf, pf[st], o, 0, 0, 0);
        }
        __builtin_amdgcn_s_setprio(0);
    }
    // per-wave l reduce across the 4 lane-groups (disjoint key subsets)
    l += __shfl_xor(l, 16);
    l += __shfl_xor(l, 32);

    if (grp == 1) {   // publish partial state
        if (lane < 16) { MB[wsub][0][lane] = m; MB[wsub][1][lane] = l; }
        #pragma unroll
        for (int i = 0; i < 4; ++i) OB[wsub][g * 4 + i][lo16] = o[i];
    }
    __syncthreads();
    if (grp == 0) {   // deterministic merge: grp0 then grp1
        float m1 = MB[wsub][0][lo16];
        float l1 = MB[wsub][1][lo16];
        float M  = fmaxf(m, m1);
        float e0 = EXP2N(m - M), e1 = EXP2N(m1 - M);
        float inv = 1.f / (l * e0 + l1 * e1);
        f32x4 res;
        #pragma unroll
        for (int i = 0; i < 4; ++i)
            res[i] = (o[i] * e0 + OB[wsub][g * 4 + i][lo16] * e1) * inv;
        *(f32x4*)(ao + (size_t)q * 64 + h * 16 + g * 4) = res;
    }
}

// ------------------------------------------------------------------- host side
static inline void launch_gemm(const float* A, const float* B, const float* bias, float* C,
                               int M, int Nc, int K, bool transB, int act, hipStream_t st) {
    dim3 grid((Nc + 63) / 64, M / 64), blk(256);
    if (!transB)       gemm_f32<false, 0><<<grid, blk, 0, st>>>(A, B, bias, C, M, Nc, K);
    else if (act == 0) gemm_f32<true, 0><<<grid, blk, 0, st>>>(A, B, bias, C, M, Nc, K);
    else               gemm_f32<true, 1><<<grid, blk, 0, st>>>(A, B, bias, C, M, Nc, K);
}

extern "C" void kernel_launch(void* const* d_in, const int* in_sizes, int n_in,
                              void* d_out, int out_size, void* d_ws, size_t ws_size,
                              hipStream_t stream) {
    const int N = NN, E = EE;
    const float* x    = (const float*)d_in[0];
    const int*   ei   = (const int*)d_in[1];
    const float* W[3]   = {(const float*)d_in[2], (const float*)d_in[6], (const float*)d_in[10]};
    const float* as_[3] = {(const float*)d_in[3], (const float*)d_in[7], (const float*)d_in[11]};
    const float* ad_[3] = {(const float*)d_in[4], (const float*)d_in[8], (const float*)d_in[12]};
    const float* bn_g = (const float*)d_in[14];
    const float* bn_b = (const float*)d_in[15];
    const float* Wq = (const float*)d_in[16];
    const float* Wk = (const float*)d_in[17];
    const float* Wv = (const float*)d_in[18];
    const float* Wo = (const float*)d_in[19];
    const float* bq = (const float*)d_in[20];
    const float* bk = (const float*)d_in[21];
    const float* bv = (const float*)d_in[22];
    const float* bo = (const float*)d_in[23];
    const float* Wc1 = (const float*)d_in[24];
    const float* bc1 = (const float*)d_in[25];
    const float* Wc2 = (const float*)d_in[26];
    const float* bc2 = (const float*)d_in[27];

    char* ws = (char*)d_ws;
    _Float16* h16 = (_Float16*)(ws + 0);       // 8192*512*2 = 8,388,608 (GAT phase)
    _Float16* qh = (_Float16*)(ws + 9437184);  // 1,048,576 (MHA phase)
    _Float16* kh = (_Float16*)(ws + 10485760); // 1,048,576
    _Float16* vh = (_Float16*)(ws + 11534336); // 1,048,576
    _Float16* vt = (_Float16*)(ws + 12582912); // 1,048,576
    _Float16* khp = (_Float16*)(ws + 13631488);// 1,048,576
    float* a_s  = (float*)(ws + 16777216);     // 262,144
    float* a_d  = (float*)(ws + 17039360);     // 262,144
    int* row_ptr = (int*)(ws + 17301504);      // 33,024
    int* cursor  = (int*)(ws + 17334528);      // 32,768
    int* deg     = (int*)(ws + 17367296);      // 32,768
    int* col     = (int*)(ws + 17400064);      // 1,081,344
    float* xg   = (float*)(ws + 18481408);     // 2,097,152
    float* xb   = (float*)(ws + 20578560);     // 2,097,152
    float* ao   = (float*)(ws + 28967168);     // 2,097,152
    float* c1   = (float*)(ws + 31064320);     // 1,048,576
    float* bnscale = (float*)(ws + 32112896);  // 64
    float* bnshift = bnscale + 64;             // 64

    // ---- CSR build (same graph all layers); self-loops via deg init = 1
    k_fill_i32<<<(N + 255) / 256, 256, 0, stream>>>(deg, 1, N);
    count_deg<<<(E + 255) / 256, 256, 0, stream>>>(ei, deg, E);
    scan_deg<<<1, 1024, 0, stream>>>(deg, row_ptr, cursor, N);
    fill_csr<<<(E + N + 255) / 256, 256, 0, stream>>>(ei, cursor, col, E, N);

    // ---- 3 GAT layers (+BN+ReLU).  GAT bias cancels through BN -> skipped.
    // gat_coef is fused into the GEMM epilogue; bn_apply re-zeros xg for next layer.
    hipMemsetAsync(xg, 0, (size_t)N * 64 * 4, stream);
    const int heads[3] = {8, 8, 1};
    const int fins[3]  = {128, 64, 64};
    const float* xin = x;
    for (int i = 0; i < 3; ++i) {
        int H = heads[i], K = fins[i];
        mfma_gemm<false, true, 0, true><<<dim3(H, N / 64), 256, 0, stream>>>(
            xin, W[i], nullptr, h16, N, H * 64, K, 1.f, as_[i], ad_[i], a_s, a_d, H);
        gat_gather3<<<(N * H) / 4, 256, 0, stream>>>(h16, a_s, a_d, row_ptr, col, xg, N, H);
        bn_stats<<<64, 256, 0, stream>>>(xg, bn_g + i * 64, bn_b + i * 64, bnscale, bnshift, N);
        bn_apply<<<(N * 64) / 256, 256, 0, stream>>>(xg, bnscale, bnshift, xb, xg, N * 64);
        xin = xb;
    }

    // ---- MHA (4 heads, hd=16): f16 Q/K/V from MFMA GEMM; exp2-domain flash
    // Q scale = 0.25 (1/sqrt(hd)) * log2(e) -> softmax in exp2 domain
    mfma_gemm<true, true, 0, false><<<dim3(1, N / 64), 256, 0, stream>>>(
        xb, Wq, bq, qh, N, 64, 64, 0.36067376f, nullptr, nullptr, nullptr, nullptr, 0);
    mfma_gemm<true, true, 0, false><<<dim3(1, N / 64), 256, 0, stream>>>(
        xb, Wk, bk, kh, N, 64, 64, 1.f, nullptr, nullptr, nullptr, nullptr, 0);
    mfma_gemm<true, true, 0, false><<<dim3(1, N / 64), 256, 0, stream>>>(
        xb, Wv, bv, vh, N, 64, 64, 1.f, nullptr, nullptr, nullptr, nullptr, 0);
    vtrans<<<N / 64, 256, 0, stream>>>(vh, vt, N);
    kpack<<<N * 8 / 256, 256, 0, stream>>>(kh, khp, N);
    mha_fa4<<<dim3(N / 64, 4), 512, 0, stream>>>(qh, khp, vt, ao, N);
    mfma_gemm<true, false, 0, false><<<dim3(1, N / 64), 256, 0, stream>>>(
        ao, Wo, bo, xg, N, 64, 64, 1.f, nullptr, nullptr, nullptr, nullptr, 0);

    // ---- classifier (small Nc: f32 path)
    launch_gemm(xg, Wc1, bc1, c1, N, 32, 64, true, 1, stream);
    launch_gemm(c1, Wc2, bc2, (float*)d_out, N, 10, 32, true, 0, stream);
}

// Round 10
// 359.569 us; speedup vs baseline: 2.3631x; 1.0479x over previous
//
#include <hip/hip_runtime.h>
#include <hip/hip_bf16.h>

#define NN 8192
#define EE 262144
#define HID 64

typedef _Float16 half4_t __attribute__((ext_vector_type(4)));
typedef _Float16 half8_t __attribute__((ext_vector_type(8)));
typedef float f32x4 __attribute__((ext_vector_type(4)));

extern "C" __device__ float __ocml_native_exp2_f32(float);
#define EXP2N(x) __ocml_native_exp2_f32(x)

// ---------------------------------------------------------------- GEMM (f32, small Nc)
template<bool TRANS_B, int ACT>
__global__ void gemm_f32(const float* __restrict__ A, const float* __restrict__ B,
                         const float* __restrict__ bias, float* __restrict__ C,
                         int M, int Nc, int K) {
    __shared__ float As[16][65];
    __shared__ float Bs[16][65];
    int tid = threadIdx.x;
    int brow = blockIdx.y * 64, bcol = blockIdx.x * 64;
    int tr = (tid / 16) * 4;
    int tc = (tid % 16) * 4;
    float acc[4][4] = {};
    for (int k0 = 0; k0 < K; k0 += 16) {
        {   // A tile 64x16
            int r  = tid / 4;
            int kk = (tid % 4) * 4;
            const float* a = A + (size_t)(brow + r) * K + k0 + kk;
            #pragma unroll
            for (int j = 0; j < 4; ++j) As[kk + j][r] = a[j];
        }
        if (!TRANS_B) {   // B[K][Nc]
            int kk = tid / 16;
            int n4 = (tid % 16) * 4;
            #pragma unroll
            for (int j = 0; j < 4; ++j) {
                int n = bcol + n4 + j;
                Bs[kk][n4 + j] = (n < Nc) ? B[(size_t)(k0 + kk) * Nc + n] : 0.f;
            }
        } else {          // B[Nc][K]
            int n  = tid / 4;
            int kk = (tid % 4) * 4;
            #pragma unroll
            for (int j = 0; j < 4; ++j)
                Bs[kk + j][n] = (bcol + n < Nc) ? B[(size_t)(bcol + n) * K + k0 + kk + j] : 0.f;
        }
        __syncthreads();
        #pragma unroll
        for (int kk = 0; kk < 16; ++kk) {
            float av[4], bv[4];
            #pragma unroll
            for (int i = 0; i < 4; ++i) av[i] = As[kk][tr + i];
            #pragma unroll
            for (int j = 0; j < 4; ++j) bv[j] = Bs[kk][tc + j];
            #pragma unroll
            for (int i = 0; i < 4; ++i)
                #pragma unroll
                for (int j = 0; j < 4; ++j)
                    acc[i][j] += av[i] * bv[j];
        }
        __syncthreads();
    }
    #pragma unroll
    for (int i = 0; i < 4; ++i) {
        int r = brow + tr + i;
        #pragma unroll
        for (int j = 0; j < 4; ++j) {
            int c = bcol + tc + j;
            if (c < Nc) {
                float v = acc[i][j];
                if (bias) v += bias[c];
                if (ACT == 1) v = fmaxf(v, 0.f);
                C[(size_t)r * Nc + c] = v;
            }
        }
    }
}

// ---------------------------------------------------------------- MFMA GEMM body
// (f16 inputs staged in LDS, f32 acc). Fragment conventions as verified:
//   mfma(X,Y,C): D[r][c] = sum_k X[r][k]*Y[c][k]; frag lane: [lane&15][4*(lane>>4)+i]
template<bool TRANS_B, bool OUT_F16, int ACT, bool GAT>
__device__ __forceinline__ void mfma_gemm_body(
        const float* __restrict__ A, const float* __restrict__ B,
        const float* __restrict__ bias, void* __restrict__ Cout,
        int M, int Nc, int K, float scale, int brow, int bcol,
        const float* __restrict__ att_s, const float* __restrict__ att_d,
        float* __restrict__ a_s, float* __restrict__ a_d, int H) {
    __shared__ _Float16 Ah[64][36];
    __shared__ _Float16 Bt[64][36];
    int tid  = threadIdx.x;
    int wave = tid >> 6, lane = tid & 63, lo16 = lane & 15, g = lane >> 4;
    f32x4 acc[4];
    #pragma unroll
    for (int i = 0; i < 4; ++i) acc[i] = (f32x4){0.f, 0.f, 0.f, 0.f};

    for (int k0 = 0; k0 < K; k0 += 32) {
        {   // stage A 64x32 -> f16
            int r  = tid >> 2;
            int ks = (tid & 3) * 8;
            const float* ap = A + (size_t)(brow + r) * K + k0 + ks;
            f32x4 a0 = *(const f32x4*)ap;
            f32x4 a1 = *(const f32x4*)(ap + 4);
            half4_t h0, h1;
            #pragma unroll
            for (int i = 0; i < 4; ++i) { h0[i] = (_Float16)a0[i]; h1[i] = (_Float16)a1[i]; }
            *(half4_t*)&Ah[r][ks]     = h0;
            *(half4_t*)&Ah[r][ks + 4] = h1;
        }
        if (TRANS_B) {   // B[Nc][K] -> Bt[n][k]
            int n  = tid >> 2;
            int ks = (tid & 3) * 8;
            const float* bp = B + (size_t)(bcol + n) * K + k0 + ks;
            f32x4 b0 = *(const f32x4*)bp;
            f32x4 b1 = *(const f32x4*)(bp + 4);
            half4_t h0, h1;
            #pragma unroll
            for (int i = 0; i < 4; ++i) { h0[i] = (_Float16)b0[i]; h1[i] = (_Float16)b1[i]; }
            *(half4_t*)&Bt[n][ks]     = h0;
            *(half4_t*)&Bt[n][ks + 4] = h1;
        } else {         // B[K][Nc] -> Bt[n][k] (transpose during staging)
            int n  = tid & 63;
            int kb = (tid >> 6) * 8;
            half4_t h0, h1;
            #pragma unroll
            for (int i = 0; i < 4; ++i)
                h0[i] = (_Float16)B[(size_t)(k0 + kb + i) * Nc + bcol + n];
            #pragma unroll
            for (int i = 0; i < 4; ++i)
                h1[i] = (_Float16)B[(size_t)(k0 + kb + 4 + i) * Nc + bcol + n];
            *(half4_t*)&Bt[n][kb]     = h0;
            *(half4_t*)&Bt[n][kb + 4] = h1;
        }
        __syncthreads();
        #pragma unroll
        for (int kh = 0; kh < 2; ++kh) {
            half4_t af = *(const half4_t*)&Ah[wave * 16 + lo16][kh * 16 + g * 4];
            #pragma unroll
            for (int cf = 0; cf < 4; ++cf) {
                half4_t bf = *(const half4_t*)&Bt[cf * 16 + lo16][kh * 16 + g * 4];
                acc[cf] = __builtin_amdgcn_mfma_f32_16x16x16f16(af, bf, acc[cf], 0, 0, 0);
            }
        }
        __syncthreads();
    }
    int rbase = brow + wave * 16 + g * 4;
    #pragma unroll
    for (int cf = 0; cf < 4; ++cf) {
        int c = bcol + cf * 16 + lo16;
        float bv = bias ? bias[c] : 0.f;
        #pragma unroll
        for (int reg = 0; reg < 4; ++reg) {
            float v = (acc[cf][reg] + bv) * scale;
            if (ACT == 1) v = fmaxf(v, 0.f);
            if (OUT_F16) ((_Float16*)Cout)[(size_t)(rbase + reg) * Nc + c] = (_Float16)v;
            else         ((float*)Cout)[(size_t)(rbase + reg) * Nc + c] = v;
        }
    }
    if (GAT) {
        float as_c[4], ad_c[4];
        #pragma unroll
        for (int cf = 0; cf < 4; ++cf) {
            int c = bcol + cf * 16 + lo16;
            as_c[cf] = att_s[c];
            ad_c[cf] = att_d[c];
        }
        int head = bcol >> 6;
        #pragma unroll
        for (int reg = 0; reg < 4; ++reg) {
            float ps = 0.f, pd = 0.f;
            #pragma unroll
            for (int cf = 0; cf < 4; ++cf) {
                ps += acc[cf][reg] * as_c[cf];
                pd += acc[cf][reg] * ad_c[cf];
            }
            #pragma unroll
            for (int off = 8; off; off >>= 1) {
                ps += __shfl_xor(ps, off);
                pd += __shfl_xor(pd, off);
            }
            if (lo16 == 0) {
                int row = rbase + reg;
                a_s[row * H + head] = ps;
                a_d[row * H + head] = pd;
            }
        }
    }
}

template<bool TRANS_B, bool OUT_F16, int ACT, bool GAT>
__global__ void mfma_gemm(const float* __restrict__ A, const float* __restrict__ B,
                          const float* __restrict__ bias, void* __restrict__ Cout,
                          int M, int Nc, int K, float scale,
                          const float* __restrict__ att_s, const float* __restrict__ att_d,
                          float* __restrict__ a_s, float* __restrict__ a_d, int H) {
    mfma_gemm_body<TRANS_B, OUT_F16, ACT, GAT>(A, B, bias, Cout, M, Nc, K, scale,
                                               blockIdx.y * 64, blockIdx.x * 64,
                                               att_s, att_d, a_s, a_d, H);
}

// fused Q/K/V projection: blockIdx.z selects weight/bias/output/scale
__global__ void qkv_gemm(const float* __restrict__ A,
                         const float* __restrict__ Wq, const float* __restrict__ Wk,
                         const float* __restrict__ Wv, const float* __restrict__ bq,
                         const float* __restrict__ bk, const float* __restrict__ bv,
                         _Float16* __restrict__ qh, _Float16* __restrict__ kh,
                         _Float16* __restrict__ vh, int M, float qscale) {
    int z = blockIdx.z;
    const float* B    = z == 0 ? Wq : (z == 1 ? Wk : Wv);
    const float* bias = z == 0 ? bq : (z == 1 ? bk : bv);
    _Float16* Cout    = z == 0 ? qh : (z == 1 ? kh : vh);
    float scale       = z == 0 ? qscale : 1.f;
    mfma_gemm_body<true, true, 0, false>(A, B, bias, Cout, M, 64, 64, scale,
                                         blockIdx.y * 64, 0,
                                         nullptr, nullptr, nullptr, nullptr, 0);
}

// ------------------------------------------------------------------ GAT prep
__global__ void count_deg(const int* __restrict__ ei, int* __restrict__ deg, int E) {
    int e = blockIdx.x * 256 + threadIdx.x;
    if (e < E) atomicAdd(&deg[ei[E + e]], 1);   // ei[1] row = dst
}

// single block, 1024 threads, N=8192 (8 per thread); +1 per node = self-loop
__global__ void scan_deg(const int* __restrict__ deg, int* __restrict__ row_ptr,
                         int* __restrict__ cursor, int N) {
    __shared__ int tmp[1024];
    int tid = threadIdx.x;
    int base = tid * 8;
    int local[8];
    int s = 0;
    #pragma unroll
    for (int j = 0; j < 8; ++j) { local[j] = deg[base + j] + 1; s += local[j]; }
    tmp[tid] = s;
    __syncthreads();
    for (int off = 1; off < 1024; off <<= 1) {
        int add = (tid >= off) ? tmp[tid - off] : 0;
        __syncthreads();
        tmp[tid] += add;
        __syncthreads();
    }
    int run = tmp[tid] - s;   // exclusive prefix of this chunk
    #pragma unroll
    for (int j = 0; j < 8; ++j) {
        row_ptr[base + j] = run;
        cursor[base + j]  = run;
        run += local[j];
    }
    if (tid == 1023) row_ptr[N] = run;
}

__global__ void fill_csr(const int* __restrict__ ei, int* __restrict__ cursor,
                         int* __restrict__ col, int E, int N) {
    int e = blockIdx.x * 256 + threadIdx.x;
    if (e < E) {
        int dst = ei[E + e];
        int pos = atomicAdd(&cursor[dst], 1);
        col[pos] = ei[e];
    } else if (e < E + N) {
        int n = e - E;
        int pos = atomicAdd(&cursor[n], 1);
        col[pos] = n;
    }
}

// ---------------------------------------------------------------- GAT gather
// wave per (dst n, head h); per-wave LDS stash of (w,col); uniform ds broadcasts,
// 8 independent FMA chains. f16 h. atomicAdd head-mean (order noise ~1e-6).
__global__ void gat_gather3(const _Float16* __restrict__ h, const float* __restrict__ a_s,
                            const float* __restrict__ a_d, const int* __restrict__ row_ptr,
                            const int* __restrict__ col, float* __restrict__ out,
                            int N, int H) {
    __shared__ uint2 wc[4][64];
    int t    = threadIdx.x;
    int wave = t >> 6;
    int lane = t & 63;
    int wid  = (blockIdx.x * 256 + t) >> 6;
    if (wid >= N * H) return;
    int n = wid / H, hh = wid % H;
    int beg = row_ptr[n], end = row_ptr[n + 1];
    float adn = a_d[n * H + hh];
    float m = -1e30f;
    for (int j = beg + lane; j < end; j += 64) {
        float sc = a_s[col[j] * H + hh] + adn;
        sc = sc > 0.f ? sc : 0.2f * sc;
        m = fmaxf(m, sc);
    }
    #pragma unroll
    for (int off = 32; off; off >>= 1) m = fmaxf(m, __shfl_xor(m, off));
    const _Float16* hb = h + (size_t)hh * 64 + lane;
    const size_t rs = (size_t)H * 64;
    float denom = 0.f;
    float acc0 = 0.f, acc1 = 0.f, acc2 = 0.f, acc3 = 0.f;
    float acc4 = 0.f, acc5 = 0.f, acc6 = 0.f, acc7 = 0.f;
    for (int base = beg; base < end; base += 64) {
        int j = base + lane;
        float w = 0.f; int s = 0;
        if (j < end) {
            s = col[j];
            float sc = a_s[s * H + hh] + adn;
            sc = sc > 0.f ? sc : 0.2f * sc;
            w = __expf(sc - m);
        }
        denom += w;
        uint2 p; p.x = __float_as_uint(w); p.y = (unsigned)s;
        wc[wave][lane] = p;   // same-wave DS ops are in-order; no barrier needed
        int cnt = min(64, end - base);
        int k = 0;
        for (; k + 8 <= cnt; k += 8) {
            uint2 p0 = wc[wave][k];
            uint2 p1 = wc[wave][k + 1];
            uint2 p2 = wc[wave][k + 2];
            uint2 p3 = wc[wave][k + 3];
            uint2 p4 = wc[wave][k + 4];
            uint2 p5 = wc[wave][k + 5];
            uint2 p6 = wc[wave][k + 6];
            uint2 p7 = wc[wave][k + 7];
            acc0 += __uint_as_float(p0.x) * (float)hb[(size_t)p0.y * rs];
            acc1 += __uint_as_float(p1.x) * (float)hb[(size_t)p1.y * rs];
            acc2 += __uint_as_float(p2.x) * (float)hb[(size_t)p2.y * rs];
            acc3 += __uint_as_float(p3.x) * (float)hb[(size_t)p3.y * rs];
            acc4 += __uint_as_float(p4.x) * (float)hb[(size_t)p4.y * rs];
            acc5 += __uint_as_float(p5.x) * (float)hb[(size_t)p5.y * rs];
            acc6 += __uint_as_float(p6.x) * (float)hb[(size_t)p6.y * rs];
            acc7 += __uint_as_float(p7.x) * (float)hb[(size_t)p7.y * rs];
        }
        for (; k < cnt; ++k) {
            uint2 p0 = wc[wave][k];
            acc0 += __uint_as_float(p0.x) * (float)hb[(size_t)p0.y * rs];
        }
    }
    float acc = ((acc0 + acc1) + (acc2 + acc3)) + ((acc4 + acc5) + (acc6 + acc7));
    #pragma unroll
    for (int off = 32; off; off >>= 1) denom += __shfl_xor(denom, off);
    atomicAdd(&out[n * 64 + lane], acc / ((denom + 1e-16f) * H));
}

// ------------------------------------------------------------------ BatchNorm
__global__ void bn_stats(const float* __restrict__ x, const float* __restrict__ gamma,
                         const float* __restrict__ beta, float* __restrict__ scale,
                         float* __restrict__ shift, int N) {
    int c = blockIdx.x;
    float s = 0.f, ss = 0.f;
    for (int r = threadIdx.x; r < N; r += 256) {
        float v = x[(size_t)r * 64 + c];
        s += v; ss += v * v;
    }
    #pragma unroll
    for (int off = 32; off; off >>= 1) {
        s  += __shfl_xor(s, off);
        ss += __shfl_xor(ss, off);
    }
    __shared__ float red[8];
    int wv = threadIdx.x >> 6, ln = threadIdx.x & 63;
    if (ln == 0) { red[wv] = s; red[4 + wv] = ss; }
    __syncthreads();
    if (threadIdx.x == 0) {
        float S  = red[0] + red[1] + red[2] + red[3];
        float SS = red[4] + red[5] + red[6] + red[7];
        float mu  = S / N;
        float var = SS / N - mu * mu;
        float istd = rsqrtf(var + 1e-5f);
        scale[c] = gamma[c] * istd;
        shift[c] = beta[c] - mu * gamma[c] * istd;
    }
}

// applies BN+ReLU to y, then re-zeros x (the gather accumulator) for the next layer.
__global__ void bn_apply(const float* x, const float* __restrict__ scale,
                         const float* __restrict__ shift, float* __restrict__ y,
                         float* xz, int total) {
    int i = blockIdx.x * 256 + threadIdx.x;
    if (i < total) {
        int c = i & 63;
        float v = x[i];
        y[i] = fmaxf(v * scale[c] + shift[c], 0.f);
        xz[i] = 0.f;
    }
}

// ------------------------------------------------------------------ MHA prep
// fused: vh [N][64] -> vt [64][N] (transpose) AND kh [N][64] -> khp [4][N][16]
__global__ void vkpack(const _Float16* __restrict__ vh, const _Float16* __restrict__ kh,
                       _Float16* __restrict__ vt, _Float16* __restrict__ khp, int N) {
    __shared__ _Float16 tile[64][68];
    int kb = blockIdx.x * 64;
    int t  = threadIdx.x;
    {
        int r = t >> 2, c0 = (t & 3) * 16;
        half8_t x0 = *(const half8_t*)(vh + (size_t)(kb + r) * 64 + c0);
        half8_t x1 = *(const half8_t*)(vh + (size_t)(kb + r) * 64 + c0 + 8);
        #pragma unroll
        for (int i = 0; i < 8; ++i) { tile[r][c0 + i] = x0[i]; tile[r][c0 + 8 + i] = x1[i]; }
    }
    // kpack (independent of the transpose; no sync needed yet)
    #pragma unroll
    for (int rep = 0; rep < 2; ++rep) {
        int l = t + 256 * rep;
        int n = kb + (l >> 3), c8 = (l & 7) * 8;
        half8_t v = *(const half8_t*)(kh + (size_t)n * 64 + c8);
        *(half8_t*)(khp + ((size_t)(c8 >> 4) * N + n) * 16 + (c8 & 15)) = v;
    }
    __syncthreads();
    {
        int c = t >> 2, ks = (t & 3) * 16;
        half8_t y0, y1;
        #pragma unroll
        for (int i = 0; i < 8; ++i) { y0[i] = tile[ks + i][c]; y1[i] = tile[ks + 8 + i][c]; }
        *(half8_t*)(vt + (size_t)c * N + kb + ks)     = y0;
        *(half8_t*)(vt + (size_t)c * N + kb + ks + 8) = y1;
    }
}

// Block = 8 waves / 512 thr, one head, 32 queries (2 q-subtiles x 4-way key split).
// Group grp (2 waves) processes tiles grp, grp+4, ... ; double-buffered LDS;
// exp2-domain softmax with defer-max; deterministic fixed-order 4-way merge
// (merge buffers OVERLAY the Kt region after a post-loop barrier).
__global__ __launch_bounds__(512) void mha_fa5(const _Float16* __restrict__ qh,
                                               const _Float16* __restrict__ khp,
                                               const _Float16* __restrict__ vt,
                                               float* __restrict__ ao, int N) {
    __shared__ alignas(16) char smem[38912];
    typedef _Float16 (*KtT)[2][64][20];   // [grp][buf][key][ch]   20480 B
    typedef _Float16 (*VtT)[2][16][68];   // [grp][buf][ch][key]   17408 B
    KtT Kt = (KtT)smem;
    VtT Vt = (VtT)(smem + 20480);
    float* MBp = (float*)(smem + 37888);  // [wsub][grp][2][16] = 1024 B
    float* OBp = (float*)smem;            // overlay on Kt: [wsub][grp][16][17] f32 = 8704 B

    int h    = blockIdx.y;
    int t    = threadIdx.x;
    int lane = t & 63;
    int wave = t >> 6;
    int grp  = wave >> 1;
    int wsub = wave & 1;
    int lo16 = lane & 15;
    int g    = lane >> 4;
    int q    = blockIdx.x * 32 + wsub * 16 + lo16;

    half4_t qf = *(const half4_t*)(qh + (size_t)q * 64 + h * 16 + g * 4);
    const _Float16* kp = khp + (size_t)h * N * 16;
    const _Float16* vp = vt + (size_t)h * 16 * N;

    int gt   = t & 127;                   // thread id within the group (2 waves)
    int skey = gt >> 1, sch = (gt & 1) * 8;   // K staging: 16B per thread
    int sd   = gt >> 3, skv = (gt & 7) * 8;   // V staging: 16B per thread

    {   // prologue: stage this group's tile 0
        int kt = grp * 64;
        half8_t kv = *(const half8_t*)(kp + (size_t)(kt + skey) * 16 + sch);
        half8_t vv = *(const half8_t*)(vp + (size_t)sd * N + kt + skv);
        half4_t a, b, c, d;
        #pragma unroll
        for (int i = 0; i < 4; ++i) { a[i] = kv[i]; b[i] = kv[4 + i]; c[i] = vv[i]; d[i] = vv[4 + i]; }
        *(half4_t*)&Kt[grp][0][skey][sch]     = a;
        *(half4_t*)&Kt[grp][0][skey][sch + 4] = b;
        *(half4_t*)&Vt[grp][0][sd][skv]       = c;
        *(half4_t*)&Vt[grp][0][sd][skv + 4]   = d;
    }

    float m = -1e30f, l = 0.f;
    f32x4 o = {0.f, 0.f, 0.f, 0.f};
    const f32x4 zero = {0.f, 0.f, 0.f, 0.f};
    const int nit = N / 256;              // 4 groups x 64 keys

    for (int it = 0; it < nit; ++it) {
        int cur = it & 1;
        __syncthreads();
        if (it + 1 < nit) {
            int kt = ((it + 1) * 4 + grp) * 64;
            half8_t kv = *(const half8_t*)(kp + (size_t)(kt + skey) * 16 + sch);
            half8_t vv = *(const half8_t*)(vp + (size_t)sd * N + kt + skv);
            half4_t a, b, c, d;
            #pragma unroll
            for (int i = 0; i < 4; ++i) { a[i] = kv[i]; b[i] = kv[4 + i]; c[i] = vv[i]; d[i] = vv[4 + i]; }
            *(half4_t*)&Kt[grp][cur ^ 1][skey][sch]     = a;
            *(half4_t*)&Kt[grp][cur ^ 1][skey][sch + 4] = b;
            *(half4_t*)&Vt[grp][cur ^ 1][sd][skv]       = c;
            *(half4_t*)&Vt[grp][cur ^ 1][sd][skv + 4]   = d;
        }
        // ---- QK^T: 4 sub-tiles of 16 keys (scores in log2 domain)
        f32x4 s[4];
        __builtin_amdgcn_s_setprio(1);
        #pragma unroll
        for (int st = 0; st < 4; ++st) {
            half4_t kf = *(const half4_t*)&Kt[grp][cur][st * 16 + lo16][g * 4];
            s[st] = __builtin_amdgcn_mfma_f32_16x16x16f16(kf, qf, zero, 0, 0, 0);
        }
        __builtin_amdgcn_s_setprio(0);
        // ---- online softmax, defer-max (THR=8 in log2 domain)
        float t0 = fmaxf(fmaxf(s[0][0], s[0][1]), s[0][2]);
        float t1 = fmaxf(fmaxf(s[0][3], s[1][0]), s[1][1]);
        float t2 = fmaxf(fmaxf(s[1][2], s[1][3]), s[2][0]);
        float t3 = fmaxf(fmaxf(s[2][1], s[2][2]), s[2][3]);
        float t4 = fmaxf(fmaxf(s[3][0], s[3][1]), fmaxf(s[3][2], s[3][3]));
        float tm = fmaxf(fmaxf(fmaxf(t0, t1), fmaxf(t2, t3)), t4);
        tm = fmaxf(tm, __shfl_xor(tm, 16));
        tm = fmaxf(tm, __shfl_xor(tm, 32));
        if (!__all(tm <= m + 8.f)) {
            float mnew = fmaxf(m, tm);
            float r = EXP2N(m - mnew);
            l *= r;
            #pragma unroll
            for (int i = 0; i < 4; ++i) o[i] *= r;
            m = mnew;
        }
        float lsum = 0.f;
        half4_t pf[4];
        #pragma unroll
        for (int st = 0; st < 4; ++st) {
            float p0 = EXP2N(s[st][0] - m);
            float p1 = EXP2N(s[st][1] - m);
            float p2 = EXP2N(s[st][2] - m);
            float p3 = EXP2N(s[st][3] - m);
            lsum += (p0 + p1) + (p2 + p3);
            auto lo = __builtin_amdgcn_cvt_pkrtz(p0, p1);   // __fp16x2
            auto hi = __builtin_amdgcn_cvt_pkrtz(p2, p3);
            pf[st][0] = (_Float16)lo[0]; pf[st][1] = (_Float16)lo[1];
            pf[st][2] = (_Float16)hi[0]; pf[st][3] = (_Float16)hi[1];
        }
        l += lsum;
        // ---- PV
        __builtin_amdgcn_s_setprio(1);
        #pragma unroll
        for (int st = 0; st < 4; ++st) {
            half4_t vf = *(const half4_t*)&Vt[grp][cur][lo16][st * 16 + g * 4];
            o = __builtin_amdgcn_mfma_f32_16x16x16f16(vf, pf[st], o, 0, 0, 0);
        }
        __builtin_amdgcn_s_setprio(0);
    }
    // per-wave l reduce across the 4 lane-groups (disjoint key subsets)
    l += __shfl_xor(l, 16);
    l += __shfl_xor(l, 32);

    __syncthreads();   // all tile reads done -> safe to overlay merge buffers on Kt
    if (grp != 0) {    // publish partial state
        if (lane < 16) {
            MBp[((wsub * 4 + grp) * 2 + 0) * 16 + lane] = m;
            MBp[((wsub * 4 + grp) * 2 + 1) * 16 + lane] = l;
        }
        #pragma unroll
        for (int i = 0; i < 4; ++i)
            OBp[((wsub * 4 + grp) * 16 + g * 4 + i) * 17 + lo16] = o[i];
    }
    __syncthreads();
    if (grp == 0) {    // deterministic merge: grp 0,1,2,3 in fixed order
        float M = m, L = l;
        f32x4 O = o;
        #pragma unroll
        for (int gg = 1; gg < 4; ++gg) {
            float m1 = MBp[((wsub * 4 + gg) * 2 + 0) * 16 + lo16];
            float l1 = MBp[((wsub * 4 + gg) * 2 + 1) * 16 + lo16];
            float Mn = fmaxf(M, m1);
            float e0 = EXP2N(M - Mn), e1 = EXP2N(m1 - Mn);
            L = L * e0 + l1 * e1;
            #pragma unroll
            for (int i = 0; i < 4; ++i)
                O[i] = O[i] * e0 + OBp[((wsub * 4 + gg) * 16 + g * 4 + i) * 17 + lo16] * e1;
            M = Mn;
        }
        float inv = 1.f / L;
        f32x4 res;
        #pragma unroll
        for (int i = 0; i < 4; ++i) res[i] = O[i] * inv;
        *(f32x4*)(ao + (size_t)q * 64 + h * 16 + g * 4) = res;
    }
}

// ------------------------------------------------------------------- host side
static inline void launch_gemm(const float* A, const float* B, const float* bias, float* C,
                               int M, int Nc, int K, bool transB, int act, hipStream_t st) {
    dim3 grid((Nc + 63) / 64, M / 64), blk(256);
    if (!transB)       gemm_f32<false, 0><<<grid, blk, 0, st>>>(A, B, bias, C, M, Nc, K);
    else if (act == 0) gemm_f32<true, 0><<<grid, blk, 0, st>>>(A, B, bias, C, M, Nc, K);
    else               gemm_f32<true, 1><<<grid, blk, 0, st>>>(A, B, bias, C, M, Nc, K);
}

extern "C" void kernel_launch(void* const* d_in, const int* in_sizes, int n_in,
                              void* d_out, int out_size, void* d_ws, size_t ws_size,
                              hipStream_t stream) {
    const int N = NN, E = EE;
    const float* x    = (const float*)d_in[0];
    const int*   ei   = (const int*)d_in[1];
    const float* W[3]   = {(const float*)d_in[2], (const float*)d_in[6], (const float*)d_in[10]};
    const float* as_[3] = {(const float*)d_in[3], (const float*)d_in[7], (const float*)d_in[11]};
    const float* ad_[3] = {(const float*)d_in[4], (const float*)d_in[8], (const float*)d_in[12]};
    const float* bn_g = (const float*)d_in[14];
    const float* bn_b = (const float*)d_in[15];
    const float* Wq = (const float*)d_in[16];
    const float* Wk = (const float*)d_in[17];
    const float* Wv = (const float*)d_in[18];
    const float* Wo = (const float*)d_in[19];
    const float* bq = (const float*)d_in[20];
    const float* bk = (const float*)d_in[21];
    const float* bv = (const float*)d_in[22];
    const float* bo = (const float*)d_in[23];
    const float* Wc1 = (const float*)d_in[24];
    const float* bc1 = (const float*)d_in[25];
    const float* Wc2 = (const float*)d_in[26];
    const float* bc2 = (const float*)d_in[27];

    char* ws = (char*)d_ws;
    _Float16* h16 = (_Float16*)(ws + 0);       // 8192*512*2 = 8,388,608 (GAT phase)
    _Float16* qh = (_Float16*)(ws + 9437184);  // 1,048,576 (MHA phase)
    _Float16* kh = (_Float16*)(ws + 10485760); // 1,048,576
    _Float16* vh = (_Float16*)(ws + 11534336); // 1,048,576
    _Float16* vt = (_Float16*)(ws + 12582912); // 1,048,576
    _Float16* khp = (_Float16*)(ws + 13631488);// 1,048,576
    float* a_s  = (float*)(ws + 16777216);     // 262,144
    float* a_d  = (float*)(ws + 17039360);     // 262,144
    int* row_ptr = (int*)(ws + 17301504);      // 33,024
    int* cursor  = (int*)(ws + 17334528);      // 32,768
    int* deg     = (int*)(ws + 17367296);      // 32,768
    int* col     = (int*)(ws + 17400064);      // 1,081,344
    float* xg   = (float*)(ws + 18481408);     // 2,097,152
    float* xb   = (float*)(ws + 20578560);     // 2,097,152
    float* ao   = (float*)(ws + 28967168);     // 2,097,152
    float* c1   = (float*)(ws + 31064320);     // 1,048,576
    float* bnscale = (float*)(ws + 32112896);  // 64
    float* bnshift = bnscale + 64;             // 64

    // ---- CSR build (same graph all layers); self-loops via +1 in scan_deg
    hipMemsetAsync(deg, 0, (size_t)N * 4, stream);
    count_deg<<<(E + 255) / 256, 256, 0, stream>>>(ei, deg, E);
    scan_deg<<<1, 1024, 0, stream>>>(deg, row_ptr, cursor, N);
    fill_csr<<<(E + N + 255) / 256, 256, 0, stream>>>(ei, cursor, col, E, N);

    // ---- 3 GAT layers (+BN+ReLU).  GAT bias cancels through BN -> skipped.
    // gat_coef fused into GEMM epilogue; bn_apply re-zeros xg for next layer.
    hipMemsetAsync(xg, 0, (size_t)N * 64 * 4, stream);
    const int heads[3] = {8, 8, 1};
    const int fins[3]  = {128, 64, 64};
    const float* xin = x;
    for (int i = 0; i < 3; ++i) {
        int H = heads[i], K = fins[i];
        mfma_gemm<false, true, 0, true><<<dim3(H, N / 64), 256, 0, stream>>>(
            xin, W[i], nullptr, h16, N, H * 64, K, 1.f, as_[i], ad_[i], a_s, a_d, H);
        gat_gather3<<<(N * H) / 4, 256, 0, stream>>>(h16, a_s, a_d, row_ptr, col, xg, N, H);
        bn_stats<<<64, 256, 0, stream>>>(xg, bn_g + i * 64, bn_b + i * 64, bnscale, bnshift, N);
        bn_apply<<<(N * 64) / 256, 256, 0, stream>>>(xg, bnscale, bnshift, xb, xg, N * 64);
        xin = xb;
    }

    // ---- MHA (4 heads, hd=16): fused QKV proj; exp2-domain flash, 4-way split
    // Q scale = 0.25 (1/sqrt(hd)) * log2(e) -> softmax in exp2 domain
    qkv_gemm<<<dim3(1, N / 64, 3), 256, 0, stream>>>(
        xb, Wq, Wk, Wv, bq, bk, bv, qh, kh, vh, N, 0.36067376f);
    vkpack<<<N / 64, 256, 0, stream>>>(vh, kh, vt, khp, N);
    mha_fa5<<<dim3(N / 32, 4), 512, 0, stream>>>(qh, khp, vt, ao, N);
    mfma_gemm<true, false, 0, false><<<dim3(1, N / 64), 256, 0, stream>>>(
        ao, Wo, bo, xg, N, 64, 64, 1.f, nullptr, nullptr, nullptr, nullptr, 0);

    // ---- classifier (small Nc: f32 path)
    launch_gemm(xg, Wc1, bc1, c1, N, 32, 64, true, 1, stream);
    launch_gemm(c1, Wc2, bc2, (float*)d_out, N, 10, 32, true, 0, stream);
}

// Round 11
// 300.100 us; speedup vs baseline: 2.8313x; 1.1982x over previous
//
#include <hip/hip_runtime.h>
#include <hip/hip_bf16.h>

#define NN 8192
#define EE 262144
#define HID 64

typedef _Float16 half4_t __attribute__((ext_vector_type(4)));
typedef _Float16 half8_t __attribute__((ext_vector_type(8)));
typedef float f32x4 __attribute__((ext_vector_type(4)));

extern "C" __device__ float __ocml_native_exp2_f32(float);
#define EXP2N(x) __ocml_native_exp2_f32(x)

// ---------------------------------------------------------------- GEMM (f32, small Nc)
template<bool TRANS_B, int ACT>
__global__ void gemm_f32(const float* __restrict__ A, const float* __restrict__ B,
                         const float* __restrict__ bias, float* __restrict__ C,
                         int M, int Nc, int K) {
    __shared__ float As[16][65];
    __shared__ float Bs[16][65];
    int tid = threadIdx.x;
    int brow = blockIdx.y * 64, bcol = blockIdx.x * 64;
    int tr = (tid / 16) * 4;
    int tc = (tid % 16) * 4;
    float acc[4][4] = {};
    for (int k0 = 0; k0 < K; k0 += 16) {
        {   // A tile 64x16
            int r  = tid / 4;
            int kk = (tid % 4) * 4;
            const float* a = A + (size_t)(brow + r) * K + k0 + kk;
            #pragma unroll
            for (int j = 0; j < 4; ++j) As[kk + j][r] = a[j];
        }
        if (!TRANS_B) {   // B[K][Nc]
            int kk = tid / 16;
            int n4 = (tid % 16) * 4;
            #pragma unroll
            for (int j = 0; j < 4; ++j) {
                int n = bcol + n4 + j;
                Bs[kk][n4 + j] = (n < Nc) ? B[(size_t)(k0 + kk) * Nc + n] : 0.f;
            }
        } else {          // B[Nc][K]
            int n  = tid / 4;
            int kk = (tid % 4) * 4;
            #pragma unroll
            for (int j = 0; j < 4; ++j)
                Bs[kk + j][n] = (bcol + n < Nc) ? B[(size_t)(bcol + n) * K + k0 + kk + j] : 0.f;
        }
        __syncthreads();
        #pragma unroll
        for (int kk = 0; kk < 16; ++kk) {
            float av[4], bv[4];
            #pragma unroll
            for (int i = 0; i < 4; ++i) av[i] = As[kk][tr + i];
            #pragma unroll
            for (int j = 0; j < 4; ++j) bv[j] = Bs[kk][tc + j];
            #pragma unroll
            for (int i = 0; i < 4; ++i)
                #pragma unroll
                for (int j = 0; j < 4; ++j)
                    acc[i][j] += av[i] * bv[j];
        }
        __syncthreads();
    }
    #pragma unroll
    for (int i = 0; i < 4; ++i) {
        int r = brow + tr + i;
        #pragma unroll
        for (int j = 0; j < 4; ++j) {
            int c = bcol + tc + j;
            if (c < Nc) {
                float v = acc[i][j];
                if (bias) v += bias[c];
                if (ACT == 1) v = fmaxf(v, 0.f);
                C[(size_t)r * Nc + c] = v;
            }
        }
    }
}

// ---------------------------------------------------------------- MFMA GEMM body
// (f16 inputs staged in LDS, f32 acc). Fragment conventions as verified:
//   mfma(X,Y,C): D[r][c] = sum_k X[r][k]*Y[c][k]; frag lane: [lane&15][4*(lane>>4)+i]
template<bool TRANS_B, bool OUT_F16, int ACT, bool GAT>
__device__ __forceinline__ void mfma_gemm_body(
        const float* __restrict__ A, const float* __restrict__ B,
        const float* __restrict__ bias, void* __restrict__ Cout,
        int M, int Nc, int K, float scale, int brow, int bcol,
        const float* __restrict__ att_s, const float* __restrict__ att_d,
        float* __restrict__ a_s, float* __restrict__ a_d, int H) {
    __shared__ _Float16 Ah[64][36];
    __shared__ _Float16 Bt[64][36];
    int tid  = threadIdx.x;
    int wave = tid >> 6, lane = tid & 63, lo16 = lane & 15, g = lane >> 4;
    f32x4 acc[4];
    #pragma unroll
    for (int i = 0; i < 4; ++i) acc[i] = (f32x4){0.f, 0.f, 0.f, 0.f};

    for (int k0 = 0; k0 < K; k0 += 32) {
        {   // stage A 64x32 -> f16
            int r  = tid >> 2;
            int ks = (tid & 3) * 8;
            const float* ap = A + (size_t)(brow + r) * K + k0 + ks;
            f32x4 a0 = *(const f32x4*)ap;
            f32x4 a1 = *(const f32x4*)(ap + 4);
            half4_t h0, h1;
            #pragma unroll
            for (int i = 0; i < 4; ++i) { h0[i] = (_Float16)a0[i]; h1[i] = (_Float16)a1[i]; }
            *(half4_t*)&Ah[r][ks]     = h0;
            *(half4_t*)&Ah[r][ks + 4] = h1;
        }
        if (TRANS_B) {   // B[Nc][K] -> Bt[n][k]
            int n  = tid >> 2;
            int ks = (tid & 3) * 8;
            const float* bp = B + (size_t)(bcol + n) * K + k0 + ks;
            f32x4 b0 = *(const f32x4*)bp;
            f32x4 b1 = *(const f32x4*)(bp + 4);
            half4_t h0, h1;
            #pragma unroll
            for (int i = 0; i < 4; ++i) { h0[i] = (_Float16)b0[i]; h1[i] = (_Float16)b1[i]; }
            *(half4_t*)&Bt[n][ks]     = h0;
            *(half4_t*)&Bt[n][ks + 4] = h1;
        } else {         // B[K][Nc] -> Bt[n][k] (transpose during staging)
            int n  = tid & 63;
            int kb = (tid >> 6) * 8;
            half4_t h0, h1;
            #pragma unroll
            for (int i = 0; i < 4; ++i)
                h0[i] = (_Float16)B[(size_t)(k0 + kb + i) * Nc + bcol + n];
            #pragma unroll
            for (int i = 0; i < 4; ++i)
                h1[i] = (_Float16)B[(size_t)(k0 + kb + 4 + i) * Nc + bcol + n];
            *(half4_t*)&Bt[n][kb]     = h0;
            *(half4_t*)&Bt[n][kb + 4] = h1;
        }
        __syncthreads();
        #pragma unroll
        for (int kh = 0; kh < 2; ++kh) {
            half4_t af = *(const half4_t*)&Ah[wave * 16 + lo16][kh * 16 + g * 4];
            #pragma unroll
            for (int cf = 0; cf < 4; ++cf) {
                half4_t bf = *(const half4_t*)&Bt[cf * 16 + lo16][kh * 16 + g * 4];
                acc[cf] = __builtin_amdgcn_mfma_f32_16x16x16f16(af, bf, acc[cf], 0, 0, 0);
            }
        }
        __syncthreads();
    }
    int rbase = brow + wave * 16 + g * 4;
    #pragma unroll
    for (int cf = 0; cf < 4; ++cf) {
        int c = bcol + cf * 16 + lo16;
        float bv = bias ? bias[c] : 0.f;
        #pragma unroll
        for (int reg = 0; reg < 4; ++reg) {
            float v = (acc[cf][reg] + bv) * scale;
            if (ACT == 1) v = fmaxf(v, 0.f);
            if (OUT_F16) ((_Float16*)Cout)[(size_t)(rbase + reg) * Nc + c] = (_Float16)v;
            else         ((float*)Cout)[(size_t)(rbase + reg) * Nc + c] = v;
        }
    }
    if (GAT) {
        float as_c[4], ad_c[4];
        #pragma unroll
        for (int cf = 0; cf < 4; ++cf) {
            int c = bcol + cf * 16 + lo16;
            as_c[cf] = att_s[c];
            ad_c[cf] = att_d[c];
        }
        int head = bcol >> 6;
        #pragma unroll
        for (int reg = 0; reg < 4; ++reg) {
            float ps = 0.f, pd = 0.f;
            #pragma unroll
            for (int cf = 0; cf < 4; ++cf) {
                ps += acc[cf][reg] * as_c[cf];
                pd += acc[cf][reg] * ad_c[cf];
            }
            #pragma unroll
            for (int off = 8; off; off >>= 1) {
                ps += __shfl_xor(ps, off);
                pd += __shfl_xor(pd, off);
            }
            if (lo16 == 0) {
                int row = rbase + reg;
                a_s[row * H + head] = ps;
                a_d[row * H + head] = pd;
            }
        }
    }
}

template<bool TRANS_B, bool OUT_F16, int ACT, bool GAT>
__global__ void mfma_gemm(const float* __restrict__ A, const float* __restrict__ B,
                          const float* __restrict__ bias, void* __restrict__ Cout,
                          int M, int Nc, int K, float scale,
                          const float* __restrict__ att_s, const float* __restrict__ att_d,
                          float* __restrict__ a_s, float* __restrict__ a_d, int H) {
    mfma_gemm_body<TRANS_B, OUT_F16, ACT, GAT>(A, B, bias, Cout, M, Nc, K, scale,
                                               blockIdx.y * 64, blockIdx.x * 64,
                                               att_s, att_d, a_s, a_d, H);
}

// fused Q/K/V projection: blockIdx.z selects weight/bias/output/scale
__global__ void qkv_gemm(const float* __restrict__ A,
                         const float* __restrict__ Wq, const float* __restrict__ Wk,
                         const float* __restrict__ Wv, const float* __restrict__ bq,
                         const float* __restrict__ bk, const float* __restrict__ bv,
                         _Float16* __restrict__ qh, _Float16* __restrict__ kh,
                         _Float16* __restrict__ vh, int M, float qscale) {
    int z = blockIdx.z;
    const float* B    = z == 0 ? Wq : (z == 1 ? Wk : Wv);
    const float* bias = z == 0 ? bq : (z == 1 ? bk : bv);
    _Float16* Cout    = z == 0 ? qh : (z == 1 ? kh : vh);
    float scale       = z == 0 ? qscale : 1.f;
    mfma_gemm_body<true, true, 0, false>(A, B, bias, Cout, M, 64, 64, scale,
                                         blockIdx.y * 64, 0,
                                         nullptr, nullptr, nullptr, nullptr, 0);
}

// ------------------------------------------------------------------ GAT prep
__global__ void count_deg(const int* __restrict__ ei, int* __restrict__ deg, int E) {
    int e = blockIdx.x * 256 + threadIdx.x;
    if (e < E) atomicAdd(&deg[ei[E + e]], 1);   // ei[1] row = dst
}

// single block, 1024 threads, N=8192 (8 per thread); +1 per node = self-loop
__global__ void scan_deg(const int* __restrict__ deg, int* __restrict__ row_ptr,
                         int* __restrict__ cursor, int N) {
    __shared__ int tmp[1024];
    int tid = threadIdx.x;
    int base = tid * 8;
    int local[8];
    int s = 0;
    #pragma unroll
    for (int j = 0; j < 8; ++j) { local[j] = deg[base + j] + 1; s += local[j]; }
    tmp[tid] = s;
    __syncthreads();
    for (int off = 1; off < 1024; off <<= 1) {
        int add = (tid >= off) ? tmp[tid - off] : 0;
        __syncthreads();
        tmp[tid] += add;
        __syncthreads();
    }
    int run = tmp[tid] - s;   // exclusive prefix of this chunk
    #pragma unroll
    for (int j = 0; j < 8; ++j) {
        row_ptr[base + j] = run;
        cursor[base + j]  = run;
        run += local[j];
    }
    if (tid == 1023) row_ptr[N] = run;
}

__global__ void fill_csr(const int* __restrict__ ei, int* __restrict__ cursor,
                         int* __restrict__ col, int E, int N) {
    int e = blockIdx.x * 256 + threadIdx.x;
    if (e < E) {
        int dst = ei[E + e];
        int pos = atomicAdd(&cursor[dst], 1);
        col[pos] = ei[e];
    } else if (e < E + N) {
        int n = e - E;
        int pos = atomicAdd(&cursor[n], 1);
        col[pos] = n;
    }
}

// ---------------------------------------------------------------- GAT gather (H=8)
// WAVE PER DST NODE, all 8 heads at once. lane = (head l>>3, chan-slice l&7).
// Per edge: ONE 16B/lane load of the full 1KB h-row (vs 8x128B before).
// Weight stash: per chunk each lane computes w[8] for ITS edge (a_s[col*8..] is
// one 32B read), stashes (w[8], col) in per-wave LDS; inner loop broadcasts.
// Epilogue: per-head denom shfl-reduce, xor-tree over head bits sums channels;
// lanes 0-7 write the full row. NO atomics -> deterministic, no pre-zero needed.
__global__ void gat_gather_h8(const _Float16* __restrict__ h, const float* __restrict__ a_s,
                              const float* __restrict__ a_d, const int* __restrict__ row_ptr,
                              const int* __restrict__ col, float* __restrict__ out, int N) {
    __shared__ float wsf[4][64][8];
    __shared__ int   wsc[4][64];
    int t = threadIdx.x, wave = t >> 6, lane = t & 63;
    int n = (blockIdx.x * 256 + t) >> 6;
    int hd = lane >> 3;
    int beg = row_ptr[n], end = row_ptr[n + 1];
    float ad[8];
    #pragma unroll
    for (int i = 0; i < 8; ++i) ad[i] = a_d[n * 8 + i];   // wave-uniform scalars
    // ---- pass 1: per-head max
    float m[8];
    #pragma unroll
    for (int i = 0; i < 8; ++i) m[i] = -1e30f;
    for (int j = beg + lane; j < end; j += 64) {
        int c = col[j];
        f32x4 s0 = *(const f32x4*)(a_s + (size_t)c * 8);
        f32x4 s1 = *(const f32x4*)(a_s + (size_t)c * 8 + 4);
        #pragma unroll
        for (int i = 0; i < 4; ++i) {
            float sa = s0[i] + ad[i];
            sa = sa > 0.f ? sa : 0.2f * sa;
            m[i] = fmaxf(m[i], sa);
            float sb = s1[i] + ad[4 + i];
            sb = sb > 0.f ? sb : 0.2f * sb;
            m[4 + i] = fmaxf(m[4 + i], sb);
        }
    }
    #pragma unroll
    for (int i = 0; i < 8; ++i)
        #pragma unroll
        for (int off = 32; off; off >>= 1) m[i] = fmaxf(m[i], __shfl_xor(m[i], off));
    // ---- pass 2: weights + dense row gather
    const _Float16* hb = h + (size_t)lane * 8;
    float acc[8] = {0.f, 0.f, 0.f, 0.f, 0.f, 0.f, 0.f, 0.f};
    float den[8] = {0.f, 0.f, 0.f, 0.f, 0.f, 0.f, 0.f, 0.f};
    for (int base = beg; base < end; base += 64) {
        int j = base + lane;
        int cj = 0;
        float w[8];
        #pragma unroll
        for (int i = 0; i < 8; ++i) w[i] = 0.f;
        if (j < end) {
            cj = col[j];
            f32x4 s0 = *(const f32x4*)(a_s + (size_t)cj * 8);
            f32x4 s1 = *(const f32x4*)(a_s + (size_t)cj * 8 + 4);
            #pragma unroll
            for (int i = 0; i < 4; ++i) {
                float sa = s0[i] + ad[i];
                sa = sa > 0.f ? sa : 0.2f * sa;
                w[i] = __expf(sa - m[i]);
                den[i] += w[i];
                float sb = s1[i] + ad[4 + i];
                sb = sb > 0.f ? sb : 0.2f * sb;
                w[4 + i] = __expf(sb - m[4 + i]);
                den[4 + i] += w[4 + i];
            }
        }
        wsc[wave][lane] = cj;
        *(f32x4*)&wsf[wave][lane][0] = (f32x4){w[0], w[1], w[2], w[3]};
        *(f32x4*)&wsf[wave][lane][4] = (f32x4){w[4], w[5], w[6], w[7]};
        int cnt = min(64, end - base);
        #pragma unroll 2
        for (int k = 0; k < cnt; ++k) {
            int ck  = wsc[wave][k];                      // uniform broadcast
            float wk = wsf[wave][k][hd];                 // per-head broadcast
            half8_t hv = *(const half8_t*)(hb + (size_t)ck * 512);
            #pragma unroll
            for (int i = 0; i < 8; ++i) acc[i] += wk * (float)hv[i];
        }
    }
    #pragma unroll
    for (int i = 0; i < 8; ++i)
        #pragma unroll
        for (int off = 32; off; off >>= 1) den[i] += __shfl_xor(den[i], off);
    float inv = 1.f / ((den[hd] + 1e-16f) * 8.f);
    float y[8];
    #pragma unroll
    for (int i = 0; i < 8; ++i) y[i] = acc[i] * inv;
    #pragma unroll
    for (int i = 0; i < 8; ++i) {
        y[i] += __shfl_xor(y[i], 8);
        y[i] += __shfl_xor(y[i], 16);
        y[i] += __shfl_xor(y[i], 32);
    }
    if (lane < 8) {   // hd==0, sub==lane: write channels lane*8 .. lane*8+7
        *(f32x4*)(out + (size_t)n * 64 + lane * 8)     = (f32x4){y[0], y[1], y[2], y[3]};
        *(f32x4*)(out + (size_t)n * 64 + lane * 8 + 4) = (f32x4){y[4], y[5], y[6], y[7]};
    }
}

// ---------------------------------------------------------------- GAT gather (generic H, used for H=1)
__global__ void gat_gather3(const _Float16* __restrict__ h, const float* __restrict__ a_s,
                            const float* __restrict__ a_d, const int* __restrict__ row_ptr,
                            const int* __restrict__ col, float* __restrict__ out,
                            int N, int H) {
    __shared__ uint2 wc[4][64];
    int t    = threadIdx.x;
    int wave = t >> 6;
    int lane = t & 63;
    int wid  = (blockIdx.x * 256 + t) >> 6;
    if (wid >= N * H) return;
    int n = wid / H, hh = wid % H;
    int beg = row_ptr[n], end = row_ptr[n + 1];
    float adn = a_d[n * H + hh];
    float m = -1e30f;
    for (int j = beg + lane; j < end; j += 64) {
        float sc = a_s[col[j] * H + hh] + adn;
        sc = sc > 0.f ? sc : 0.2f * sc;
        m = fmaxf(m, sc);
    }
    #pragma unroll
    for (int off = 32; off; off >>= 1) m = fmaxf(m, __shfl_xor(m, off));
    const _Float16* hb = h + (size_t)hh * 64 + lane;
    const size_t rs = (size_t)H * 64;
    float denom = 0.f;
    float acc0 = 0.f, acc1 = 0.f, acc2 = 0.f, acc3 = 0.f;
    float acc4 = 0.f, acc5 = 0.f, acc6 = 0.f, acc7 = 0.f;
    for (int base = beg; base < end; base += 64) {
        int j = base + lane;
        float w = 0.f; int s = 0;
        if (j < end) {
            s = col[j];
            float sc = a_s[s * H + hh] + adn;
            sc = sc > 0.f ? sc : 0.2f * sc;
            w = __expf(sc - m);
        }
        denom += w;
        uint2 p; p.x = __float_as_uint(w); p.y = (unsigned)s;
        wc[wave][lane] = p;   // same-wave DS ops are in-order; no barrier needed
        int cnt = min(64, end - base);
        int k = 0;
        for (; k + 8 <= cnt; k += 8) {
            uint2 p0 = wc[wave][k];
            uint2 p1 = wc[wave][k + 1];
            uint2 p2 = wc[wave][k + 2];
            uint2 p3 = wc[wave][k + 3];
            uint2 p4 = wc[wave][k + 4];
            uint2 p5 = wc[wave][k + 5];
            uint2 p6 = wc[wave][k + 6];
            uint2 p7 = wc[wave][k + 7];
            acc0 += __uint_as_float(p0.x) * (float)hb[(size_t)p0.y * rs];
            acc1 += __uint_as_float(p1.x) * (float)hb[(size_t)p1.y * rs];
            acc2 += __uint_as_float(p2.x) * (float)hb[(size_t)p2.y * rs];
            acc3 += __uint_as_float(p3.x) * (float)hb[(size_t)p3.y * rs];
            acc4 += __uint_as_float(p4.x) * (float)hb[(size_t)p4.y * rs];
            acc5 += __uint_as_float(p5.x) * (float)hb[(size_t)p5.y * rs];
            acc6 += __uint_as_float(p6.x) * (float)hb[(size_t)p6.y * rs];
            acc7 += __uint_as_float(p7.x) * (float)hb[(size_t)p7.y * rs];
        }
        for (; k < cnt; ++k) {
            uint2 p0 = wc[wave][k];
            acc0 += __uint_as_float(p0.x) * (float)hb[(size_t)p0.y * rs];
        }
    }
    float acc = ((acc0 + acc1) + (acc2 + acc3)) + ((acc4 + acc5) + (acc6 + acc7));
    #pragma unroll
    for (int off = 32; off; off >>= 1) denom += __shfl_xor(denom, off);
    atomicAdd(&out[n * 64 + lane], acc / ((denom + 1e-16f) * H));
}

// ------------------------------------------------------------------ BatchNorm
__global__ void bn_stats(const float* __restrict__ x, const float* __restrict__ gamma,
                         const float* __restrict__ beta, float* __restrict__ scale,
                         float* __restrict__ shift, int N) {
    int c = blockIdx.x;
    float s = 0.f, ss = 0.f;
    for (int r = threadIdx.x; r < N; r += 256) {
        float v = x[(size_t)r * 64 + c];
        s += v; ss += v * v;
    }
    #pragma unroll
    for (int off = 32; off; off >>= 1) {
        s  += __shfl_xor(s, off);
        ss += __shfl_xor(ss, off);
    }
    __shared__ float red[8];
    int wv = threadIdx.x >> 6, ln = threadIdx.x & 63;
    if (ln == 0) { red[wv] = s; red[4 + wv] = ss; }
    __syncthreads();
    if (threadIdx.x == 0) {
        float S  = red[0] + red[1] + red[2] + red[3];
        float SS = red[4] + red[5] + red[6] + red[7];
        float mu  = S / N;
        float var = SS / N - mu * mu;
        float istd = rsqrtf(var + 1e-5f);
        scale[c] = gamma[c] * istd;
        shift[c] = beta[c] - mu * gamma[c] * istd;
    }
}

// applies BN+ReLU to y, then re-zeros x (the gather accumulator for H=1 layer).
__global__ void bn_apply(const float* x, const float* __restrict__ scale,
                         const float* __restrict__ shift, float* __restrict__ y,
                         float* xz, int total) {
    int i = blockIdx.x * 256 + threadIdx.x;
    if (i < total) {
        int c = i & 63;
        float v = x[i];
        y[i] = fmaxf(v * scale[c] + shift[c], 0.f);
        xz[i] = 0.f;
    }
}

// ------------------------------------------------------------------ MHA prep
// fused: vh [N][64] -> vt [64][N] (transpose) AND kh [N][64] -> khp [4][N][16]
__global__ void vkpack(const _Float16* __restrict__ vh, const _Float16* __restrict__ kh,
                       _Float16* __restrict__ vt, _Float16* __restrict__ khp, int N) {
    __shared__ _Float16 tile[64][68];
    int kb = blockIdx.x * 64;
    int t  = threadIdx.x;
    {
        int r = t >> 2, c0 = (t & 3) * 16;
        half8_t x0 = *(const half8_t*)(vh + (size_t)(kb + r) * 64 + c0);
        half8_t x1 = *(const half8_t*)(vh + (size_t)(kb + r) * 64 + c0 + 8);
        #pragma unroll
        for (int i = 0; i < 8; ++i) { tile[r][c0 + i] = x0[i]; tile[r][c0 + 8 + i] = x1[i]; }
    }
    // kpack (independent of the transpose; no sync needed yet)
    #pragma unroll
    for (int rep = 0; rep < 2; ++rep) {
        int l = t + 256 * rep;
        int n = kb + (l >> 3), c8 = (l & 7) * 8;
        half8_t v = *(const half8_t*)(kh + (size_t)n * 64 + c8);
        *(half8_t*)(khp + ((size_t)(c8 >> 4) * N + n) * 16 + (c8 & 15)) = v;
    }
    __syncthreads();
    {
        int c = t >> 2, ks = (t & 3) * 16;
        half8_t y0, y1;
        #pragma unroll
        for (int i = 0; i < 8; ++i) { y0[i] = tile[ks + i][c]; y1[i] = tile[ks + 8 + i][c]; }
        *(half8_t*)(vt + (size_t)c * N + kb + ks)     = y0;
        *(half8_t*)(vt + (size_t)c * N + kb + ks + 8) = y1;
    }
}

// Block = 8 waves / 512 thr, one head, 32 queries (2 q-subtiles x 4-way key split).
// Group grp (2 waves) processes tiles grp, grp+4, ... ; double-buffered LDS;
// exp2-domain softmax with defer-max; deterministic fixed-order 4-way merge
// (merge buffers OVERLAY the Kt region after a post-loop barrier).
__global__ __launch_bounds__(512) void mha_fa5(const _Float16* __restrict__ qh,
                                               const _Float16* __restrict__ khp,
                                               const _Float16* __restrict__ vt,
                                               float* __restrict__ ao, int N) {
    __shared__ alignas(16) char smem[38912];
    typedef _Float16 (*KtT)[2][64][20];   // [grp][buf][key][ch]   20480 B
    typedef _Float16 (*VtT)[2][16][68];   // [grp][buf][ch][key]   17408 B
    KtT Kt = (KtT)smem;
    VtT Vt = (VtT)(smem + 20480);
    float* MBp = (float*)(smem + 37888);  // [wsub][grp][2][16] = 1024 B
    float* OBp = (float*)smem;            // overlay on Kt: [wsub][grp][16][17] f32 = 8704 B

    int h    = blockIdx.y;
    int t    = threadIdx.x;
    int lane = t & 63;
    int wave = t >> 6;
    int grp  = wave >> 1;
    int wsub = wave & 1;
    int lo16 = lane & 15;
    int g    = lane >> 4;
    int q    = blockIdx.x * 32 + wsub * 16 + lo16;

    half4_t qf = *(const half4_t*)(qh + (size_t)q * 64 + h * 16 + g * 4);
    const _Float16* kp = khp + (size_t)h * N * 16;
    const _Float16* vp = vt + (size_t)h * 16 * N;

    int gt   = t & 127;                   // thread id within the group (2 waves)
    int skey = gt >> 1, sch = (gt & 1) * 8;   // K staging: 16B per thread
    int sd   = gt >> 3, skv = (gt & 7) * 8;   // V staging: 16B per thread

    {   // prologue: stage this group's tile 0
        int kt = grp * 64;
        half8_t kv = *(const half8_t*)(kp + (size_t)(kt + skey) * 16 + sch);
        half8_t vv = *(const half8_t*)(vp + (size_t)sd * N + kt + skv);
        half4_t a, b, c, d;
        #pragma unroll
        for (int i = 0; i < 4; ++i) { a[i] = kv[i]; b[i] = kv[4 + i]; c[i] = vv[i]; d[i] = vv[4 + i]; }
        *(half4_t*)&Kt[grp][0][skey][sch]     = a;
        *(half4_t*)&Kt[grp][0][skey][sch + 4] = b;
        *(half4_t*)&Vt[grp][0][sd][skv]       = c;
        *(half4_t*)&Vt[grp][0][sd][skv + 4]   = d;
    }

    float m = -1e30f, l = 0.f;
    f32x4 o = {0.f, 0.f, 0.f, 0.f};
    const f32x4 zero = {0.f, 0.f, 0.f, 0.f};
    const int nit = N / 256;              // 4 groups x 64 keys

    for (int it = 0; it < nit; ++it) {
        int cur = it & 1;
        __syncthreads();
        if (it + 1 < nit) {
            int kt = ((it + 1) * 4 + grp) * 64;
            half8_t kv = *(const half8_t*)(kp + (size_t)(kt + skey) * 16 + sch);
            half8_t vv = *(const half8_t*)(vp + (size_t)sd * N + kt + skv);
            half4_t a, b, c, d;
            #pragma unroll
            for (int i = 0; i < 4; ++i) { a[i] = kv[i]; b[i] = kv[4 + i]; c[i] = vv[i]; d[i] = vv[4 + i]; }
            *(half4_t*)&Kt[grp][cur ^ 1][skey][sch]     = a;
            *(half4_t*)&Kt[grp][cur ^ 1][skey][sch + 4] = b;
            *(half4_t*)&Vt[grp][cur ^ 1][sd][skv]       = c;
            *(half4_t*)&Vt[grp][cur ^ 1][sd][skv + 4]   = d;
        }
        // ---- QK^T: 4 sub-tiles of 16 keys (scores in log2 domain)
        f32x4 s[4];
        __builtin_amdgcn_s_setprio(1);
        #pragma unroll
        for (int st = 0; st < 4; ++st) {
            half4_t kf = *(const half4_t*)&Kt[grp][cur][st * 16 + lo16][g * 4];
            s[st] = __builtin_amdgcn_mfma_f32_16x16x16f16(kf, qf, zero, 0, 0, 0);
        }
        __builtin_amdgcn_s_setprio(0);
        // ---- online softmax, defer-max (THR=8 in log2 domain)
        float t0 = fmaxf(fmaxf(s[0][0], s[0][1]), s[0][2]);
        float t1 = fmaxf(fmaxf(s[0][3], s[1][0]), s[1][1]);
        float t2 = fmaxf(fmaxf(s[1][2], s[1][3]), s[2][0]);
        float t3 = fmaxf(fmaxf(s[2][1], s[2][2]), s[2][3]);
        float t4 = fmaxf(fmaxf(s[3][0], s[3][1]), fmaxf(s[3][2], s[3][3]));
        float tm = fmaxf(fmaxf(fmaxf(t0, t1), fmaxf(t2, t3)), t4);
        tm = fmaxf(tm, __shfl_xor(tm, 16));
        tm = fmaxf(tm, __shfl_xor(tm, 32));
        if (!__all(tm <= m + 8.f)) {
            float mnew = fmaxf(m, tm);
            float r = EXP2N(m - mnew);
            l *= r;
            #pragma unroll
            for (int i = 0; i < 4; ++i) o[i] *= r;
            m = mnew;
        }
        float lsum = 0.f;
        half4_t pf[4];
        #pragma unroll
        for (int st = 0; st < 4; ++st) {
            float p0 = EXP2N(s[st][0] - m);
            float p1 = EXP2N(s[st][1] - m);
            float p2 = EXP2N(s[st][2] - m);
            float p3 = EXP2N(s[st][3] - m);
            lsum += (p0 + p1) + (p2 + p3);
            auto lo = __builtin_amdgcn_cvt_pkrtz(p0, p1);   // __fp16x2
            auto hi = __builtin_amdgcn_cvt_pkrtz(p2, p3);
            pf[st][0] = (_Float16)lo[0]; pf[st][1] = (_Float16)lo[1];
            pf[st][2] = (_Float16)hi[0]; pf[st][3] = (_Float16)hi[1];
        }
        l += lsum;
        // ---- PV
        __builtin_amdgcn_s_setprio(1);
        #pragma unroll
        for (int st = 0; st < 4; ++st) {
            half4_t vf = *(const half4_t*)&Vt[grp][cur][lo16][st * 16 + g * 4];
            o = __builtin_amdgcn_mfma_f32_16x16x16f16(vf, pf[st], o, 0, 0, 0);
        }
        __builtin_amdgcn_s_setprio(0);
    }
    // per-wave l reduce across the 4 lane-groups (disjoint key subsets)
    l += __shfl_xor(l, 16);
    l += __shfl_xor(l, 32);

    __syncthreads();   // all tile reads done -> safe to overlay merge buffers on Kt
    if (grp != 0) {    // publish partial state
        if (lane < 16) {
            MBp[((wsub * 4 + grp) * 2 + 0) * 16 + lane] = m;
            MBp[((wsub * 4 + grp) * 2 + 1) * 16 + lane] = l;
        }
        #pragma unroll
        for (int i = 0; i < 4; ++i)
            OBp[((wsub * 4 + grp) * 16 + g * 4 + i) * 17 + lo16] = o[i];
    }
    __syncthreads();
    if (grp == 0) {    // deterministic merge: grp 0,1,2,3 in fixed order
        float M = m, L = l;
        f32x4 O = o;
        #pragma unroll
        for (int gg = 1; gg < 4; ++gg) {
            float m1 = MBp[((wsub * 4 + gg) * 2 + 0) * 16 + lo16];
            float l1 = MBp[((wsub * 4 + gg) * 2 + 1) * 16 + lo16];
            float Mn = fmaxf(M, m1);
            float e0 = EXP2N(M - Mn), e1 = EXP2N(m1 - Mn);
            L = L * e0 + l1 * e1;
            #pragma unroll
            for (int i = 0; i < 4; ++i)
                O[i] = O[i] * e0 + OBp[((wsub * 4 + gg) * 16 + g * 4 + i) * 17 + lo16] * e1;
            M = Mn;
        }
        float inv = 1.f / L;
        f32x4 res;
        #pragma unroll
        for (int i = 0; i < 4; ++i) res[i] = O[i] * inv;
        *(f32x4*)(ao + (size_t)q * 64 + h * 16 + g * 4) = res;
    }
}

// ------------------------------------------------------------------- host side
static inline void launch_gemm(const float* A, const float* B, const float* bias, float* C,
                               int M, int Nc, int K, bool transB, int act, hipStream_t st) {
    dim3 grid((Nc + 63) / 64, M / 64), blk(256);
    if (!transB)       gemm_f32<false, 0><<<grid, blk, 0, st>>>(A, B, bias, C, M, Nc, K);
    else if (act == 0) gemm_f32<true, 0><<<grid, blk, 0, st>>>(A, B, bias, C, M, Nc, K);
    else               gemm_f32<true, 1><<<grid, blk, 0, st>>>(A, B, bias, C, M, Nc, K);
}

extern "C" void kernel_launch(void* const* d_in, const int* in_sizes, int n_in,
                              void* d_out, int out_size, void* d_ws, size_t ws_size,
                              hipStream_t stream) {
    const int N = NN, E = EE;
    const float* x    = (const float*)d_in[0];
    const int*   ei   = (const int*)d_in[1];
    const float* W[3]   = {(const float*)d_in[2], (const float*)d_in[6], (const float*)d_in[10]};
    const float* as_[3] = {(const float*)d_in[3], (const float*)d_in[7], (const float*)d_in[11]};
    const float* ad_[3] = {(const float*)d_in[4], (const float*)d_in[8], (const float*)d_in[12]};
    const float* bn_g = (const float*)d_in[14];
    const float* bn_b = (const float*)d_in[15];
    const float* Wq = (const float*)d_in[16];
    const float* Wk = (const float*)d_in[17];
    const float* Wv = (const float*)d_in[18];
    const float* Wo = (const float*)d_in[19];
    const float* bq = (const float*)d_in[20];
    const float* bk = (const float*)d_in[21];
    const float* bv = (const float*)d_in[22];
    const float* bo = (const float*)d_in[23];
    const float* Wc1 = (const float*)d_in[24];
    const float* bc1 = (const float*)d_in[25];
    const float* Wc2 = (const float*)d_in[26];
    const float* bc2 = (const float*)d_in[27];

    char* ws = (char*)d_ws;
    _Float16* h16 = (_Float16*)(ws + 0);       // 8192*512*2 = 8,388,608 (GAT phase)
    _Float16* qh = (_Float16*)(ws + 9437184);  // 1,048,576 (MHA phase)
    _Float16* kh = (_Float16*)(ws + 10485760); // 1,048,576
    _Float16* vh = (_Float16*)(ws + 11534336); // 1,048,576
    _Float16* vt = (_Float16*)(ws + 12582912); // 1,048,576
    _Float16* khp = (_Float16*)(ws + 13631488);// 1,048,576
    float* a_s  = (float*)(ws + 16777216);     // 262,144
    float* a_d  = (float*)(ws + 17039360);     // 262,144
    int* row_ptr = (int*)(ws + 17301504);      // 33,024
    int* cursor  = (int*)(ws + 17334528);      // 32,768
    int* deg     = (int*)(ws + 17367296);      // 32,768
    int* col     = (int*)(ws + 17400064);      // 1,081,344
    float* xg   = (float*)(ws + 18481408);     // 2,097,152
    float* xb   = (float*)(ws + 20578560);     // 2,097,152
    float* ao   = (float*)(ws + 28967168);     // 2,097,152
    float* c1   = (float*)(ws + 31064320);     // 1,048,576
    float* bnscale = (float*)(ws + 32112896);  // 64
    float* bnshift = bnscale + 64;             // 64

    // ---- CSR build (same graph all layers); self-loops via +1 in scan_deg
    hipMemsetAsync(deg, 0, (size_t)N * 4, stream);
    count_deg<<<(E + 255) / 256, 256, 0, stream>>>(ei, deg, E);
    scan_deg<<<1, 1024, 0, stream>>>(deg, row_ptr, cursor, N);
    fill_csr<<<(E + N + 255) / 256, 256, 0, stream>>>(ei, cursor, col, E, N);

    // ---- 3 GAT layers (+BN+ReLU).  GAT bias cancels through BN -> skipped.
    // gat_coef fused into GEMM epilogue. H=8 layers: wave-per-node gather
    // (no atomics, full overwrite). H=1 layer: generic gather into zeroed xg
    // (bn_apply of the previous layer re-zeros it).
    const int heads[3] = {8, 8, 1};
    const int fins[3]  = {128, 64, 64};
    const float* xin = x;
    for (int i = 0; i < 3; ++i) {
        int H = heads[i], K = fins[i];
        mfma_gemm<false, true, 0, true><<<dim3(H, N / 64), 256, 0, stream>>>(
            xin, W[i], nullptr, h16, N, H * 64, K, 1.f, as_[i], ad_[i], a_s, a_d, H);
        if (H == 8)
            gat_gather_h8<<<N / 4, 256, 0, stream>>>(h16, a_s, a_d, row_ptr, col, xg, N);
        else
            gat_gather3<<<(N * H) / 4, 256, 0, stream>>>(h16, a_s, a_d, row_ptr, col, xg, N, H);
        bn_stats<<<64, 256, 0, stream>>>(xg, bn_g + i * 64, bn_b + i * 64, bnscale, bnshift, N);
        bn_apply<<<(N * 64) / 256, 256, 0, stream>>>(xg, bnscale, bnshift, xb, xg, N * 64);
        xin = xb;
    }

    // ---- MHA (4 heads, hd=16): fused QKV proj; exp2-domain flash, 4-way split
    // Q scale = 0.25 (1/sqrt(hd)) * log2(e) -> softmax in exp2 domain
    qkv_gemm<<<dim3(1, N / 64, 3), 256, 0, stream>>>(
        xb, Wq, Wk, Wv, bq, bk, bv, qh, kh, vh, N, 0.36067376f);
    vkpack<<<N / 64, 256, 0, stream>>>(vh, kh, vt, khp, N);
    mha_fa5<<<dim3(N / 32, 4), 512, 0, stream>>>(qh, khp, vt, ao, N);
    mfma_gemm<true, false, 0, false><<<dim3(1, N / 64), 256, 0, stream>>>(
        ao, Wo, bo, xg, N, 64, 64, 1.f, nullptr, nullptr, nullptr, nullptr, 0);

    // ---- classifier (small Nc: f32 path)
    launch_gemm(xg, Wc1, bc1, c1, N, 32, 64, true, 1, stream);
    launch_gemm(c1, Wc2, bc2, (float*)d_out, N, 10, 32, true, 0, stream);
}

// Round 12
// 268.201 us; speedup vs baseline: 3.1681x; 1.1189x over previous
//
#include <hip/hip_runtime.h>
#include <hip/hip_bf16.h>

#define NN 8192
#define EE 262144
#define HID 64

typedef _Float16 half4_t __attribute__((ext_vector_type(4)));
typedef _Float16 half8_t __attribute__((ext_vector_type(8)));
typedef float f32x4 __attribute__((ext_vector_type(4)));

extern "C" __device__ float __ocml_native_exp2_f32(float);
#define EXP2N(x) __ocml_native_exp2_f32(x)

#define MFMA16(a, b, c) __builtin_amdgcn_mfma_f32_16x16x16f16(a, b, c, 0, 0, 0)

// ---------------------------------------------------------------- MFMA GEMM body
// (f16 inputs staged in LDS, f32 acc). Fragment conventions as verified:
//   mfma(X,Y,C): D layout col=lane&15, row=4*(lane>>4)+reg; frag lane: [lane&15][4g+i]
// BN=true: A-staging applies y = relu(a*bnsc[c]+bnsh[c])  (c = K-dim index, K==64)
template<bool TRANS_B, bool OUT_F16, int ACT, bool GAT, bool BN>
__device__ __forceinline__ void mfma_gemm_body(
        const float* __restrict__ A, const float* __restrict__ B,
        const float* __restrict__ bias, void* __restrict__ Cout,
        int M, int Nc, int K, float scale, int brow, int bcol,
        const float* __restrict__ att_s, const float* __restrict__ att_d,
        float* __restrict__ a_s, float* __restrict__ a_d, int H,
        const float* __restrict__ bnsc, const float* __restrict__ bnsh) {
    __shared__ _Float16 Ah[64][36];
    __shared__ _Float16 Bt[64][36];
    int tid  = threadIdx.x;
    int wave = tid >> 6, lane = tid & 63, lo16 = lane & 15, g = lane >> 4;
    f32x4 acc[4];
    #pragma unroll
    for (int i = 0; i < 4; ++i) acc[i] = (f32x4){0.f, 0.f, 0.f, 0.f};

    for (int k0 = 0; k0 < K; k0 += 32) {
        {   // stage A 64x32 -> f16 (optionally BN+ReLU fused)
            int r  = tid >> 2;
            int ks = (tid & 3) * 8;
            const float* ap = A + (size_t)(brow + r) * K + k0 + ks;
            f32x4 a0 = *(const f32x4*)ap;
            f32x4 a1 = *(const f32x4*)(ap + 4);
            if (BN) {
                #pragma unroll
                for (int i = 0; i < 4; ++i) {
                    int c0 = k0 + ks + i, c1 = c0 + 4;
                    a0[i] = fmaxf(a0[i] * bnsc[c0] + bnsh[c0], 0.f);
                    a1[i] = fmaxf(a1[i] * bnsc[c1] + bnsh[c1], 0.f);
                }
            }
            half4_t h0, h1;
            #pragma unroll
            for (int i = 0; i < 4; ++i) { h0[i] = (_Float16)a0[i]; h1[i] = (_Float16)a1[i]; }
            *(half4_t*)&Ah[r][ks]     = h0;
            *(half4_t*)&Ah[r][ks + 4] = h1;
        }
        if (TRANS_B) {   // B[Nc][K] -> Bt[n][k]
            int n  = tid >> 2;
            int ks = (tid & 3) * 8;
            const float* bp = B + (size_t)(bcol + n) * K + k0 + ks;
            f32x4 b0 = *(const f32x4*)bp;
            f32x4 b1 = *(const f32x4*)(bp + 4);
            half4_t h0, h1;
            #pragma unroll
            for (int i = 0; i < 4; ++i) { h0[i] = (_Float16)b0[i]; h1[i] = (_Float16)b1[i]; }
            *(half4_t*)&Bt[n][ks]     = h0;
            *(half4_t*)&Bt[n][ks + 4] = h1;
        } else {         // B[K][Nc] -> Bt[n][k] (transpose during staging)
            int n  = tid & 63;
            int kb = (tid >> 6) * 8;
            half4_t h0, h1;
            #pragma unroll
            for (int i = 0; i < 4; ++i)
                h0[i] = (_Float16)B[(size_t)(k0 + kb + i) * Nc + bcol + n];
            #pragma unroll
            for (int i = 0; i < 4; ++i)
                h1[i] = (_Float16)B[(size_t)(k0 + kb + 4 + i) * Nc + bcol + n];
            *(half4_t*)&Bt[n][kb]     = h0;
            *(half4_t*)&Bt[n][kb + 4] = h1;
        }
        __syncthreads();
        #pragma unroll
        for (int kh = 0; kh < 2; ++kh) {
            half4_t af = *(const half4_t*)&Ah[wave * 16 + lo16][kh * 16 + g * 4];
            #pragma unroll
            for (int cf = 0; cf < 4; ++cf) {
                half4_t bf = *(const half4_t*)&Bt[cf * 16 + lo16][kh * 16 + g * 4];
                acc[cf] = MFMA16(af, bf, acc[cf]);
            }
        }
        __syncthreads();
    }
    int rbase = brow + wave * 16 + g * 4;
    #pragma unroll
    for (int cf = 0; cf < 4; ++cf) {
        int c = bcol + cf * 16 + lo16;
        float bv = bias ? bias[c] : 0.f;
        #pragma unroll
        for (int reg = 0; reg < 4; ++reg) {
            float v = (acc[cf][reg] + bv) * scale;
            if (ACT == 1) v = fmaxf(v, 0.f);
            if (OUT_F16) ((_Float16*)Cout)[(size_t)(rbase + reg) * Nc + c] = (_Float16)v;
            else         ((float*)Cout)[(size_t)(rbase + reg) * Nc + c] = v;
        }
    }
    if (GAT) {
        float as_c[4], ad_c[4];
        #pragma unroll
        for (int cf = 0; cf < 4; ++cf) {
            int c = bcol + cf * 16 + lo16;
            as_c[cf] = att_s[c];
            ad_c[cf] = att_d[c];
        }
        int head = bcol >> 6;
        #pragma unroll
        for (int reg = 0; reg < 4; ++reg) {
            float ps = 0.f, pd = 0.f;
            #pragma unroll
            for (int cf = 0; cf < 4; ++cf) {
                ps += acc[cf][reg] * as_c[cf];
                pd += acc[cf][reg] * ad_c[cf];
            }
            #pragma unroll
            for (int off = 8; off; off >>= 1) {
                ps += __shfl_xor(ps, off);
                pd += __shfl_xor(pd, off);
            }
            if (lo16 == 0) {
                int row = rbase + reg;
                a_s[row * H + head] = ps;
                a_d[row * H + head] = pd;
            }
        }
    }
}

template<bool TRANS_B, bool OUT_F16, int ACT, bool GAT, bool BN>
__global__ void mfma_gemm(const float* __restrict__ A, const float* __restrict__ B,
                          const float* __restrict__ bias, void* __restrict__ Cout,
                          int M, int Nc, int K, float scale,
                          const float* __restrict__ att_s, const float* __restrict__ att_d,
                          float* __restrict__ a_s, float* __restrict__ a_d, int H,
                          const float* __restrict__ bnsc, const float* __restrict__ bnsh) {
    mfma_gemm_body<TRANS_B, OUT_F16, ACT, GAT, BN>(A, B, bias, Cout, M, Nc, K, scale,
                                                   blockIdx.y * 64, blockIdx.x * 64,
                                                   att_s, att_d, a_s, a_d, H, bnsc, bnsh);
}

// fused Q/K/V projection (BN of layer-2 fused into A): blockIdx.z selects slice
__global__ void qkv_gemm(const float* __restrict__ A,
                         const float* __restrict__ Wq, const float* __restrict__ Wk,
                         const float* __restrict__ Wv, const float* __restrict__ bq,
                         const float* __restrict__ bk, const float* __restrict__ bv,
                         _Float16* __restrict__ qh, _Float16* __restrict__ kh,
                         _Float16* __restrict__ vh, int M, float qscale,
                         const float* __restrict__ bnsc, const float* __restrict__ bnsh) {
    int z = blockIdx.z;
    const float* B    = z == 0 ? Wq : (z == 1 ? Wk : Wv);
    const float* bias = z == 0 ? bq : (z == 1 ? bk : bv);
    _Float16* Cout    = z == 0 ? qh : (z == 1 ? kh : vh);
    float scale       = z == 0 ? qscale : 1.f;
    mfma_gemm_body<true, true, 0, false, true>(A, B, bias, Cout, M, 64, 64, scale,
                                               blockIdx.y * 64, 0,
                                               nullptr, nullptr, nullptr, nullptr, 0,
                                               bnsc, bnsh);
}

// ------------------------------------------------------------------ GAT prep
__global__ void count_deg(const int* __restrict__ ei, int* __restrict__ deg, int E) {
    int e = blockIdx.x * 256 + threadIdx.x;
    if (e < E) atomicAdd(&deg[ei[E + e]], 1);   // ei[1] row = dst
}

// single block, 1024 threads, N=8192 (8 per thread); +1 per node = self-loop
__global__ void scan_deg(const int* __restrict__ deg, int* __restrict__ row_ptr,
                         int* __restrict__ cursor, int N) {
    __shared__ int tmp[1024];
    int tid = threadIdx.x;
    int base = tid * 8;
    int local[8];
    int s = 0;
    #pragma unroll
    for (int j = 0; j < 8; ++j) { local[j] = deg[base + j] + 1; s += local[j]; }
    tmp[tid] = s;
    __syncthreads();
    for (int off = 1; off < 1024; off <<= 1) {
        int add = (tid >= off) ? tmp[tid - off] : 0;
        __syncthreads();
        tmp[tid] += add;
        __syncthreads();
    }
    int run = tmp[tid] - s;   // exclusive prefix of this chunk
    #pragma unroll
    for (int j = 0; j < 8; ++j) {
        row_ptr[base + j] = run;
        cursor[base + j]  = run;
        run += local[j];
    }
    if (tid == 1023) row_ptr[N] = run;
}

__global__ void fill_csr(const int* __restrict__ ei, int* __restrict__ cursor,
                         int* __restrict__ col, int E, int N) {
    int e = blockIdx.x * 256 + threadIdx.x;
    if (e < E) {
        int dst = ei[E + e];
        int pos = atomicAdd(&cursor[dst], 1);
        col[pos] = ei[e];
    } else if (e < E + N) {
        int n = e - E;
        int pos = atomicAdd(&cursor[n], 1);
        col[pos] = n;
    }
}

// ---------------------------------------------------------------- GAT gather (H=8)
// WAVE PER DST NODE, all 8 heads at once. lane = (head l>>3, chan-slice l&7).
// Per edge: ONE 16B/lane load of the full 1KB h-row. No atomics, full overwrite.
__global__ void gat_gather_h8(const _Float16* __restrict__ h, const float* __restrict__ a_s,
                              const float* __restrict__ a_d, const int* __restrict__ row_ptr,
                              const int* __restrict__ col, float* __restrict__ out, int N) {
    __shared__ float wsf[4][64][8];
    __shared__ int   wsc[4][64];
    int t = threadIdx.x, wave = t >> 6, lane = t & 63;
    int n = (blockIdx.x * 256 + t) >> 6;
    int hd = lane >> 3;
    int beg = row_ptr[n], end = row_ptr[n + 1];
    float ad[8];
    #pragma unroll
    for (int i = 0; i < 8; ++i) ad[i] = a_d[n * 8 + i];   // wave-uniform scalars
    // ---- pass 1: per-head max
    float m[8];
    #pragma unroll
    for (int i = 0; i < 8; ++i) m[i] = -1e30f;
    for (int j = beg + lane; j < end; j += 64) {
        int c = col[j];
        f32x4 s0 = *(const f32x4*)(a_s + (size_t)c * 8);
        f32x4 s1 = *(const f32x4*)(a_s + (size_t)c * 8 + 4);
        #pragma unroll
        for (int i = 0; i < 4; ++i) {
            float sa = s0[i] + ad[i];
            sa = sa > 0.f ? sa : 0.2f * sa;
            m[i] = fmaxf(m[i], sa);
            float sb = s1[i] + ad[4 + i];
            sb = sb > 0.f ? sb : 0.2f * sb;
            m[4 + i] = fmaxf(m[4 + i], sb);
        }
    }
    #pragma unroll
    for (int i = 0; i < 8; ++i)
        #pragma unroll
        for (int off = 32; off; off >>= 1) m[i] = fmaxf(m[i], __shfl_xor(m[i], off));
    // ---- pass 2: weights + dense row gather
    const _Float16* hb = h + (size_t)lane * 8;
    float acc[8] = {0.f, 0.f, 0.f, 0.f, 0.f, 0.f, 0.f, 0.f};
    float den[8] = {0.f, 0.f, 0.f, 0.f, 0.f, 0.f, 0.f, 0.f};
    for (int base = beg; base < end; base += 64) {
        int j = base + lane;
        int cj = 0;
        float w[8];
        #pragma unroll
        for (int i = 0; i < 8; ++i) w[i] = 0.f;
        if (j < end) {
            cj = col[j];
            f32x4 s0 = *(const f32x4*)(a_s + (size_t)cj * 8);
            f32x4 s1 = *(const f32x4*)(a_s + (size_t)cj * 8 + 4);
            #pragma unroll
            for (int i = 0; i < 4; ++i) {
                float sa = s0[i] + ad[i];
                sa = sa > 0.f ? sa : 0.2f * sa;
                w[i] = __expf(sa - m[i]);
                den[i] += w[i];
                float sb = s1[i] + ad[4 + i];
                sb = sb > 0.f ? sb : 0.2f * sb;
                w[4 + i] = __expf(sb - m[4 + i]);
                den[4 + i] += w[4 + i];
            }
        }
        wsc[wave][lane] = cj;
        *(f32x4*)&wsf[wave][lane][0] = (f32x4){w[0], w[1], w[2], w[3]};
        *(f32x4*)&wsf[wave][lane][4] = (f32x4){w[4], w[5], w[6], w[7]};
        int cnt = min(64, end - base);
        #pragma unroll 2
        for (int k = 0; k < cnt; ++k) {
            int ck  = wsc[wave][k];                      // uniform broadcast
            float wk = wsf[wave][k][hd];                 // per-head broadcast
            half8_t hv = *(const half8_t*)(hb + (size_t)ck * 512);
            #pragma unroll
            for (int i = 0; i < 8; ++i) acc[i] += wk * (float)hv[i];
        }
    }
    #pragma unroll
    for (int i = 0; i < 8; ++i)
        #pragma unroll
        for (int off = 32; off; off >>= 1) den[i] += __shfl_xor(den[i], off);
    float inv = 1.f / ((den[hd] + 1e-16f) * 8.f);
    float y[8];
    #pragma unroll
    for (int i = 0; i < 8; ++i) y[i] = acc[i] * inv;
    #pragma unroll
    for (int i = 0; i < 8; ++i) {
        y[i] += __shfl_xor(y[i], 8);
        y[i] += __shfl_xor(y[i], 16);
        y[i] += __shfl_xor(y[i], 32);
    }
    if (lane < 8) {   // hd==0, sub==lane: write channels lane*8 .. lane*8+7
        *(f32x4*)(out + (size_t)n * 64 + lane * 8)     = (f32x4){y[0], y[1], y[2], y[3]};
        *(f32x4*)(out + (size_t)n * 64 + lane * 8 + 4) = (f32x4){y[4], y[5], y[6], y[7]};
    }
}

// ---------------------------------------------------------------- GAT gather (H=1)
// wave per node, single head -> plain store, no atomics, no pre-zero.
__global__ void gat_gather_h1(const _Float16* __restrict__ h, const float* __restrict__ a_s,
                              const float* __restrict__ a_d, const int* __restrict__ row_ptr,
                              const int* __restrict__ col, float* __restrict__ out, int N) {
    __shared__ uint2 wc[4][64];
    int t    = threadIdx.x;
    int wave = t >> 6;
    int lane = t & 63;
    int n    = (blockIdx.x * 256 + t) >> 6;
    int beg = row_ptr[n], end = row_ptr[n + 1];
    float adn = a_d[n];
    float m = -1e30f;
    for (int j = beg + lane; j < end; j += 64) {
        float sc = a_s[col[j]] + adn;
        sc = sc > 0.f ? sc : 0.2f * sc;
        m = fmaxf(m, sc);
    }
    #pragma unroll
    for (int off = 32; off; off >>= 1) m = fmaxf(m, __shfl_xor(m, off));
    const _Float16* hb = h + lane;
    float denom = 0.f;
    float acc0 = 0.f, acc1 = 0.f, acc2 = 0.f, acc3 = 0.f;
    float acc4 = 0.f, acc5 = 0.f, acc6 = 0.f, acc7 = 0.f;
    for (int base = beg; base < end; base += 64) {
        int j = base + lane;
        float w = 0.f; int s = 0;
        if (j < end) {
            s = col[j];
            float sc = a_s[s] + adn;
            sc = sc > 0.f ? sc : 0.2f * sc;
            w = __expf(sc - m);
        }
        denom += w;
        uint2 p; p.x = __float_as_uint(w); p.y = (unsigned)s;
        wc[wave][lane] = p;   // same-wave DS ops are in-order; no barrier needed
        int cnt = min(64, end - base);
        int k = 0;
        for (; k + 8 <= cnt; k += 8) {
            uint2 p0 = wc[wave][k];
            uint2 p1 = wc[wave][k + 1];
            uint2 p2 = wc[wave][k + 2];
            uint2 p3 = wc[wave][k + 3];
            uint2 p4 = wc[wave][k + 4];
            uint2 p5 = wc[wave][k + 5];
            uint2 p6 = wc[wave][k + 6];
            uint2 p7 = wc[wave][k + 7];
            acc0 += __uint_as_float(p0.x) * (float)hb[(size_t)p0.y * 64];
            acc1 += __uint_as_float(p1.x) * (float)hb[(size_t)p1.y * 64];
            acc2 += __uint_as_float(p2.x) * (float)hb[(size_t)p2.y * 64];
            acc3 += __uint_as_float(p3.x) * (float)hb[(size_t)p3.y * 64];
            acc4 += __uint_as_float(p4.x) * (float)hb[(size_t)p4.y * 64];
            acc5 += __uint_as_float(p5.x) * (float)hb[(size_t)p5.y * 64];
            acc6 += __uint_as_float(p6.x) * (float)hb[(size_t)p6.y * 64];
            acc7 += __uint_as_float(p7.x) * (float)hb[(size_t)p7.y * 64];
        }
        for (; k < cnt; ++k) {
            uint2 p0 = wc[wave][k];
            acc0 += __uint_as_float(p0.x) * (float)hb[(size_t)p0.y * 64];
        }
    }
    float acc = ((acc0 + acc1) + (acc2 + acc3)) + ((acc4 + acc5) + (acc6 + acc7));
    #pragma unroll
    for (int off = 32; off; off >>= 1) denom += __shfl_xor(denom, off);
    out[(size_t)n * 64 + lane] = acc / (denom + 1e-16f);
}

// ------------------------------------------------------------------ BatchNorm stats
__global__ void bn_stats(const float* __restrict__ x, const float* __restrict__ gamma,
                         const float* __restrict__ beta, float* __restrict__ scale,
                         float* __restrict__ shift, int N) {
    int c = blockIdx.x;
    float s = 0.f, ss = 0.f;
    for (int r = threadIdx.x; r < N; r += 256) {
        float v = x[(size_t)r * 64 + c];
        s += v; ss += v * v;
    }
    #pragma unroll
    for (int off = 32; off; off >>= 1) {
        s  += __shfl_xor(s, off);
        ss += __shfl_xor(ss, off);
    }
    __shared__ float red[8];
    int wv = threadIdx.x >> 6, ln = threadIdx.x & 63;
    if (ln == 0) { red[wv] = s; red[4 + wv] = ss; }
    __syncthreads();
    if (threadIdx.x == 0) {
        float S  = red[0] + red[1] + red[2] + red[3];
        float SS = red[4] + red[5] + red[6] + red[7];
        float mu  = S / N;
        float var = SS / N - mu * mu;
        float istd = rsqrtf(var + 1e-5f);
        scale[c] = gamma[c] * istd;
        shift[c] = beta[c] - mu * gamma[c] * istd;
    }
}

// ------------------------------------------------------------------ MHA prep
// fused: vh [N][64] -> vt [64][N] (transpose) AND kh [N][64] -> khp [4][N][16]
__global__ void vkpack(const _Float16* __restrict__ vh, const _Float16* __restrict__ kh,
                       _Float16* __restrict__ vt, _Float16* __restrict__ khp, int N) {
    __shared__ _Float16 tile[64][68];
    int kb = blockIdx.x * 64;
    int t  = threadIdx.x;
    {
        int r = t >> 2, c0 = (t & 3) * 16;
        half8_t x0 = *(const half8_t*)(vh + (size_t)(kb + r) * 64 + c0);
        half8_t x1 = *(const half8_t*)(vh + (size_t)(kb + r) * 64 + c0 + 8);
        #pragma unroll
        for (int i = 0; i < 8; ++i) { tile[r][c0 + i] = x0[i]; tile[r][c0 + 8 + i] = x1[i]; }
    }
    // kpack (independent of the transpose; no sync needed yet)
    #pragma unroll
    for (int rep = 0; rep < 2; ++rep) {
        int l = t + 256 * rep;
        int n = kb + (l >> 3), c8 = (l & 7) * 8;
        half8_t v = *(const half8_t*)(kh + (size_t)n * 64 + c8);
        *(half8_t*)(khp + ((size_t)(c8 >> 4) * N + n) * 16 + (c8 & 15)) = v;
    }
    __syncthreads();
    {
        int c = t >> 2, ks = (t & 3) * 16;
        half8_t y0, y1;
        #pragma unroll
        for (int i = 0; i < 8; ++i) { y0[i] = tile[ks + i][c]; y1[i] = tile[ks + 8 + i][c]; }
        *(half8_t*)(vt + (size_t)c * N + kb + ks)     = y0;
        *(half8_t*)(vt + (size_t)c * N + kb + ks + 8) = y1;
    }
}

// Block = 8 waves / 512 thr, one head, 32 queries (2 q-subtiles x 4-way key split).
// Group grp (2 waves) processes tiles grp, grp+4, ... ; double-buffered LDS;
// exp2-domain softmax with defer-max; deterministic fixed-order 4-way merge.
__global__ __launch_bounds__(512) void mha_fa5(const _Float16* __restrict__ qh,
                                               const _Float16* __restrict__ khp,
                                               const _Float16* __restrict__ vt,
                                               float* __restrict__ ao, int N) {
    __shared__ alignas(16) char smem[38912];
    typedef _Float16 (*KtT)[2][64][20];   // [grp][buf][key][ch]   20480 B
    typedef _Float16 (*VtT)[2][16][68];   // [grp][buf][ch][key]   17408 B
    KtT Kt = (KtT)smem;
    VtT Vt = (VtT)(smem + 20480);
    float* MBp = (float*)(smem + 37888);  // [wsub][grp][2][16] = 1024 B
    float* OBp = (float*)smem;            // overlay on Kt: [wsub][grp][16][17] f32

    int h    = blockIdx.y;
    int t    = threadIdx.x;
    int lane = t & 63;
    int wave = t >> 6;
    int grp  = wave >> 1;
    int wsub = wave & 1;
    int lo16 = lane & 15;
    int g    = lane >> 4;
    int q    = blockIdx.x * 32 + wsub * 16 + lo16;

    half4_t qf = *(const half4_t*)(qh + (size_t)q * 64 + h * 16 + g * 4);
    const _Float16* kp = khp + (size_t)h * N * 16;
    const _Float16* vp = vt + (size_t)h * 16 * N;

    int gt   = t & 127;                   // thread id within the group (2 waves)
    int skey = gt >> 1, sch = (gt & 1) * 8;   // K staging: 16B per thread
    int sd   = gt >> 3, skv = (gt & 7) * 8;   // V staging: 16B per thread

    {   // prologue: stage this group's tile 0
        int kt = grp * 64;
        half8_t kv = *(const half8_t*)(kp + (size_t)(kt + skey) * 16 + sch);
        half8_t vv = *(const half8_t*)(vp + (size_t)sd * N + kt + skv);
        half4_t a, b, c, d;
        #pragma unroll
        for (int i = 0; i < 4; ++i) { a[i] = kv[i]; b[i] = kv[4 + i]; c[i] = vv[i]; d[i] = vv[4 + i]; }
        *(half4_t*)&Kt[grp][0][skey][sch]     = a;
        *(half4_t*)&Kt[grp][0][skey][sch + 4] = b;
        *(half4_t*)&Vt[grp][0][sd][skv]       = c;
        *(half4_t*)&Vt[grp][0][sd][skv + 4]   = d;
    }

    float m = -1e30f, l = 0.f;
    f32x4 o = {0.f, 0.f, 0.f, 0.f};
    const f32x4 zero = {0.f, 0.f, 0.f, 0.f};
    const int nit = N / 256;              // 4 groups x 64 keys

    for (int it = 0; it < nit; ++it) {
        int cur = it & 1;
        __syncthreads();
        if (it + 1 < nit) {
            int kt = ((it + 1) * 4 + grp) * 64;
            half8_t kv = *(const half8_t*)(kp + (size_t)(kt + skey) * 16 + sch);
            half8_t vv = *(const half8_t*)(vp + (size_t)sd * N + kt + skv);
            half4_t a, b, c, d;
            #pragma unroll
            for (int i = 0; i < 4; ++i) { a[i] = kv[i]; b[i] = kv[4 + i]; c[i] = vv[i]; d[i] = vv[4 + i]; }
            *(half4_t*)&Kt[grp][cur ^ 1][skey][sch]     = a;
            *(half4_t*)&Kt[grp][cur ^ 1][skey][sch + 4] = b;
            *(half4_t*)&Vt[grp][cur ^ 1][sd][skv]       = c;
            *(half4_t*)&Vt[grp][cur ^ 1][sd][skv + 4]   = d;
        }
        // ---- QK^T: 4 sub-tiles of 16 keys (scores in log2 domain)
        f32x4 s[4];
        __builtin_amdgcn_s_setprio(1);
        #pragma unroll
        for (int st = 0; st < 4; ++st) {
            half4_t kf = *(const half4_t*)&Kt[grp][cur][st * 16 + lo16][g * 4];
            s[st] = MFMA16(kf, qf, zero);
        }
        __builtin_amdgcn_s_setprio(0);
        // ---- online softmax, defer-max (THR=8 in log2 domain)
        float t0 = fmaxf(fmaxf(s[0][0], s[0][1]), s[0][2]);
        float t1 = fmaxf(fmaxf(s[0][3], s[1][0]), s[1][1]);
        float t2 = fmaxf(fmaxf(s[1][2], s[1][3]), s[2][0]);
        float t3 = fmaxf(fmaxf(s[2][1], s[2][2]), s[2][3]);
        float t4 = fmaxf(fmaxf(s[3][0], s[3][1]), fmaxf(s[3][2], s[3][3]));
        float tm = fmaxf(fmaxf(fmaxf(t0, t1), fmaxf(t2, t3)), t4);
        tm = fmaxf(tm, __shfl_xor(tm, 16));
        tm = fmaxf(tm, __shfl_xor(tm, 32));
        if (!__all(tm <= m + 8.f)) {
            float mnew = fmaxf(m, tm);
            float r = EXP2N(m - mnew);
            l *= r;
            #pragma unroll
            for (int i = 0; i < 4; ++i) o[i] *= r;
            m = mnew;
        }
        float lsum = 0.f;
        half4_t pf[4];
        #pragma unroll
        for (int st = 0; st < 4; ++st) {
            float p0 = EXP2N(s[st][0] - m);
            float p1 = EXP2N(s[st][1] - m);
            float p2 = EXP2N(s[st][2] - m);
            float p3 = EXP2N(s[st][3] - m);
            lsum += (p0 + p1) + (p2 + p3);
            auto lo = __builtin_amdgcn_cvt_pkrtz(p0, p1);   // __fp16x2
            auto hi = __builtin_amdgcn_cvt_pkrtz(p2, p3);
            pf[st][0] = (_Float16)lo[0]; pf[st][1] = (_Float16)lo[1];
            pf[st][2] = (_Float16)hi[0]; pf[st][3] = (_Float16)hi[1];
        }
        l += lsum;
        // ---- PV
        __builtin_amdgcn_s_setprio(1);
        #pragma unroll
        for (int st = 0; st < 4; ++st) {
            half4_t vf = *(const half4_t*)&Vt[grp][cur][lo16][st * 16 + g * 4];
            o = MFMA16(vf, pf[st], o);
        }
        __builtin_amdgcn_s_setprio(0);
    }
    // per-wave l reduce across the 4 lane-groups (disjoint key subsets)
    l += __shfl_xor(l, 16);
    l += __shfl_xor(l, 32);

    __syncthreads();   // all tile reads done -> safe to overlay merge buffers on Kt
    if (grp != 0) {    // publish partial state
        if (lane < 16) {
            MBp[((wsub * 4 + grp) * 2 + 0) * 16 + lane] = m;
            MBp[((wsub * 4 + grp) * 2 + 1) * 16 + lane] = l;
        }
        #pragma unroll
        for (int i = 0; i < 4; ++i)
            OBp[((wsub * 4 + grp) * 16 + g * 4 + i) * 17 + lo16] = o[i];
    }
    __syncthreads();
    if (grp == 0) {    // deterministic merge: grp 0,1,2,3 in fixed order
        float M = m, L = l;
        f32x4 O = o;
        #pragma unroll
        for (int gg = 1; gg < 4; ++gg) {
            float m1 = MBp[((wsub * 4 + gg) * 2 + 0) * 16 + lo16];
            float l1 = MBp[((wsub * 4 + gg) * 2 + 1) * 16 + lo16];
            float Mn = fmaxf(M, m1);
            float e0 = EXP2N(M - Mn), e1 = EXP2N(m1 - Mn);
            L = L * e0 + l1 * e1;
            #pragma unroll
            for (int i = 0; i < 4; ++i)
                O[i] = O[i] * e0 + OBp[((wsub * 4 + gg) * 16 + g * 4 + i) * 17 + lo16] * e1;
            M = Mn;
        }
        float inv = 1.f / L;
        f32x4 res;
        #pragma unroll
        for (int i = 0; i < 4; ++i) res[i] = O[i] * inv;
        *(f32x4*)(ao + (size_t)q * 64 + h * 16 + g * 4) = res;
    }
}

// ------------------------------------------------------------------ fused MLP head
// per 64-row block: S1 = ao@Wo^T+bo (64x64); S2 = relu(S1@Wc1^T+bc1) (64x32);
// out = S2@Wc2^T+bc2 (64x10). Intermediates stay in LDS; wave's own 16 rows are
// written back without cross-wave hazard (only Bt restages need barriers).
__global__ void mlp_head(const float* __restrict__ ao,
                         const float* __restrict__ Wo, const float* __restrict__ bo,
                         const float* __restrict__ Wc1, const float* __restrict__ bc1,
                         const float* __restrict__ Wc2, const float* __restrict__ bc2,
                         float* __restrict__ outp, int N) {
    __shared__ _Float16 At[64][68];
    __shared__ _Float16 Bt[64][68];
    int t = threadIdx.x, wave = t >> 6, lane = t & 63, lo16 = lane & 15, g = lane >> 4;
    int brow = blockIdx.x * 64;
    const f32x4 zero = {0.f, 0.f, 0.f, 0.f};
    {   // stage At <- ao, Bt <- Wo (both 64x64 f32 -> f16)
        int r = t >> 2, c0 = (t & 3) * 16;
        const float* ap = ao + (size_t)(brow + r) * 64 + c0;
        const float* wp = Wo + (size_t)r * 64 + c0;
        #pragma unroll
        for (int j = 0; j < 16; j += 4) {
            f32x4 va = *(const f32x4*)(ap + j);
            f32x4 vw = *(const f32x4*)(wp + j);
            half4_t ha, hw;
            #pragma unroll
            for (int i = 0; i < 4; ++i) { ha[i] = (_Float16)va[i]; hw[i] = (_Float16)vw[i]; }
            *(half4_t*)&At[r][c0 + j] = ha;
            *(half4_t*)&Bt[r][c0 + j] = hw;
        }
    }
    __syncthreads();
    // ---- S1 = At @ Wo^T + bo
    f32x4 acc1[4];
    #pragma unroll
    for (int i = 0; i < 4; ++i) acc1[i] = zero;
    #pragma unroll
    for (int kc = 0; kc < 4; ++kc) {
        half4_t af = *(const half4_t*)&At[wave * 16 + lo16][kc * 16 + g * 4];
        #pragma unroll
        for (int cf = 0; cf < 4; ++cf) {
            half4_t bf = *(const half4_t*)&Bt[cf * 16 + lo16][kc * 16 + g * 4];
            acc1[cf] = MFMA16(af, bf, acc1[cf]);
        }
    }
    // write S1 back to the wave's own 16 rows of At (wave-local, no barrier needed)
    #pragma unroll
    for (int cf = 0; cf < 4; ++cf) {
        int c = cf * 16 + lo16;
        float bv = bo[c];
        #pragma unroll
        for (int reg = 0; reg < 4; ++reg)
            At[wave * 16 + g * 4 + reg][c] = (_Float16)(acc1[cf][reg] + bv);
    }
    __syncthreads();
    {   // restage Bt <- Wc1 (32x64)
        int r = t >> 2, c0 = (t & 3) * 16;
        if (r < 32) {
            const float* wp = Wc1 + (size_t)r * 64 + c0;
            #pragma unroll
            for (int j = 0; j < 16; j += 4) {
                f32x4 vw = *(const f32x4*)(wp + j);
                half4_t hw;
                #pragma unroll
                for (int i = 0; i < 4; ++i) hw[i] = (_Float16)vw[i];
                *(half4_t*)&Bt[r][c0 + j] = hw;
            }
        }
    }
    __syncthreads();
    // ---- S2 = relu(S1 @ Wc1^T + bc1), 64x32
    f32x4 acc2[2];
    acc2[0] = zero; acc2[1] = zero;
    #pragma unroll
    for (int kc = 0; kc < 4; ++kc) {
        half4_t af = *(const half4_t*)&At[wave * 16 + lo16][kc * 16 + g * 4];
        #pragma unroll
        for (int cf = 0; cf < 2; ++cf) {
            half4_t bf = *(const half4_t*)&Bt[cf * 16 + lo16][kc * 16 + g * 4];
            acc2[cf] = MFMA16(af, bf, acc2[cf]);
        }
    }
    #pragma unroll
    for (int cf = 0; cf < 2; ++cf) {
        int c = cf * 16 + lo16;
        float bv = bc1[c];
        #pragma unroll
        for (int reg = 0; reg < 4; ++reg)
            At[wave * 16 + g * 4 + reg][c] = (_Float16)fmaxf(acc2[cf][reg] + bv, 0.f);
    }
    __syncthreads();
    {   // restage Bt <- Wc2 (10x32, zero-pad rows 10..15)
        if (t < 32) {
            int r = t >> 1, c0 = (t & 1) * 16;
            half4_t hw;
            #pragma unroll
            for (int j = 0; j < 16; j += 4) {
                if (r < 10) {
                    f32x4 vw = *(const f32x4*)(Wc2 + (size_t)r * 32 + c0 + j);
                    #pragma unroll
                    for (int i = 0; i < 4; ++i) hw[i] = (_Float16)vw[i];
                } else {
                    #pragma unroll
                    for (int i = 0; i < 4; ++i) hw[i] = (_Float16)0.f;
                }
                *(half4_t*)&Bt[r][c0 + j] = hw;
            }
        }
    }
    __syncthreads();
    // ---- out = S2 @ Wc2^T + bc2, 64x10
    f32x4 acc3 = zero;
    #pragma unroll
    for (int kc = 0; kc < 2; ++kc) {
        half4_t af = *(const half4_t*)&At[wave * 16 + lo16][kc * 16 + g * 4];
        half4_t bf = *(const half4_t*)&Bt[lo16][kc * 16 + g * 4];
        acc3 = MFMA16(af, bf, acc3);
    }
    if (lo16 < 10) {
        float bv = bc2[lo16];
        #pragma unroll
        for (int reg = 0; reg < 4; ++reg) {
            int row = brow + wave * 16 + g * 4 + reg;
            outp[(size_t)row * 10 + lo16] = acc3[reg] + bv;
        }
    }
}

// ------------------------------------------------------------------- host side
extern "C" void kernel_launch(void* const* d_in, const int* in_sizes, int n_in,
                              void* d_out, int out_size, void* d_ws, size_t ws_size,
                              hipStream_t stream) {
    const int N = NN, E = EE;
    const float* x    = (const float*)d_in[0];
    const int*   ei   = (const int*)d_in[1];
    const float* W[3]   = {(const float*)d_in[2], (const float*)d_in[6], (const float*)d_in[10]};
    const float* as_[3] = {(const float*)d_in[3], (const float*)d_in[7], (const float*)d_in[11]};
    const float* ad_[3] = {(const float*)d_in[4], (const float*)d_in[8], (const float*)d_in[12]};
    const float* bn_g = (const float*)d_in[14];
    const float* bn_b = (const float*)d_in[15];
    const float* Wq = (const float*)d_in[16];
    const float* Wk = (const float*)d_in[17];
    const float* Wv = (const float*)d_in[18];
    const float* Wo = (const float*)d_in[19];
    const float* bq = (const float*)d_in[20];
    const float* bk = (const float*)d_in[21];
    const float* bv = (const float*)d_in[22];
    const float* bo = (const float*)d_in[23];
    const float* Wc1 = (const float*)d_in[24];
    const float* bc1 = (const float*)d_in[25];
    const float* Wc2 = (const float*)d_in[26];
    const float* bc2 = (const float*)d_in[27];

    char* ws = (char*)d_ws;
    _Float16* h16 = (_Float16*)(ws + 0);       // 8192*512*2 = 8,388,608 (GAT phase)
    _Float16* qh = (_Float16*)(ws + 9437184);  // 1,048,576 (MHA phase)
    _Float16* kh = (_Float16*)(ws + 10485760); // 1,048,576
    _Float16* vh = (_Float16*)(ws + 11534336); // 1,048,576
    _Float16* vt = (_Float16*)(ws + 12582912); // 1,048,576
    _Float16* khp = (_Float16*)(ws + 13631488);// 1,048,576
    float* a_s  = (float*)(ws + 16777216);     // 262,144
    float* a_d  = (float*)(ws + 17039360);     // 262,144
    int* row_ptr = (int*)(ws + 17301504);      // 33,024
    int* cursor  = (int*)(ws + 17334528);      // 32,768
    int* deg     = (int*)(ws + 17367296);      // 32,768
    int* col     = (int*)(ws + 17400064);      // 1,081,344
    float* g0   = (float*)(ws + 18481408);     // 2,097,152
    float* g1   = (float*)(ws + 20578560);     // 2,097,152
    float* ao   = (float*)(ws + 28967168);     // 2,097,152
    float* bnscale = (float*)(ws + 32112896);  // 64
    float* bnshift = bnscale + 64;             // 64

    // ---- CSR build (same graph all layers); self-loops via +1 in scan_deg
    hipMemsetAsync(deg, 0, (size_t)N * 4, stream);
    count_deg<<<(E + 255) / 256, 256, 0, stream>>>(ei, deg, E);
    scan_deg<<<1, 1024, 0, stream>>>(deg, row_ptr, cursor, N);
    fill_csr<<<(E + N + 255) / 256, 256, 0, stream>>>(ei, cursor, col, E, N);

    // ---- 3 GAT layers. gat_coef fused into GEMM epilogue; BN+ReLU of layer i
    // fused into layer i+1's (or qkv's) A-staging. No float atomics anywhere.
    // L0 (H=8, K=128, no BN on input x)
    mfma_gemm<false, true, 0, true, false><<<dim3(8, N / 64), 256, 0, stream>>>(
        x, W[0], nullptr, h16, N, 512, 128, 1.f, as_[0], ad_[0], a_s, a_d, 8, nullptr, nullptr);
    gat_gather_h8<<<N / 4, 256, 0, stream>>>(h16, a_s, a_d, row_ptr, col, g0, N);
    bn_stats<<<64, 256, 0, stream>>>(g0, bn_g, bn_b, bnscale, bnshift, N);
    // L1 (H=8, K=64, BN0 fused)
    mfma_gemm<false, true, 0, true, true><<<dim3(8, N / 64), 256, 0, stream>>>(
        g0, W[1], nullptr, h16, N, 512, 64, 1.f, as_[1], ad_[1], a_s, a_d, 8, bnscale, bnshift);
    gat_gather_h8<<<N / 4, 256, 0, stream>>>(h16, a_s, a_d, row_ptr, col, g1, N);
    bn_stats<<<64, 256, 0, stream>>>(g1, bn_g + 64, bn_b + 64, bnscale, bnshift, N);
    // L2 (H=1, K=64, BN1 fused); gather is plain-store -> g0 reusable
    mfma_gemm<false, true, 0, true, true><<<dim3(1, N / 64), 256, 0, stream>>>(
        g1, W[2], nullptr, h16, N, 64, 64, 1.f, as_[2], ad_[2], a_s, a_d, 1, bnscale, bnshift);
    gat_gather_h1<<<N / 4, 256, 0, stream>>>(h16, a_s, a_d, row_ptr, col, g0, N);
    bn_stats<<<64, 256, 0, stream>>>(g0, bn_g + 128, bn_b + 128, bnscale, bnshift, N);

    // ---- MHA (4 heads, hd=16): QKV proj with BN2 fused; exp2-domain flash
    // Q scale = 0.25 (1/sqrt(hd)) * log2(e) -> softmax in exp2 domain
    qkv_gemm<<<dim3(1, N / 64, 3), 256, 0, stream>>>(
        g0, Wq, Wk, Wv, bq, bk, bv, qh, kh, vh, N, 0.36067376f, bnscale, bnshift);
    vkpack<<<N / 64, 256, 0, stream>>>(vh, kh, vt, khp, N);
    mha_fa5<<<dim3(N / 32, 4), 512, 0, stream>>>(qh, khp, vt, ao, N);

    // ---- fused output head: Wo -> relu(Wc1) -> Wc2
    mlp_head<<<N / 64, 256, 0, stream>>>(ao, Wo, bo, Wc1, bc1, Wc2, bc2, (float*)d_out, N);
}